// Round 1
// 3282.725 us; speedup vs baseline: 1.5962x; 1.5962x over previous
//
#include <hip/hip_runtime.h>
#include <hip/hip_bf16.h>
#include <math.h>

// ---- problem constants (from reference) ----
#define DIM    1280
#define HEADS  8
#define DH     160            // DIM / HEADS
#define FRAMES 16
#define BATCH  2
#define TOK    256
#define ESEQ   77
#define INNER  5120           // 4*DIM
#define CROSS  768
#define BF     (BATCH*FRAMES) // 32
#define ROWS   (BF*TOK)       // 8192
#define EROWS  (BF*ESEQ)      // 2464

typedef __hip_bfloat16 bf16;
typedef __attribute__((ext_vector_type(8))) short s8v;
typedef __attribute__((ext_vector_type(4))) short s4v;
typedef __attribute__((ext_vector_type(4))) float f4v;

__device__ __forceinline__ float us2f(unsigned short u) {
    union { float f; unsigned int i; } c; c.i = ((unsigned int)u) << 16; return c.f;
}
__device__ __forceinline__ float b2f(bf16 x) { return __bfloat162float(x); }
__device__ __forceinline__ bf16  f2b(float x) { return __float2bfloat16(x); }
// f32 -> bf16 bits (RNE), as short
__device__ __forceinline__ short f2s(float x) {
    union { float f; unsigned int u; } c; c.f = x;
    unsigned int r = c.u + 0x7FFF + ((c.u >> 16) & 1);
    return (short)(r >> 16);
}

__device__ __forceinline__ void load4(const float* p, float* d) {
    float4 v = *(const float4*)p; d[0] = v.x; d[1] = v.y; d[2] = v.z; d[3] = v.w;
}
__device__ __forceinline__ float ldval(const float* p) { return *p; }
__device__ __forceinline__ float ldval(const bf16* p) { return b2f(*p); }

// ---- LayerNorm: one block per row of DIM=1280 (256 thr x 5 elems) ----
__global__ __launch_bounds__(256) void ln_kernel(const float* __restrict__ x,
                                                 const float* __restrict__ w,
                                                 const float* __restrict__ b,
                                                 bf16* __restrict__ out) {
    __shared__ float r1[256], r2[256];
    int row = blockIdx.x, t = threadIdx.x;
    const float* xp = x + (size_t)row * DIM;
    float v[5], s = 0.f, s2 = 0.f;
#pragma unroll
    for (int i = 0; i < 5; i++) {
        float xv = xp[t + 256 * i];
        v[i] = xv; s += xv; s2 += xv * xv;
    }
    r1[t] = s; r2[t] = s2; __syncthreads();
    for (int st = 128; st > 0; st >>= 1) {
        if (t < st) { r1[t] += r1[t + st]; r2[t] += r2[t + st]; }
        __syncthreads();
    }
    float mean = r1[0] * (1.f / DIM);
    float var  = r2[0] * (1.f / DIM) - mean * mean;
    float rstd = rsqrtf(var + 1e-5f);
    bf16* op = out + (size_t)row * DIM;
#pragma unroll
    for (int i = 0; i < 5; i++) {
        int c = t + 256 * i;
        op[c] = f2b((v[i] - mean) * rstd * w[c] + b[c]);
    }
}

// =====================================================================
// MFMA GEMM: C[M,N] = A[M,K](bf16) @ B[K,N](f32 weights)
// 128x128 block tile, BK=32, mfma_f32_16x16x32_bf16, 4 waves (each 64x64).
// EPI: 0 = bf16 out, no bias
//      1 = f32 out = acc + bias[n] + res[m] (residual stream)
//      2 = geglu: bf16 out = (accP+bias[n]) * gelu(accG+bias[INNER+n]),
//          G strip at B+INNER (ldb = 2*INNER)
// Requires M%128==0, N%128==0, K%32==0.
// =====================================================================
template <int EPI>
__global__ __launch_bounds__(256) void gemm_mfma(
    const bf16* __restrict__ A, int lda,
    const float* __restrict__ B, int ldb,
    void* __restrict__ C, int ldc,
    const float* __restrict__ bias,
    const float* __restrict__ res, int ldres,
    int M, int N, int K) {
    constexpr int LR = 40;                       // LDS row pitch in shorts (32 + 8 pad, 16B-aligned)
    __shared__ short A_lds[128 * LR];
    __shared__ short B_lds[128 * LR];
    __shared__ short G_lds[EPI == 2 ? 128 * LR : 4];

    const int t    = threadIdx.x;
    const int wid  = t >> 6, lane = t & 63;
    const int lrow = lane & 15, lgrp = lane >> 4;
    const int m0   = blockIdx.y * 128, n0 = blockIdx.x * 128;
    const int wm   = (wid & 1) * 64, wn = (wid >> 1) * 64;

    f4v acc[4][4];
    f4v accg[4][4];
#pragma unroll
    for (int i = 0; i < 4; i++)
#pragma unroll
        for (int j = 0; j < 4; j++) {
            acc[i][j] = (f4v){0.f, 0.f, 0.f, 0.f};
            if (EPI == 2) accg[i][j] = (f4v){0.f, 0.f, 0.f, 0.f};
        }

    const int b_np = (t & 31) * 4;   // n patch base (0..124)
    const int b_kp = (t >> 5) * 4;   // k patch base (0..28)

    for (int k0 = 0; k0 < K; k0 += 32) {
        // ---- stage A: 128x32 bf16, 2 chunks of 16B per thread ----
#pragma unroll
        for (int c = 0; c < 2; c++) {
            int idx = t + c * 256;
            int row = idx >> 2, g = (idx & 3) * 8;
            uint4 v = *(const uint4*)(A + (size_t)(m0 + row) * lda + k0 + g);
            *(uint4*)&A_lds[row * LR + g] = v;
        }
        // ---- stage B: 32x128 f32 -> transposed bf16 B_lds[n][k] ----
        {
            const float* bp = B + (size_t)(k0 + b_kp) * ldb + n0 + b_np;
            float4 r0 = *(const float4*)(bp);
            float4 r1 = *(const float4*)(bp + ldb);
            float4 r2 = *(const float4*)(bp + 2 * ldb);
            float4 r3 = *(const float4*)(bp + 3 * ldb);
            *(s4v*)&B_lds[(b_np + 0) * LR + b_kp] = (s4v){f2s(r0.x), f2s(r1.x), f2s(r2.x), f2s(r3.x)};
            *(s4v*)&B_lds[(b_np + 1) * LR + b_kp] = (s4v){f2s(r0.y), f2s(r1.y), f2s(r2.y), f2s(r3.y)};
            *(s4v*)&B_lds[(b_np + 2) * LR + b_kp] = (s4v){f2s(r0.z), f2s(r1.z), f2s(r2.z), f2s(r3.z)};
            *(s4v*)&B_lds[(b_np + 3) * LR + b_kp] = (s4v){f2s(r0.w), f2s(r1.w), f2s(r2.w), f2s(r3.w)};
        }
        if (EPI == 2) {
            const float* gp = B + (size_t)(k0 + b_kp) * ldb + INNER + n0 + b_np;
            float4 r0 = *(const float4*)(gp);
            float4 r1 = *(const float4*)(gp + ldb);
            float4 r2 = *(const float4*)(gp + 2 * ldb);
            float4 r3 = *(const float4*)(gp + 3 * ldb);
            *(s4v*)&G_lds[(b_np + 0) * LR + b_kp] = (s4v){f2s(r0.x), f2s(r1.x), f2s(r2.x), f2s(r3.x)};
            *(s4v*)&G_lds[(b_np + 1) * LR + b_kp] = (s4v){f2s(r0.y), f2s(r1.y), f2s(r2.y), f2s(r3.y)};
            *(s4v*)&G_lds[(b_np + 2) * LR + b_kp] = (s4v){f2s(r0.z), f2s(r1.z), f2s(r2.z), f2s(r3.z)};
            *(s4v*)&G_lds[(b_np + 3) * LR + b_kp] = (s4v){f2s(r0.w), f2s(r1.w), f2s(r2.w), f2s(r3.w)};
        }
        __syncthreads();
        // ---- fragments + MFMA ----
        s8v af[4], bfr[4];
#pragma unroll
        for (int i = 0; i < 4; i++)
            af[i] = *(const s8v*)&A_lds[(wm + i * 16 + lrow) * LR + lgrp * 8];
#pragma unroll
        for (int j = 0; j < 4; j++)
            bfr[j] = *(const s8v*)&B_lds[(wn + j * 16 + lrow) * LR + lgrp * 8];
#pragma unroll
        for (int i = 0; i < 4; i++)
#pragma unroll
            for (int j = 0; j < 4; j++)
                acc[i][j] = __builtin_amdgcn_mfma_f32_16x16x32_bf16(af[i], bfr[j], acc[i][j], 0, 0, 0);
        if (EPI == 2) {
            s8v gfr[4];
#pragma unroll
            for (int j = 0; j < 4; j++)
                gfr[j] = *(const s8v*)&G_lds[(wn + j * 16 + lrow) * LR + lgrp * 8];
#pragma unroll
            for (int i = 0; i < 4; i++)
#pragma unroll
                for (int j = 0; j < 4; j++)
                    accg[i][j] = __builtin_amdgcn_mfma_f32_16x16x32_bf16(af[i], gfr[j], accg[i][j], 0, 0, 0);
        }
        __syncthreads();
    }

    // ---- epilogue: C/D layout col=lane&15, row=(lane>>4)*4+reg ----
#pragma unroll
    for (int i = 0; i < 4; i++) {
#pragma unroll
        for (int r = 0; r < 4; r++) {
            int m = m0 + wm + i * 16 + lgrp * 4 + r;
#pragma unroll
            for (int j = 0; j < 4; j++) {
                int n = n0 + wn + j * 16 + lrow;
                float v = acc[i][j][r];
                if (EPI == 0) {
                    ((bf16*)C)[(size_t)m * ldc + n] = f2b(v);
                } else if (EPI == 1) {
                    v += bias[n] + res[(size_t)m * ldres + n];
                    ((float*)C)[(size_t)m * ldc + n] = v;
                } else {
                    float p = v + bias[n];
                    float g = accg[i][j][r] + bias[INNER + n];
                    float gl = 0.5f * g * (1.f + erff(g * 0.70710678118654752f));
                    ((bf16*)C)[(size_t)m * ldc + n] = f2b(p * gl);
                }
            }
        }
    }
}

// ---- old VALU GEMM (used only for encoder projections: M=2464 not %128) ----
__global__ __launch_bounds__(256) void gemm_valu(
    const float* __restrict__ A, int lda,
    const float* __restrict__ B, int ldb,
    bf16* __restrict__ C, int ldc,
    int M, int N, int K) {
    __shared__ float As[16][65];
    __shared__ float Bs[16][65];
    const int t  = threadIdx.x;
    const int m0 = blockIdx.y * 64, n0 = blockIdx.x * 64;
    const int ar = t >> 2, ak = (t & 3) * 4;
    const int bk = t >> 4, bn = (t & 15) * 4;
    const int ty = t >> 4, tx = t & 15;
    float acc[4][4];
#pragma unroll
    for (int i = 0; i < 4; i++)
#pragma unroll
        for (int j = 0; j < 4; j++) acc[i][j] = 0.f;

    for (int k0 = 0; k0 < K; k0 += 16) {
        {
            int m = m0 + ar;
            float tmp[4];
            if (m < M) load4(A + (size_t)m * lda + k0 + ak, tmp);
            else { tmp[0] = tmp[1] = tmp[2] = tmp[3] = 0.f; }
            As[ak + 0][ar] = tmp[0]; As[ak + 1][ar] = tmp[1];
            As[ak + 2][ar] = tmp[2]; As[ak + 3][ar] = tmp[3];
        }
        {
            float tmp[4];
            load4(B + (size_t)(k0 + bk) * ldb + n0 + bn, tmp);
            Bs[bk][bn + 0] = tmp[0]; Bs[bk][bn + 1] = tmp[1];
            Bs[bk][bn + 2] = tmp[2]; Bs[bk][bn + 3] = tmp[3];
        }
        __syncthreads();
#pragma unroll
        for (int k = 0; k < 16; k++) {
            float a[4], b[4];
#pragma unroll
            for (int i = 0; i < 4; i++) a[i] = As[k][ty * 4 + i];
#pragma unroll
            for (int j = 0; j < 4; j++) b[j] = Bs[k][tx * 4 + j];
#pragma unroll
            for (int i = 0; i < 4; i++)
#pragma unroll
                for (int j = 0; j < 4; j++) acc[i][j] += a[i] * b[j];
        }
        __syncthreads();
    }
#pragma unroll
    for (int i = 0; i < 4; i++) {
        int m = m0 + ty * 4 + i;
        if (m >= M) continue;
#pragma unroll
        for (int j = 0; j < 4; j++) {
            int n = n0 + tx * 4 + j;
            C[(size_t)m * ldc + n] = f2b(acc[i][j]);
        }
    }
}

#define SOFTMAX_SCALE 0.07905694150420949f  // 1/sqrt(160)

// =====================================================================
// attn1 (sparse-causal, 512 keys) — MFMA flash-attention.
// Grid: (TOK/64, HEADS, BF). Block: 256 thr = 4 waves, 16 queries/wave.
// Per chunk of 64 keys: stage K[64][160] + V^T[160][64] (xor-swizzled) in
// LDS, QK^T via mfma_16x16x32_bf16 (Q A-frags live in registers), online
// softmax in-register (row = (lane>>4)*4+r, cols spread over lane&15 and
// 4 frags -> shfl_xor(1,2,4,8) row-reduce), P -> per-wave LDS tile to
// re-shape into A-frag layout, PV via mfma into 16x160 f32 accumulator.
// =====================================================================
#define A1_KP 168   // K LDS pitch (shorts): 160 + 8 pad
#define A1_VP 72    // V^T pitch (shorts):   64 + 8 pad (keeps reads spread)
#define A1_PP 72    // P  pitch (shorts)

__global__ __launch_bounds__(256) void attn1_mfma(const bf16* __restrict__ q,
                                                  const bf16* __restrict__ k,
                                                  const bf16* __restrict__ v,
                                                  bf16* __restrict__ o) {
    __shared__ short K_lds[64 * A1_KP];         // 21.0 KB
    __shared__ short Vt_lds[160 * A1_VP];       // 22.5 KB
    __shared__ short P_lds[4 * 16 * A1_PP];     //  9.0 KB

    const int t = threadIdx.x;
    const int wid = t >> 6, lane = t & 63;
    const int lrow = lane & 15, lgrp = lane >> 4;
    const int bx = blockIdx.x, hd = blockIdx.y, bfi = blockIdx.z;
    const int bi = bfi >> 4, fi = bfi & 15;
    const int former = fi > 0 ? fi - 1 : 0;
    const int qbase = bfi * TOK + bx * 64 + wid * 16;

    // ---- Q A-fragments straight from global: lane holds Q[lrow][lgrp*8+e] ----
    s8v qf[5];
    {
        const bf16* qp = q + (size_t)(qbase + lrow) * DIM + hd * DH + lgrp * 8;
#pragma unroll
        for (int ks = 0; ks < 5; ks++)
            qf[ks] = *(const s8v*)(qp + ks * 32);
    }

    f4v oacc[10];
#pragma unroll
    for (int dg = 0; dg < 10; dg++) oacc[dg] = (f4v){0.f, 0.f, 0.f, 0.f};
    float m_run[4], l_run[4];
#pragma unroll
    for (int r = 0; r < 4; r++) { m_run[r] = -1e30f; l_run[r] = 0.f; }

    short* P_w = P_lds + wid * 16 * A1_PP;

    for (int c = 0; c < 8; c++) {
        const int kf = (c < 4) ? 0 : former;                    // frame-0 keys then former-frame keys
        const size_t krow0 = (size_t)(bi * FRAMES + kf) * TOK + (c & 3) * 64;

        __syncthreads();                                        // prev chunk's reads done
        // ---- stage K [key][d] and V^T [d][key^(d&56)] ----
#pragma unroll
        for (int it = 0; it < 5; it++) {
            int idx = t + it * 256;                             // 1280 groups = 64 rows x 20
            int jr = idx / 20, g = idx % 20;
            const bf16* kp = k + (krow0 + jr) * DIM + hd * DH + g * 8;
            *(uint4*)&K_lds[jr * A1_KP + g * 8] = *(const uint4*)kp;
            s8v vv = *(const s8v*)(v + (krow0 + jr) * DIM + hd * DH + g * 8);
#pragma unroll
            for (int i = 0; i < 8; i++) {
                int d = g * 8 + i;
                Vt_lds[d * A1_VP + (jr ^ (d & 56))] = vv[i];
            }
        }
        __syncthreads();

        // ---- QK^T: S[q=lgrp*4+r][key=kg*16+lrow] ----
        f4v sacc[4];
#pragma unroll
        for (int kg = 0; kg < 4; kg++) {
            sacc[kg] = (f4v){0.f, 0.f, 0.f, 0.f};
#pragma unroll
            for (int ks = 0; ks < 5; ks++) {
                s8v kfr = *(const s8v*)&K_lds[(kg * 16 + lrow) * A1_KP + ks * 32 + lgrp * 8];
                sacc[kg] = __builtin_amdgcn_mfma_f32_16x16x32_bf16(qf[ks], kfr, sacc[kg], 0, 0, 0);
            }
        }

        // ---- online softmax (per row, reduce across the 16-lane group) ----
        float mc[4];
#pragma unroll
        for (int r = 0; r < 4; r++) {
            float mm = fmaxf(fmaxf(sacc[0][r], sacc[1][r]), fmaxf(sacc[2][r], sacc[3][r]));
            mc[r] = mm * SOFTMAX_SCALE;
        }
#pragma unroll
        for (int x = 1; x < 16; x <<= 1)
#pragma unroll
            for (int r = 0; r < 4; r++)
                mc[r] = fmaxf(mc[r], __shfl_xor(mc[r], x));

        float p[4][4], rs[4];
#pragma unroll
        for (int r = 0; r < 4; r++) {
            float mn = fmaxf(m_run[r], mc[r]);
            float sc = __expf(m_run[r] - mn);
            m_run[r] = mn;
            l_run[r] *= sc;
#pragma unroll
            for (int dg = 0; dg < 10; dg++) oacc[dg][r] *= sc;
            float acc = 0.f;
#pragma unroll
            for (int kg = 0; kg < 4; kg++) {
                float e = __expf(sacc[kg][r] * SOFTMAX_SCALE - mn);
                p[kg][r] = e; acc += e;
            }
            rs[r] = acc;
        }
#pragma unroll
        for (int x = 1; x < 16; x <<= 1)
#pragma unroll
            for (int r = 0; r < 4; r++)
                rs[r] += __shfl_xor(rs[r], x);
#pragma unroll
        for (int r = 0; r < 4; r++) l_run[r] += rs[r];

        // ---- P -> per-wave LDS tile [q][j] (bf16) ----
#pragma unroll
        for (int kg = 0; kg < 4; kg++)
#pragma unroll
            for (int r = 0; r < 4; r++)
                P_w[(lgrp * 4 + r) * A1_PP + kg * 16 + lrow] = f2s(p[kg][r]);
        __syncthreads();    // cheap safety fence (also keeps waves in phase)

        // ---- PV: O[q][d] += P[q][j] * V[j][d] ----
        s8v pa[2];
#pragma unroll
        for (int ks2 = 0; ks2 < 2; ks2++)
            pa[ks2] = *(const s8v*)&P_w[lrow * A1_PP + ks2 * 32 + lgrp * 8];
#pragma unroll
        for (int dg = 0; dg < 10; dg++) {
            int dd = dg * 16 + lrow;
#pragma unroll
            for (int ks2 = 0; ks2 < 2; ks2++) {
                s8v vfr = *(const s8v*)&Vt_lds[dd * A1_VP + ((ks2 * 32 + lgrp * 8) ^ (dd & 56))];
                oacc[dg] = __builtin_amdgcn_mfma_f32_16x16x32_bf16(pa[ks2], vfr, oacc[dg], 0, 0, 0);
            }
        }
    }

    // ---- epilogue: O / l ----
    float invl[4];
#pragma unroll
    for (int r = 0; r < 4; r++) invl[r] = 1.f / l_run[r];
#pragma unroll
    for (int dg = 0; dg < 10; dg++) {
#pragma unroll
        for (int r = 0; r < 4; r++) {
            int qq = qbase + lgrp * 4 + r;
            o[(size_t)qq * DIM + hd * DH + dg * 16 + lrow] = f2b(oacc[dg][r] * invl[r]);
        }
    }
}

// ---- attn2: cross-attention, 77 keys ----
__global__ __launch_bounds__(256) void attn2_kernel(const bf16* __restrict__ q,
                                                    const bf16* __restrict__ k,
                                                    const bf16* __restrict__ v,
                                                    bf16* __restrict__ o) {
    __shared__ float sQ[DH];
    __shared__ float sS[128];
    __shared__ float red[256];
    int t = threadIdx.x;
    int qi = blockIdx.x, hd = blockIdx.y, bfi = blockIdx.z;
    size_t qbase = ((size_t)(bfi * TOK + qi)) * DIM + hd * DH;
    if (t < DH) sQ[t] = b2f(q[qbase + t]);
    __syncthreads();
    if (t < ESEQ) {
        size_t kbase = ((size_t)(bfi * ESEQ + t)) * DIM + hd * DH;
        float acc = 0.f;
        for (int d = 0; d < DH; d++) acc += sQ[d] * b2f(k[kbase + d]);
        sS[t] = acc * SOFTMAX_SCALE;
    }
    __syncthreads();
    float lm = (t < ESEQ) ? sS[t] : -1e30f;
    red[t] = lm; __syncthreads();
    for (int s = 128; s > 0; s >>= 1) { if (t < s) red[t] = fmaxf(red[t], red[t + s]); __syncthreads(); }
    float mx = red[0]; __syncthreads();
    float ls = 0.f;
    if (t < ESEQ) { float e = __expf(sS[t] - mx); sS[t] = e; ls = e; }
    red[t] = ls; __syncthreads();
    for (int s = 128; s > 0; s >>= 1) { if (t < s) red[t] += red[t + s]; __syncthreads(); }
    float inv = 1.f / red[0];
    __syncthreads();
    if (t < DH) {
        float acc = 0.f;
        for (int j = 0; j < ESEQ; j++) {
            size_t vbase = ((size_t)(bfi * ESEQ + j)) * DIM + hd * DH;
            acc += sS[j] * b2f(v[vbase + t]);
        }
        o[qbase + t] = f2b(acc * inv);
    }
}

// ---- temporal self-attn: 16 keys (frames) per (batch, token) ----
__global__ __launch_bounds__(256) void attnt_kernel(const bf16* __restrict__ q,
                                                    const bf16* __restrict__ k,
                                                    const bf16* __restrict__ v,
                                                    bf16* __restrict__ o) {
    __shared__ float sQ[DH];
    __shared__ float sS[16];
    __shared__ float red[256];
    int t = threadIdx.x;
    int qfi = blockIdx.x, hd = blockIdx.y, z = blockIdx.z;
    int bi = z >> 8, ti = z & 255;
    size_t qbase = ((size_t)((bi * FRAMES + qfi) * TOK + ti)) * DIM + hd * DH;
    if (t < DH) sQ[t] = b2f(q[qbase + t]);
    __syncthreads();
    if (t < FRAMES) {
        size_t kbase = ((size_t)((bi * FRAMES + t) * TOK + ti)) * DIM + hd * DH;
        float acc = 0.f;
        for (int d = 0; d < DH; d++) acc += sQ[d] * b2f(k[kbase + d]);
        sS[t] = acc * SOFTMAX_SCALE;
    }
    __syncthreads();
    float lm = (t < FRAMES) ? sS[t] : -1e30f;
    red[t] = lm; __syncthreads();
    for (int s = 128; s > 0; s >>= 1) { if (t < s) red[t] = fmaxf(red[t], red[t + s]); __syncthreads(); }
    float mx = red[0]; __syncthreads();
    float ls = 0.f;
    if (t < FRAMES) { float e = __expf(sS[t] - mx); sS[t] = e; ls = e; }
    red[t] = ls; __syncthreads();
    for (int s = 128; s > 0; s >>= 1) { if (t < s) red[t] += red[t + s]; __syncthreads(); }
    float inv = 1.f / red[0];
    __syncthreads();
    if (t < DH) {
        float acc = 0.f;
        for (int j = 0; j < FRAMES; j++) {
            size_t vbase = ((size_t)((bi * FRAMES + j) * TOK + ti)) * DIM + hd * DH;
            acc += sS[j] * b2f(v[vbase + t]);
        }
        o[qbase + t] = f2b(acc * inv);
    }
}

extern "C" void kernel_launch(void* const* d_in, const int* in_sizes, int n_in,
                              void* d_out, int out_size, void* d_ws, size_t ws_size,
                              hipStream_t stream) {
    (void)in_sizes; (void)n_in; (void)out_size; (void)ws_size;
    const float* hs   = (const float*)d_in[0];
    const float* enc  = (const float*)d_in[1];
    const float* n1w  = (const float*)d_in[2];
    const float* n1b  = (const float*)d_in[3];
    const float* a1wq = (const float*)d_in[4];
    const float* a1wk = (const float*)d_in[5];
    const float* a1wv = (const float*)d_in[6];
    const float* a1wo = (const float*)d_in[7];
    const float* a1bo = (const float*)d_in[8];
    const float* n2w  = (const float*)d_in[9];
    const float* n2b  = (const float*)d_in[10];
    const float* a2wq = (const float*)d_in[11];
    const float* a2wk = (const float*)d_in[12];
    const float* a2wv = (const float*)d_in[13];
    const float* a2wo = (const float*)d_in[14];
    const float* a2bo = (const float*)d_in[15];
    const float* n3w  = (const float*)d_in[16];
    const float* n3b  = (const float*)d_in[17];
    const float* ffw1 = (const float*)d_in[18];
    const float* ffb1 = (const float*)d_in[19];
    const float* ffw2 = (const float*)d_in[20];
    const float* ffb2 = (const float*)d_in[21];
    const float* ntw  = (const float*)d_in[22];
    const float* ntb  = (const float*)d_in[23];
    const float* atwq = (const float*)d_in[24];
    const float* atwk = (const float*)d_in[25];
    const float* atwv = (const float*)d_in[26];
    const float* atwo = (const float*)d_in[27];
    const float* atbo = (const float*)d_in[28];

    // ---- workspace carve: 105 MB total (proven to fit) ----
    char* wp = (char*)d_ws;
    auto carve = [&](size_t bytes) -> char* {
        char* p = wp; wp += (bytes + 255) & ~((size_t)255); return p;
    };
    bf16* nh = (bf16*)carve((size_t)ROWS * DIM * 2);
    bf16* qb = (bf16*)carve((size_t)ROWS * DIM * 2);
    bf16* kb = (bf16*)carve((size_t)ROWS * DIM * 2);
    bf16* vb = (bf16*)carve((size_t)ROWS * DIM * 2);
    bf16* ob = (bf16*)carve((size_t)ROWS * DIM * 2);
    bf16* Pb = qb;  // FFN intermediate aliases qb..ob (exactly ROWS*INNER*2 bytes)
    float* out = (float*)d_out;   // f32 residual stream lives in d_out

    dim3 blk(256);
    // bf16 A -> bf16 C projection
    auto proj = [&](const bf16* A, int lda, const float* B, int ldb,
                    bf16* C, int ldc, int M, int N, int K) {
        gemm_mfma<0><<<dim3(N / 128, M / 128), blk, 0, stream>>>(
            A, lda, B, ldb, C, ldc, nullptr, nullptr, 0, M, N, K);
    };
    // out-projection: f32 out = A@B + bias + res
    auto outproj = [&](const bf16* A, int lda, const float* B,
                       const float* bias, const float* res, int K) {
        gemm_mfma<1><<<dim3(DIM / 128, ROWS / 128), blk, 0, stream>>>(
            A, lda, B, DIM, out, DIM, bias, res, DIM, ROWS, DIM, K);
    };

    // ---- attn1: sparse-causal self-attention ----
    ln_kernel<<<dim3(ROWS), blk, 0, stream>>>(hs, n1w, n1b, nh);
    proj(nh, DIM, a1wq, DIM, qb, DIM, ROWS, DIM, DIM);
    proj(nh, DIM, a1wk, DIM, kb, DIM, ROWS, DIM, DIM);
    proj(nh, DIM, a1wv, DIM, vb, DIM, ROWS, DIM, DIM);
    attn1_mfma<<<dim3(TOK / 64, HEADS, BF), blk, 0, stream>>>(qb, kb, vb, ob);
    outproj(ob, DIM, a1wo, a1bo, hs, DIM);

    // ---- attn2: cross-attention ----
    ln_kernel<<<dim3(ROWS), blk, 0, stream>>>(out, n2w, n2b, nh);
    proj(nh, DIM, a2wq, DIM, qb, DIM, ROWS, DIM, DIM);
    gemm_valu<<<dim3(DIM / 64, (EROWS + 63) / 64), blk, 0, stream>>>(enc, CROSS, a2wk, DIM, kb, DIM, EROWS, DIM, CROSS);
    gemm_valu<<<dim3(DIM / 64, (EROWS + 63) / 64), blk, 0, stream>>>(enc, CROSS, a2wv, DIM, vb, DIM, EROWS, DIM, CROSS);
    attn2_kernel<<<dim3(TOK, HEADS, BF), blk, 0, stream>>>(qb, kb, vb, ob);
    outproj(ob, DIM, a2wo, a2bo, out, DIM);

    // ---- geglu FFN ----
    ln_kernel<<<dim3(ROWS), blk, 0, stream>>>(out, n3w, n3b, nh);
    gemm_mfma<2><<<dim3(INNER / 128, ROWS / 128), blk, 0, stream>>>(
        nh, DIM, ffw1, 2 * INNER, Pb, INNER, ffb1, nullptr, 0, ROWS, INNER, DIM);
    outproj(Pb, INNER, ffw2, ffb2, out, INNER);

    // ---- temporal self-attention ----
    ln_kernel<<<dim3(ROWS), blk, 0, stream>>>(out, ntw, ntb, nh);
    proj(nh, DIM, atwq, DIM, qb, DIM, ROWS, DIM, DIM);
    proj(nh, DIM, atwk, DIM, kb, DIM, ROWS, DIM, DIM);
    proj(nh, DIM, atwv, DIM, vb, DIM, ROWS, DIM, DIM);
    attnt_kernel<<<dim3(FRAMES, HEADS, BATCH * TOK), blk, 0, stream>>>(qb, kb, vb, ob);
    outproj(ob, DIM, atwo, atbo, out, DIM);
}

// Round 2
// 2414.441 us; speedup vs baseline: 2.1702x; 1.3596x over previous
//
#include <hip/hip_runtime.h>
#include <hip/hip_bf16.h>
#include <math.h>

// ---- problem constants (from reference) ----
#define DIM    1280
#define HEADS  8
#define DH     160            // DIM / HEADS
#define FRAMES 16
#define BATCH  2
#define TOK    256
#define ESEQ   77
#define INNER  5120           // 4*DIM
#define CROSS  768
#define BF     (BATCH*FRAMES) // 32
#define ROWS   (BF*TOK)       // 8192
#define EROWS  (BF*ESEQ)      // 2464
#define EPAD   2560           // EROWS padded to %128

typedef __hip_bfloat16 bf16;
typedef __attribute__((ext_vector_type(8))) short s8v;
typedef __attribute__((ext_vector_type(4))) short s4v;
typedef __attribute__((ext_vector_type(4))) float f4v;

__device__ __forceinline__ float b2f(bf16 x) { return __bfloat162float(x); }
__device__ __forceinline__ bf16  f2b(float x) { return __float2bfloat16(x); }
// f32 -> bf16 bits (RNE), as short
__device__ __forceinline__ short f2s(float x) {
    union { float f; unsigned int u; } c; c.f = x;
    unsigned int r = c.u + 0x7FFF + ((c.u >> 16) & 1);
    return (short)(r >> 16);
}
__device__ __forceinline__ void load4(const float* p, float* d) {
    float4 v = *(const float4*)p; d[0] = v.x; d[1] = v.y; d[2] = v.z; d[3] = v.w;
}
// async global->LDS, 16B per lane; LDS dest is wave-uniform base + lane*16
__device__ __forceinline__ void gl_lds16(const bf16* g, short* l) {
    __builtin_amdgcn_global_load_lds(
        (const __attribute__((address_space(1))) void*)g,
        (__attribute__((address_space(3))) void*)l, 16, 0, 0);
}

// ---- LayerNorm: one block per row of DIM=1280 (256 thr x 5 elems) ----
__global__ __launch_bounds__(256) void ln_kernel(const float* __restrict__ x,
                                                 const float* __restrict__ w,
                                                 const float* __restrict__ b,
                                                 bf16* __restrict__ out) {
    __shared__ float r1[256], r2[256];
    int row = blockIdx.x, t = threadIdx.x;
    const float* xp = x + (size_t)row * DIM;
    float v[5], s = 0.f, s2 = 0.f;
#pragma unroll
    for (int i = 0; i < 5; i++) {
        float xv = xp[t + 256 * i];
        v[i] = xv; s += xv; s2 += xv * xv;
    }
    r1[t] = s; r2[t] = s2; __syncthreads();
    for (int st = 128; st > 0; st >>= 1) {
        if (t < st) { r1[t] += r1[t + st]; r2[t] += r2[t + st]; }
        __syncthreads();
    }
    float mean = r1[0] * (1.f / DIM);
    float var  = r2[0] * (1.f / DIM) - mean * mean;
    float rstd = rsqrtf(var + 1e-5f);
    bf16* op = out + (size_t)row * DIM;
#pragma unroll
    for (int i = 0; i < 5; i++) {
        int c = t + 256 * i;
        op[c] = f2b((v[i] - mean) * rstd * w[c] + b[c]);
    }
}

// ---- transpose-convert: W f32 [K][N] -> Wt bf16 [N][K]; N,K % 64 == 0 ----
__global__ __launch_bounds__(256) void wconv_t(const float* __restrict__ w,
                                               bf16* __restrict__ wt,
                                               int N, int K) {
    __shared__ float tile[64][65];
    const int n0 = blockIdx.x * 64, k0 = blockIdx.y * 64;
    const int t = threadIdx.x;
    const int tr = t >> 4;          // 0..15
    const int tc = (t & 15) * 4;    // 0..60
#pragma unroll
    for (int i = 0; i < 4; i++) {
        int kk = tr + i * 16;
        float4 vv = *(const float4*)(w + (size_t)(k0 + kk) * N + n0 + tc);
        tile[kk][tc + 0] = vv.x; tile[kk][tc + 1] = vv.y;
        tile[kk][tc + 2] = vv.z; tile[kk][tc + 3] = vv.w;
    }
    __syncthreads();
#pragma unroll
    for (int i = 0; i < 4; i++) {
        int nn = tr + i * 16;
        s4v o4 = (s4v){ f2s(tile[tc + 0][nn]), f2s(tile[tc + 1][nn]),
                        f2s(tile[tc + 2][nn]), f2s(tile[tc + 3][nn]) };
        *(s4v*)(wt + (size_t)(n0 + nn) * K + k0 + tc) = o4;
    }
}

// ---- encoder f32 [EROWS][CROSS] -> bf16 [EPAD][CROSS], zero-padded rows ----
__global__ __launch_bounds__(256) void encconv(const float* __restrict__ e,
                                               bf16* __restrict__ eb) {
    int idx = blockIdx.x * 256 + threadIdx.x;   // 4 elems each
    int base = idx * 4;
    int row = base / CROSS;
    s4v o4;
    if (row < EROWS) {
        float4 vv = *(const float4*)(e + (size_t)base);
        o4 = (s4v){ f2s(vv.x), f2s(vv.y), f2s(vv.z), f2s(vv.w) };
    } else {
        o4 = (s4v){ 0, 0, 0, 0 };
    }
    *(s4v*)(eb + base) = o4;
}

// =====================================================================
// MFMA GEMM (new): C[M,N] = A[M,K](bf16) @ Bt[N,K](bf16, pre-transposed)
// 128x128 tile, BK=32, global_load_lds width-16 staging (linear LDS),
// 4 waves (each 64x64). EPI: 0 bf16 out; 1 f32 out = acc+bias+res;
// 2 geglu (G strip at Bt rows +INNER). M%128==0, N%128==0, K%32==0.
// =====================================================================
template <int EPI>
__global__ __launch_bounds__(256) void gemm_bt(
    const bf16* __restrict__ A, int lda,
    const bf16* __restrict__ Bt, int ldb,
    void* __restrict__ C, int ldc,
    const float* __restrict__ bias,
    const float* __restrict__ res, int ldres,
    int M, int N, int K) {
    __shared__ short A_lds[128 * 32];
    __shared__ short B_lds[128 * 32];
    __shared__ short G_lds[EPI == 2 ? 128 * 32 : 8];

    const int t = threadIdx.x;
    const int wid = t >> 6, lane = t & 63;
    const int lrow = lane & 15, lgrp = lane >> 4;
    const int m0 = blockIdx.y * 128, n0 = blockIdx.x * 128;
    const int wm = (wid & 1) * 64, wn = (wid >> 1) * 64;

    f4v acc[4][4], accg[4][4];
#pragma unroll
    for (int i = 0; i < 4; i++)
#pragma unroll
        for (int j = 0; j < 4; j++) {
            acc[i][j] = (f4v){0.f, 0.f, 0.f, 0.f};
            if (EPI == 2) accg[i][j] = (f4v){0.f, 0.f, 0.f, 0.f};
        }

    // staging geometry: wave w covers rows [w*32, w*32+32); lane -> row w*32+(l>>2),
    // 16B chunk (l&3). LDS dest linear: bytes w*2048 + lane*16 (+1024 for 2nd issue).
    const int srow = wid * 32 + (lane >> 2);
    const int scol = (lane & 3) * 8;            // shorts
    const bf16* Ag = A + (size_t)(m0 + srow) * lda + scol;
    const bf16* Bg = Bt + (size_t)(n0 + srow) * ldb + scol;
    const bf16* Gg = Bt + ((EPI == 2) ? ((size_t)(INNER + n0 + srow) * ldb + scol) : 0);
    short* Aw = &A_lds[wid * 1024];
    short* Bw = &B_lds[wid * 1024];
    short* Gw = &G_lds[(EPI == 2) ? wid * 1024 : 0];

    for (int k0 = 0; k0 < K; k0 += 32) {
        gl_lds16(Ag, Aw);
        gl_lds16(Ag + (size_t)16 * lda, Aw + 512);
        gl_lds16(Bg, Bw);
        gl_lds16(Bg + (size_t)16 * ldb, Bw + 512);
        if (EPI == 2) {
            gl_lds16(Gg, Gw);
            gl_lds16(Gg + (size_t)16 * ldb, Gw + 512);
        }
        Ag += 32; Bg += 32;
        if (EPI == 2) Gg += 32;
        __syncthreads();                        // drains vmcnt (compiler-inserted)

        s8v af[4], bfr[4];
#pragma unroll
        for (int i = 0; i < 4; i++)
            af[i] = *(const s8v*)&A_lds[(wm + i * 16 + lrow) * 32 + lgrp * 8];
#pragma unroll
        for (int j = 0; j < 4; j++)
            bfr[j] = *(const s8v*)&B_lds[(wn + j * 16 + lrow) * 32 + lgrp * 8];
#pragma unroll
        for (int i = 0; i < 4; i++)
#pragma unroll
            for (int j = 0; j < 4; j++)
                acc[i][j] = __builtin_amdgcn_mfma_f32_16x16x32_bf16(af[i], bfr[j], acc[i][j], 0, 0, 0);
        if (EPI == 2) {
            s8v gfr[4];
#pragma unroll
            for (int j = 0; j < 4; j++)
                gfr[j] = *(const s8v*)&G_lds[(wn + j * 16 + lrow) * 32 + lgrp * 8];
#pragma unroll
            for (int i = 0; i < 4; i++)
#pragma unroll
                for (int j = 0; j < 4; j++)
                    accg[i][j] = __builtin_amdgcn_mfma_f32_16x16x32_bf16(af[i], gfr[j], accg[i][j], 0, 0, 0);
        }
        __syncthreads();
    }

    // ---- epilogue: C/D layout col=lane&15, row=(lane>>4)*4+reg ----
#pragma unroll
    for (int i = 0; i < 4; i++) {
#pragma unroll
        for (int r = 0; r < 4; r++) {
            int m = m0 + wm + i * 16 + lgrp * 4 + r;
#pragma unroll
            for (int j = 0; j < 4; j++) {
                int n = n0 + wn + j * 16 + lrow;
                float v = acc[i][j][r];
                if (EPI == 0) {
                    ((bf16*)C)[(size_t)m * ldc + n] = f2b(v);
                } else if (EPI == 1) {
                    v += bias[n] + res[(size_t)m * ldres + n];
                    ((float*)C)[(size_t)m * ldc + n] = v;
                } else {
                    float p = v + bias[n];
                    float g = accg[i][j][r] + bias[INNER + n];
                    float gl = 0.5f * g * (1.f + erff(g * 0.70710678118654752f));
                    ((bf16*)C)[(size_t)m * ldc + n] = f2b(p * gl);
                }
            }
        }
    }
}

// =====================================================================
// LEGACY kernels (fallback when workspace is too small for weight scratch)
// =====================================================================
template <int EPI>
__global__ __launch_bounds__(256) void gemm_mfma(
    const bf16* __restrict__ A, int lda,
    const float* __restrict__ B, int ldb,
    void* __restrict__ C, int ldc,
    const float* __restrict__ bias,
    const float* __restrict__ res, int ldres,
    int M, int N, int K) {
    constexpr int LR = 40;
    __shared__ short A_lds[128 * LR];
    __shared__ short B_lds[128 * LR];
    __shared__ short G_lds[EPI == 2 ? 128 * LR : 4];

    const int t    = threadIdx.x;
    const int wid  = t >> 6, lane = t & 63;
    const int lrow = lane & 15, lgrp = lane >> 4;
    const int m0   = blockIdx.y * 128, n0 = blockIdx.x * 128;
    const int wm   = (wid & 1) * 64, wn = (wid >> 1) * 64;

    f4v acc[4][4];
    f4v accg[4][4];
#pragma unroll
    for (int i = 0; i < 4; i++)
#pragma unroll
        for (int j = 0; j < 4; j++) {
            acc[i][j] = (f4v){0.f, 0.f, 0.f, 0.f};
            if (EPI == 2) accg[i][j] = (f4v){0.f, 0.f, 0.f, 0.f};
        }

    const int b_np = (t & 31) * 4;
    const int b_kp = (t >> 5) * 4;

    for (int k0 = 0; k0 < K; k0 += 32) {
#pragma unroll
        for (int c = 0; c < 2; c++) {
            int idx = t + c * 256;
            int row = idx >> 2, g = (idx & 3) * 8;
            uint4 v = *(const uint4*)(A + (size_t)(m0 + row) * lda + k0 + g);
            *(uint4*)&A_lds[row * LR + g] = v;
        }
        {
            const float* bp = B + (size_t)(k0 + b_kp) * ldb + n0 + b_np;
            float4 r0 = *(const float4*)(bp);
            float4 r1 = *(const float4*)(bp + ldb);
            float4 r2 = *(const float4*)(bp + 2 * ldb);
            float4 r3 = *(const float4*)(bp + 3 * ldb);
            *(s4v*)&B_lds[(b_np + 0) * LR + b_kp] = (s4v){f2s(r0.x), f2s(r1.x), f2s(r2.x), f2s(r3.x)};
            *(s4v*)&B_lds[(b_np + 1) * LR + b_kp] = (s4v){f2s(r0.y), f2s(r1.y), f2s(r2.y), f2s(r3.y)};
            *(s4v*)&B_lds[(b_np + 2) * LR + b_kp] = (s4v){f2s(r0.z), f2s(r1.z), f2s(r2.z), f2s(r3.z)};
            *(s4v*)&B_lds[(b_np + 3) * LR + b_kp] = (s4v){f2s(r0.w), f2s(r1.w), f2s(r2.w), f2s(r3.w)};
        }
        if (EPI == 2) {
            const float* gp = B + (size_t)(k0 + b_kp) * ldb + INNER + n0 + b_np;
            float4 r0 = *(const float4*)(gp);
            float4 r1 = *(const float4*)(gp + ldb);
            float4 r2 = *(const float4*)(gp + 2 * ldb);
            float4 r3 = *(const float4*)(gp + 3 * ldb);
            *(s4v*)&G_lds[(b_np + 0) * LR + b_kp] = (s4v){f2s(r0.x), f2s(r1.x), f2s(r2.x), f2s(r3.x)};
            *(s4v*)&G_lds[(b_np + 1) * LR + b_kp] = (s4v){f2s(r0.y), f2s(r1.y), f2s(r2.y), f2s(r3.y)};
            *(s4v*)&G_lds[(b_np + 2) * LR + b_kp] = (s4v){f2s(r0.z), f2s(r1.z), f2s(r2.z), f2s(r3.z)};
            *(s4v*)&G_lds[(b_np + 3) * LR + b_kp] = (s4v){f2s(r0.w), f2s(r1.w), f2s(r2.w), f2s(r3.w)};
        }
        __syncthreads();
        s8v af[4], bfr[4];
#pragma unroll
        for (int i = 0; i < 4; i++)
            af[i] = *(const s8v*)&A_lds[(wm + i * 16 + lrow) * LR + lgrp * 8];
#pragma unroll
        for (int j = 0; j < 4; j++)
            bfr[j] = *(const s8v*)&B_lds[(wn + j * 16 + lrow) * LR + lgrp * 8];
#pragma unroll
        for (int i = 0; i < 4; i++)
#pragma unroll
            for (int j = 0; j < 4; j++)
                acc[i][j] = __builtin_amdgcn_mfma_f32_16x16x32_bf16(af[i], bfr[j], acc[i][j], 0, 0, 0);
        if (EPI == 2) {
            s8v gfr[4];
#pragma unroll
            for (int j = 0; j < 4; j++)
                gfr[j] = *(const s8v*)&G_lds[(wn + j * 16 + lrow) * LR + lgrp * 8];
#pragma unroll
            for (int i = 0; i < 4; i++)
#pragma unroll
                for (int j = 0; j < 4; j++)
                    accg[i][j] = __builtin_amdgcn_mfma_f32_16x16x32_bf16(af[i], gfr[j], accg[i][j], 0, 0, 0);
        }
        __syncthreads();
    }
#pragma unroll
    for (int i = 0; i < 4; i++) {
#pragma unroll
        for (int r = 0; r < 4; r++) {
            int m = m0 + wm + i * 16 + lgrp * 4 + r;
#pragma unroll
            for (int j = 0; j < 4; j++) {
                int n = n0 + wn + j * 16 + lrow;
                float v = acc[i][j][r];
                if (EPI == 0) {
                    ((bf16*)C)[(size_t)m * ldc + n] = f2b(v);
                } else if (EPI == 1) {
                    v += bias[n] + res[(size_t)m * ldres + n];
                    ((float*)C)[(size_t)m * ldc + n] = v;
                } else {
                    float p = v + bias[n];
                    float g = accg[i][j][r] + bias[INNER + n];
                    float gl = 0.5f * g * (1.f + erff(g * 0.70710678118654752f));
                    ((bf16*)C)[(size_t)m * ldc + n] = f2b(p * gl);
                }
            }
        }
    }
}

__global__ __launch_bounds__(256) void gemm_valu(
    const float* __restrict__ A, int lda,
    const float* __restrict__ B, int ldb,
    bf16* __restrict__ C, int ldc,
    int M, int N, int K) {
    __shared__ float As[16][65];
    __shared__ float Bs[16][65];
    const int t  = threadIdx.x;
    const int m0 = blockIdx.y * 64, n0 = blockIdx.x * 64;
    const int ar = t >> 2, ak = (t & 3) * 4;
    const int bk = t >> 4, bn = (t & 15) * 4;
    const int ty = t >> 4, tx = t & 15;
    float acc[4][4];
#pragma unroll
    for (int i = 0; i < 4; i++)
#pragma unroll
        for (int j = 0; j < 4; j++) acc[i][j] = 0.f;

    for (int k0 = 0; k0 < K; k0 += 16) {
        {
            int m = m0 + ar;
            float tmp[4];
            if (m < M) load4(A + (size_t)m * lda + k0 + ak, tmp);
            else { tmp[0] = tmp[1] = tmp[2] = tmp[3] = 0.f; }
            As[ak + 0][ar] = tmp[0]; As[ak + 1][ar] = tmp[1];
            As[ak + 2][ar] = tmp[2]; As[ak + 3][ar] = tmp[3];
        }
        {
            float tmp[4];
            load4(B + (size_t)(k0 + bk) * ldb + n0 + bn, tmp);
            Bs[bk][bn + 0] = tmp[0]; Bs[bk][bn + 1] = tmp[1];
            Bs[bk][bn + 2] = tmp[2]; Bs[bk][bn + 3] = tmp[3];
        }
        __syncthreads();
#pragma unroll
        for (int k = 0; k < 16; k++) {
            float a[4], b[4];
#pragma unroll
            for (int i = 0; i < 4; i++) a[i] = As[k][ty * 4 + i];
#pragma unroll
            for (int j = 0; j < 4; j++) b[j] = Bs[k][tx * 4 + j];
#pragma unroll
            for (int i = 0; i < 4; i++)
#pragma unroll
                for (int j = 0; j < 4; j++) acc[i][j] += a[i] * b[j];
        }
        __syncthreads();
    }
#pragma unroll
    for (int i = 0; i < 4; i++) {
        int m = m0 + ty * 4 + i;
        if (m >= M) continue;
#pragma unroll
        for (int j = 0; j < 4; j++) {
            int n = n0 + tx * 4 + j;
            C[(size_t)m * ldc + n] = f2b(acc[i][j]);
        }
    }
}

#define SOFTMAX_SCALE 0.07905694150420949f  // 1/sqrt(160)

// =====================================================================
// attn1 (sparse-causal, 512 keys) — MFMA flash-attention.
// =====================================================================
#define A1_KP 168   // K LDS pitch (shorts): 160 + 8 pad
#define A1_VP 72    // V^T pitch (shorts):   64 + 8 pad
#define A1_PP 72    // P  pitch (shorts)

__global__ __launch_bounds__(256) void attn1_mfma(const bf16* __restrict__ q,
                                                  const bf16* __restrict__ k,
                                                  const bf16* __restrict__ v,
                                                  bf16* __restrict__ o) {
    __shared__ short K_lds[64 * A1_KP];
    __shared__ short Vt_lds[160 * A1_VP];
    __shared__ short P_lds[4 * 16 * A1_PP];

    const int t = threadIdx.x;
    const int wid = t >> 6, lane = t & 63;
    const int lrow = lane & 15, lgrp = lane >> 4;
    const int bx = blockIdx.x, hd = blockIdx.y, bfi = blockIdx.z;
    const int bi = bfi >> 4, fi = bfi & 15;
    const int former = fi > 0 ? fi - 1 : 0;
    const int qbase = bfi * TOK + bx * 64 + wid * 16;

    s8v qf[5];
    {
        const bf16* qp = q + (size_t)(qbase + lrow) * DIM + hd * DH + lgrp * 8;
#pragma unroll
        for (int ks = 0; ks < 5; ks++)
            qf[ks] = *(const s8v*)(qp + ks * 32);
    }

    f4v oacc[10];
#pragma unroll
    for (int dg = 0; dg < 10; dg++) oacc[dg] = (f4v){0.f, 0.f, 0.f, 0.f};
    float m_run[4], l_run[4];
#pragma unroll
    for (int r = 0; r < 4; r++) { m_run[r] = -1e30f; l_run[r] = 0.f; }

    short* P_w = P_lds + wid * 16 * A1_PP;

    for (int c = 0; c < 8; c++) {
        const int kf = (c < 4) ? 0 : former;
        const size_t krow0 = (size_t)(bi * FRAMES + kf) * TOK + (c & 3) * 64;

        __syncthreads();
#pragma unroll
        for (int it = 0; it < 5; it++) {
            int idx = t + it * 256;
            int jr = idx / 20, g = idx % 20;
            const bf16* kp = k + (krow0 + jr) * DIM + hd * DH + g * 8;
            *(uint4*)&K_lds[jr * A1_KP + g * 8] = *(const uint4*)kp;
            s8v vv = *(const s8v*)(v + (krow0 + jr) * DIM + hd * DH + g * 8);
#pragma unroll
            for (int i = 0; i < 8; i++) {
                int d = g * 8 + i;
                Vt_lds[d * A1_VP + (jr ^ (d & 56))] = vv[i];
            }
        }
        __syncthreads();

        f4v sacc[4];
#pragma unroll
        for (int kg = 0; kg < 4; kg++) {
            sacc[kg] = (f4v){0.f, 0.f, 0.f, 0.f};
#pragma unroll
            for (int ks = 0; ks < 5; ks++) {
                s8v kfr = *(const s8v*)&K_lds[(kg * 16 + lrow) * A1_KP + ks * 32 + lgrp * 8];
                sacc[kg] = __builtin_amdgcn_mfma_f32_16x16x32_bf16(qf[ks], kfr, sacc[kg], 0, 0, 0);
            }
        }

        float mc[4];
#pragma unroll
        for (int r = 0; r < 4; r++) {
            float mm = fmaxf(fmaxf(sacc[0][r], sacc[1][r]), fmaxf(sacc[2][r], sacc[3][r]));
            mc[r] = mm * SOFTMAX_SCALE;
        }
#pragma unroll
        for (int x = 1; x < 16; x <<= 1)
#pragma unroll
            for (int r = 0; r < 4; r++)
                mc[r] = fmaxf(mc[r], __shfl_xor(mc[r], x));

        float p[4][4], rs[4];
#pragma unroll
        for (int r = 0; r < 4; r++) {
            float mn = fmaxf(m_run[r], mc[r]);
            float sc = __expf(m_run[r] - mn);
            m_run[r] = mn;
            l_run[r] *= sc;
#pragma unroll
            for (int dg = 0; dg < 10; dg++) oacc[dg][r] *= sc;
            float acc = 0.f;
#pragma unroll
            for (int kg = 0; kg < 4; kg++) {
                float e = __expf(sacc[kg][r] * SOFTMAX_SCALE - mn);
                p[kg][r] = e; acc += e;
            }
            rs[r] = acc;
        }
#pragma unroll
        for (int x = 1; x < 16; x <<= 1)
#pragma unroll
            for (int r = 0; r < 4; r++)
                rs[r] += __shfl_xor(rs[r], x);
#pragma unroll
        for (int r = 0; r < 4; r++) l_run[r] += rs[r];

#pragma unroll
        for (int kg = 0; kg < 4; kg++)
#pragma unroll
            for (int r = 0; r < 4; r++)
                P_w[(lgrp * 4 + r) * A1_PP + kg * 16 + lrow] = f2s(p[kg][r]);
        __syncthreads();

        s8v pa[2];
#pragma unroll
        for (int ks2 = 0; ks2 < 2; ks2++)
            pa[ks2] = *(const s8v*)&P_w[lrow * A1_PP + ks2 * 32 + lgrp * 8];
#pragma unroll
        for (int dg = 0; dg < 10; dg++) {
            int dd = dg * 16 + lrow;
#pragma unroll
            for (int ks2 = 0; ks2 < 2; ks2++) {
                s8v vfr = *(const s8v*)&Vt_lds[dd * A1_VP + ((ks2 * 32 + lgrp * 8) ^ (dd & 56))];
                oacc[dg] = __builtin_amdgcn_mfma_f32_16x16x32_bf16(pa[ks2], vfr, oacc[dg], 0, 0, 0);
            }
        }
    }

    float invl[4];
#pragma unroll
    for (int r = 0; r < 4; r++) invl[r] = 1.f / l_run[r];
#pragma unroll
    for (int dg = 0; dg < 10; dg++) {
#pragma unroll
        for (int r = 0; r < 4; r++) {
            int qq = qbase + lgrp * 4 + r;
            o[(size_t)qq * DIM + hd * DH + dg * 16 + lrow] = f2b(oacc[dg][r] * invl[r]);
        }
    }
}

// ---- attn2: cross-attention, 77 keys ----
__global__ __launch_bounds__(256) void attn2_kernel(const bf16* __restrict__ q,
                                                    const bf16* __restrict__ k,
                                                    const bf16* __restrict__ v,
                                                    bf16* __restrict__ o) {
    __shared__ float sQ[DH];
    __shared__ float sS[128];
    __shared__ float red[256];
    int t = threadIdx.x;
    int qi = blockIdx.x, hd = blockIdx.y, bfi = blockIdx.z;
    size_t qbase = ((size_t)(bfi * TOK + qi)) * DIM + hd * DH;
    if (t < DH) sQ[t] = b2f(q[qbase + t]);
    __syncthreads();
    if (t < ESEQ) {
        size_t kbase = ((size_t)(bfi * ESEQ + t)) * DIM + hd * DH;
        float acc = 0.f;
        for (int d = 0; d < DH; d++) acc += sQ[d] * b2f(k[kbase + d]);
        sS[t] = acc * SOFTMAX_SCALE;
    }
    __syncthreads();
    float lm = (t < ESEQ) ? sS[t] : -1e30f;
    red[t] = lm; __syncthreads();
    for (int s = 128; s > 0; s >>= 1) { if (t < s) red[t] = fmaxf(red[t], red[t + s]); __syncthreads(); }
    float mx = red[0]; __syncthreads();
    float ls = 0.f;
    if (t < ESEQ) { float e = __expf(sS[t] - mx); sS[t] = e; ls = e; }
    red[t] = ls; __syncthreads();
    for (int s = 128; s > 0; s >>= 1) { if (t < s) red[t] += red[t + s]; __syncthreads(); }
    float inv = 1.f / red[0];
    __syncthreads();
    if (t < DH) {
        float acc = 0.f;
        for (int j = 0; j < ESEQ; j++) {
            size_t vbase = ((size_t)(bfi * ESEQ + j)) * DIM + hd * DH;
            acc += sS[j] * b2f(v[vbase + t]);
        }
        o[qbase + t] = f2b(acc * inv);
    }
}

// ---- temporal self-attn: 16 keys (frames) per (batch, token) ----
__global__ __launch_bounds__(256) void attnt_kernel(const bf16* __restrict__ q,
                                                    const bf16* __restrict__ k,
                                                    const bf16* __restrict__ v,
                                                    bf16* __restrict__ o) {
    __shared__ float sQ[DH];
    __shared__ float sS[16];
    __shared__ float red[256];
    int t = threadIdx.x;
    int qfi = blockIdx.x, hd = blockIdx.y, z = blockIdx.z;
    int bi = z >> 8, ti = z & 255;
    size_t qbase = ((size_t)((bi * FRAMES + qfi) * TOK + ti)) * DIM + hd * DH;
    if (t < DH) sQ[t] = b2f(q[qbase + t]);
    __syncthreads();
    if (t < FRAMES) {
        size_t kbase = ((size_t)((bi * FRAMES + t) * TOK + ti)) * DIM + hd * DH;
        float acc = 0.f;
        for (int d = 0; d < DH; d++) acc += sQ[d] * b2f(k[kbase + d]);
        sS[t] = acc * SOFTMAX_SCALE;
    }
    __syncthreads();
    float lm = (t < FRAMES) ? sS[t] : -1e30f;
    red[t] = lm; __syncthreads();
    for (int s = 128; s > 0; s >>= 1) { if (t < s) red[t] = fmaxf(red[t], red[t + s]); __syncthreads(); }
    float mx = red[0]; __syncthreads();
    float ls = 0.f;
    if (t < FRAMES) { float e = __expf(sS[t] - mx); sS[t] = e; ls = e; }
    red[t] = ls; __syncthreads();
    for (int s = 128; s > 0; s >>= 1) { if (t < s) red[t] += red[t + s]; __syncthreads(); }
    float inv = 1.f / red[0];
    __syncthreads();
    if (t < DH) {
        float acc = 0.f;
        for (int j = 0; j < FRAMES; j++) {
            size_t vbase = ((size_t)((bi * FRAMES + j) * TOK + ti)) * DIM + hd * DH;
            acc += sS[j] * b2f(v[vbase + t]);
        }
        o[qbase + t] = f2b(acc * inv);
    }
}

extern "C" void kernel_launch(void* const* d_in, const int* in_sizes, int n_in,
                              void* d_out, int out_size, void* d_ws, size_t ws_size,
                              hipStream_t stream) {
    (void)in_sizes; (void)n_in; (void)out_size;
    const float* hs   = (const float*)d_in[0];
    const float* enc  = (const float*)d_in[1];
    const float* n1w  = (const float*)d_in[2];
    const float* n1b  = (const float*)d_in[3];
    const float* a1wq = (const float*)d_in[4];
    const float* a1wk = (const float*)d_in[5];
    const float* a1wv = (const float*)d_in[6];
    const float* a1wo = (const float*)d_in[7];
    const float* a1bo = (const float*)d_in[8];
    const float* n2w  = (const float*)d_in[9];
    const float* n2b  = (const float*)d_in[10];
    const float* a2wq = (const float*)d_in[11];
    const float* a2wk = (const float*)d_in[12];
    const float* a2wv = (const float*)d_in[13];
    const float* a2wo = (const float*)d_in[14];
    const float* a2bo = (const float*)d_in[15];
    const float* n3w  = (const float*)d_in[16];
    const float* n3b  = (const float*)d_in[17];
    const float* ffw1 = (const float*)d_in[18];
    const float* ffb1 = (const float*)d_in[19];
    const float* ffw2 = (const float*)d_in[20];
    const float* ffb2 = (const float*)d_in[21];
    const float* ntw  = (const float*)d_in[22];
    const float* ntb  = (const float*)d_in[23];
    const float* atwq = (const float*)d_in[24];
    const float* atwk = (const float*)d_in[25];
    const float* atwv = (const float*)d_in[26];
    const float* atwo = (const float*)d_in[27];
    const float* atbo = (const float*)d_in[28];

    char* wp = (char*)d_ws;
    auto carve = [&](size_t bytes) -> char* {
        char* p = wp; wp += (bytes + 255) & ~((size_t)255); return p;
    };
    const size_t BUF = (size_t)ROWS * DIM * 2;   // 20,971,520
    bf16* nh = (bf16*)carve(BUF);
    bf16* qb = (bf16*)carve(BUF);
    bf16* kb = (bf16*)carve(BUF);
    bf16* vb = (bf16*)carve(BUF);
    bf16* ob = (bf16*)carve(BUF);
    bf16* Pb = qb;                 // FFN intermediate aliases qb..ob
    float* out = (float*)d_out;    // f32 residual stream lives in d_out

    dim3 blk(256);

    const size_t W_FULL = 26214400;   // ffw1t: 10240x1280 bf16
    const size_t W_MID  = 14417920;   // attn2 set
    size_t avail = (ws_size > 5 * BUF) ? ws_size - 5 * BUF : 0;
    int tier = (avail >= W_FULL + 256) ? 2 : ((avail >= W_MID + 256) ? 1 : 0);

    if (tier == 0) {
        // ------- legacy path (R1 kernel, known-good at 105 MB ws) -------
        auto proj = [&](const bf16* A, int lda, const float* B, int ldb,
                        bf16* C, int ldc, int M, int N, int K) {
            gemm_mfma<0><<<dim3(N / 128, M / 128), blk, 0, stream>>>(
                A, lda, B, ldb, C, ldc, nullptr, nullptr, 0, M, N, K);
        };
        auto outproj = [&](const bf16* A, int lda, const float* B,
                           const float* bias, const float* res, int K) {
            gemm_mfma<1><<<dim3(DIM / 128, ROWS / 128), blk, 0, stream>>>(
                A, lda, B, DIM, out, DIM, bias, res, DIM, ROWS, DIM, K);
        };
        ln_kernel<<<dim3(ROWS), blk, 0, stream>>>(hs, n1w, n1b, nh);
        proj(nh, DIM, a1wq, DIM, qb, DIM, ROWS, DIM, DIM);
        proj(nh, DIM, a1wk, DIM, kb, DIM, ROWS, DIM, DIM);
        proj(nh, DIM, a1wv, DIM, vb, DIM, ROWS, DIM, DIM);
        attn1_mfma<<<dim3(TOK / 64, HEADS, BF), blk, 0, stream>>>(qb, kb, vb, ob);
        outproj(ob, DIM, a1wo, a1bo, hs, DIM);

        ln_kernel<<<dim3(ROWS), blk, 0, stream>>>(out, n2w, n2b, nh);
        proj(nh, DIM, a2wq, DIM, qb, DIM, ROWS, DIM, DIM);
        gemm_valu<<<dim3(DIM / 64, (EROWS + 63) / 64), blk, 0, stream>>>(enc, CROSS, a2wk, DIM, kb, DIM, EROWS, DIM, CROSS);
        gemm_valu<<<dim3(DIM / 64, (EROWS + 63) / 64), blk, 0, stream>>>(enc, CROSS, a2wv, DIM, vb, DIM, EROWS, DIM, CROSS);
        attn2_kernel<<<dim3(TOK, HEADS, BF), blk, 0, stream>>>(qb, kb, vb, ob);
        outproj(ob, DIM, a2wo, a2bo, out, DIM);

        ln_kernel<<<dim3(ROWS), blk, 0, stream>>>(out, n3w, n3b, nh);
        gemm_mfma<2><<<dim3(INNER / 128, ROWS / 128), blk, 0, stream>>>(
            nh, DIM, ffw1, 2 * INNER, Pb, INNER, ffb1, nullptr, 0, ROWS, INNER, DIM);
        outproj(Pb, INNER, ffw2, ffb2, out, INNER);

        ln_kernel<<<dim3(ROWS), blk, 0, stream>>>(out, ntw, ntb, nh);
        proj(nh, DIM, atwq, DIM, qb, DIM, ROWS, DIM, DIM);
        proj(nh, DIM, atwk, DIM, kb, DIM, ROWS, DIM, DIM);
        proj(nh, DIM, atwv, DIM, vb, DIM, ROWS, DIM, DIM);
        attnt_kernel<<<dim3(FRAMES, HEADS, BATCH * TOK), blk, 0, stream>>>(qb, kb, vb, ob);
        outproj(ob, DIM, atwo, atbo, out, DIM);
        return;
    }

    // ------- new path: pre-converted bf16 B^T weights + global_load_lds GEMM -------
    bf16* Ws = (bf16*)carve(tier == 2 ? W_FULL : W_MID);
    const size_t WQ = (size_t)DIM * DIM;     // 1,638,400 elems
    const size_t WC = (size_t)DIM * CROSS;   //   983,040 elems

    auto convW = [&](const float* w, bf16* wt, int N, int K) {
        wconv_t<<<dim3(N / 64, K / 64), blk, 0, stream>>>(w, wt, N, K);
    };
    auto projN = [&](const bf16* A, int lda, const bf16* Bt, int ldb,
                     bf16* C, int ldc, int M, int N, int K) {
        gemm_bt<0><<<dim3(N / 128, M / 128), blk, 0, stream>>>(
            A, lda, Bt, ldb, C, ldc, nullptr, nullptr, 0, M, N, K);
    };
    auto outprojN = [&](const bf16* A, int lda, const bf16* Bt, int ldb,
                        const float* bias, const float* res, int K) {
        gemm_bt<1><<<dim3(DIM / 128, ROWS / 128), blk, 0, stream>>>(
            A, lda, Bt, ldb, out, DIM, bias, res, DIM, ROWS, DIM, K);
    };

    // ---- attn1: sparse-causal self-attention ----
    convW(a1wq, Ws,          DIM, DIM);
    convW(a1wk, Ws + WQ,     DIM, DIM);
    convW(a1wv, Ws + 2 * WQ, DIM, DIM);
    convW(a1wo, Ws + 3 * WQ, DIM, DIM);
    ln_kernel<<<dim3(ROWS), blk, 0, stream>>>(hs, n1w, n1b, nh);
    projN(nh, DIM, Ws,          DIM, qb, DIM, ROWS, DIM, DIM);
    projN(nh, DIM, Ws + WQ,     DIM, kb, DIM, ROWS, DIM, DIM);
    projN(nh, DIM, Ws + 2 * WQ, DIM, vb, DIM, ROWS, DIM, DIM);
    attn1_mfma<<<dim3(TOK / 64, HEADS, BF), blk, 0, stream>>>(qb, kb, vb, ob);
    outprojN(ob, DIM, Ws + 3 * WQ, DIM, a1bo, hs, DIM);

    // ---- attn2: cross-attention ----
    {
        bf16* w2q  = Ws;
        bf16* w2k  = Ws + WQ;
        bf16* w2v  = w2k + WC;
        bf16* w2o  = w2v + WC;
        bf16* encb = w2o + WQ;                 // [EPAD][CROSS]
        convW(a2wq, w2q, DIM, DIM);
        convW(a2wk, w2k, DIM, CROSS);
        convW(a2wv, w2v, DIM, CROSS);
        convW(a2wo, w2o, DIM, DIM);
        encconv<<<dim3(EPAD * CROSS / 1024), blk, 0, stream>>>(enc, encb);
        ln_kernel<<<dim3(ROWS), blk, 0, stream>>>(out, n2w, n2b, nh);
        projN(nh, DIM, w2q, DIM, qb, DIM, ROWS, DIM, DIM);
        projN(encb, CROSS, w2k, CROSS, kb, DIM, EPAD, DIM, CROSS);
        projN(encb, CROSS, w2v, CROSS, vb, DIM, EPAD, DIM, CROSS);
        attn2_kernel<<<dim3(TOK, HEADS, BF), blk, 0, stream>>>(qb, kb, vb, ob);
        outprojN(ob, DIM, w2o, DIM, a2bo, out, DIM);
    }

    // ---- geglu FFN ----
    if (tier == 2) {
        convW(ffw1, Ws, 2 * INNER, DIM);       // [10240][1280] bf16
        ln_kernel<<<dim3(ROWS), blk, 0, stream>>>(out, n3w, n3b, nh);
        gemm_bt<2><<<dim3(INNER / 128, ROWS / 128), blk, 0, stream>>>(
            nh, DIM, Ws, DIM, Pb, INNER, ffb1, nullptr, 0, ROWS, INNER, DIM);
        convW(ffw2, Ws, DIM, INNER);           // [1280][5120] bf16
        gemm_bt<1><<<dim3(DIM / 128, ROWS / 128), blk, 0, stream>>>(
            Pb, INNER, Ws, INNER, out, DIM, ffb2, out, DIM, ROWS, DIM, INNER);
    } else {
        ln_kernel<<<dim3(ROWS), blk, 0, stream>>>(out, n3w, n3b, nh);
        gemm_mfma<2><<<dim3(INNER / 128, ROWS / 128), blk, 0, stream>>>(
            nh, DIM, ffw1, 2 * INNER, Pb, INNER, ffb1, nullptr, 0, ROWS, INNER, DIM);
        gemm_mfma<1><<<dim3(DIM / 128, ROWS / 128), blk, 0, stream>>>(
            Pb, INNER, ffw2, DIM, out, DIM, ffb2, out, DIM, ROWS, DIM, INNER);
    }

    // ---- temporal self-attention ----
    convW(atwq, Ws,          DIM, DIM);
    convW(atwk, Ws + WQ,     DIM, DIM);
    convW(atwv, Ws + 2 * WQ, DIM, DIM);
    convW(atwo, Ws + 3 * WQ, DIM, DIM);
    ln_kernel<<<dim3(ROWS), blk, 0, stream>>>(out, ntw, ntb, nh);
    projN(nh, DIM, Ws,          DIM, qb, DIM, ROWS, DIM, DIM);
    projN(nh, DIM, Ws + WQ,     DIM, kb, DIM, ROWS, DIM, DIM);
    projN(nh, DIM, Ws + 2 * WQ, DIM, vb, DIM, ROWS, DIM, DIM);
    attnt_kernel<<<dim3(FRAMES, HEADS, BATCH * TOK), blk, 0, stream>>>(qb, kb, vb, ob);
    outprojN(ob, DIM, Ws + 3 * WQ, DIM, atbo, out, DIM);
}

// Round 3
// 1603.536 us; speedup vs baseline: 3.2677x; 1.5057x over previous
//
#include <hip/hip_runtime.h>
#include <hip/hip_bf16.h>
#include <math.h>

// ---- problem constants (from reference) ----
#define DIM    1280
#define HEADS  8
#define DH     160            // DIM / HEADS
#define FRAMES 16
#define BATCH  2
#define TOK    256
#define ESEQ   77
#define INNER  5120           // 4*DIM
#define CROSS  768
#define BF     (BATCH*FRAMES) // 32
#define ROWS   (BF*TOK)       // 8192
#define EROWS  (BF*ESEQ)      // 2464
#define EPAD   2560           // EROWS padded to %128

typedef __hip_bfloat16 bf16;
typedef __attribute__((ext_vector_type(8))) short s8v;
typedef __attribute__((ext_vector_type(4))) short s4v;
typedef __attribute__((ext_vector_type(4))) float f4v;

__device__ __forceinline__ float b2f(bf16 x) { return __bfloat162float(x); }
__device__ __forceinline__ bf16  f2b(float x) { return __float2bfloat16(x); }
// f32 -> bf16 bits (RNE), as short
__device__ __forceinline__ short f2s(float x) {
    union { float f; unsigned int u; } c; c.f = x;
    unsigned int r = c.u + 0x7FFF + ((c.u >> 16) & 1);
    return (short)(r >> 16);
}
__device__ __forceinline__ void load4(const float* p, float* d) {
    float4 v = *(const float4*)p; d[0] = v.x; d[1] = v.y; d[2] = v.z; d[3] = v.w;
}
// async global->LDS, 16B per lane; LDS dest is wave-uniform base + lane*16
__device__ __forceinline__ void gl_lds16(const bf16* g, short* l) {
    __builtin_amdgcn_global_load_lds(
        (const __attribute__((address_space(1))) void*)g,
        (__attribute__((address_space(3))) void*)l, 16, 0, 0);
}

// ---- LayerNorm: one block per row of DIM=1280 (256 thr x 5 elems) ----
__global__ __launch_bounds__(256) void ln_kernel(const float* __restrict__ x,
                                                 const float* __restrict__ w,
                                                 const float* __restrict__ b,
                                                 bf16* __restrict__ out) {
    __shared__ float r1[256], r2[256];
    int row = blockIdx.x, t = threadIdx.x;
    const float* xp = x + (size_t)row * DIM;
    float v[5], s = 0.f, s2 = 0.f;
#pragma unroll
    for (int i = 0; i < 5; i++) {
        float xv = xp[t + 256 * i];
        v[i] = xv; s += xv; s2 += xv * xv;
    }
    r1[t] = s; r2[t] = s2; __syncthreads();
    for (int st = 128; st > 0; st >>= 1) {
        if (t < st) { r1[t] += r1[t + st]; r2[t] += r2[t + st]; }
        __syncthreads();
    }
    float mean = r1[0] * (1.f / DIM);
    float var  = r2[0] * (1.f / DIM) - mean * mean;
    float rstd = rsqrtf(var + 1e-5f);
    bf16* op = out + (size_t)row * DIM;
#pragma unroll
    for (int i = 0; i < 5; i++) {
        int c = t + 256 * i;
        op[c] = f2b((v[i] - mean) * rstd * w[c] + b[c]);
    }
}

// ---- transpose-convert: W f32 [K][N] -> Wt bf16 [N][K]; N,K % 64 == 0 ----
__global__ __launch_bounds__(256) void wconv_t(const float* __restrict__ w,
                                               bf16* __restrict__ wt,
                                               int N, int K) {
    __shared__ float tile[64][65];
    const int n0 = blockIdx.x * 64, k0 = blockIdx.y * 64;
    const int t = threadIdx.x;
    const int tr = t >> 4;          // 0..15
    const int tc = (t & 15) * 4;    // 0..60
#pragma unroll
    for (int i = 0; i < 4; i++) {
        int kk = tr + i * 16;
        float4 vv = *(const float4*)(w + (size_t)(k0 + kk) * N + n0 + tc);
        tile[kk][tc + 0] = vv.x; tile[kk][tc + 1] = vv.y;
        tile[kk][tc + 2] = vv.z; tile[kk][tc + 3] = vv.w;
    }
    __syncthreads();
#pragma unroll
    for (int i = 0; i < 4; i++) {
        int nn = tr + i * 16;
        s4v o4 = (s4v){ f2s(tile[tc + 0][nn]), f2s(tile[tc + 1][nn]),
                        f2s(tile[tc + 2][nn]), f2s(tile[tc + 3][nn]) };
        *(s4v*)(wt + (size_t)(n0 + nn) * K + k0 + tc) = o4;
    }
}

// ---- encoder f32 [EROWS][CROSS] -> bf16 [EPAD][CROSS], zero-padded rows ----
__global__ __launch_bounds__(256) void encconv(const float* __restrict__ e,
                                               bf16* __restrict__ eb) {
    int idx = blockIdx.x * 256 + threadIdx.x;   // 4 elems each
    int base = idx * 4;
    int row = base / CROSS;
    s4v o4;
    if (row < EROWS) {
        float4 vv = *(const float4*)(e + (size_t)base);
        o4 = (s4v){ f2s(vv.x), f2s(vv.y), f2s(vv.z), f2s(vv.w) };
    } else {
        o4 = (s4v){ 0, 0, 0, 0 };
    }
    *(s4v*)(eb + base) = o4;
}

// =====================================================================
// MFMA GEMM: C[M,N] = A[M,K](bf16) @ Bt[N,K](bf16, pre-transposed).
// Prefetch double-buffered LDS (stage k+1 before computing k; ONE barrier
// per iter), global_load_lds width-16 staging, 4 waves.
// EPI 0/1: 128x128 tile, waves 64x64.  EPI 2 (geglu): 128x64 tile, waves
// 32x64 of BOTH P and G strips (acc+accg = 64 regs -> 2 blocks/CU).
// M%128==0, N%(EPI==2?64:128)==0, K%32==0.
// =====================================================================
template <int EPI>
__global__ __launch_bounds__(256) void gemm_bt(
    const bf16* __restrict__ A, int lda,
    const bf16* __restrict__ Bt, int ldb,
    void* __restrict__ C, int ldc,
    const float* __restrict__ bias,
    const float* __restrict__ res, int ldres,
    int M, int N, int K) {
    constexpr int BN = (EPI == 2) ? 64 : 128;
    constexpr int MI = (EPI == 2) ? 2 : 4;
    __shared__ short A_lds[2][128 * 32];
    __shared__ short B_lds[2][BN * 32];
    __shared__ short G_lds[EPI == 2 ? 2 * 64 * 32 : 8];

    const int t = threadIdx.x;
    const int wid = t >> 6, lane = t & 63;
    const int lrow = lane & 15, lgrp = lane >> 4;
    const int m0 = blockIdx.y * 128, n0 = blockIdx.x * BN;
    const int wm = (EPI == 2) ? wid * 32 : (wid & 1) * 64;
    const int wn = (EPI == 2) ? 0 : (wid >> 1) * 64;

    f4v acc[MI][4];
    f4v accg[EPI == 2 ? MI : 1][4];
#pragma unroll
    for (int i = 0; i < MI; i++)
#pragma unroll
        for (int j = 0; j < 4; j++) {
            acc[i][j] = (f4v){0.f, 0.f, 0.f, 0.f};
            if (EPI == 2) accg[i][j] = (f4v){0.f, 0.f, 0.f, 0.f};
        }

    // staging: lane covers row (wid*R + (lane>>2)), 16B col chunk (lane&3)
    const int scol = (lane & 3) * 8;
    const int arow = wid * 32 + (lane >> 2);
    const int brow = (EPI == 2) ? (wid * 16 + (lane >> 2)) : arow;
    const bf16* Ag0 = A + (size_t)(m0 + arow) * lda + scol;
    const bf16* Bg0 = Bt + (size_t)(n0 + brow) * ldb + scol;
    const bf16* Gg0 = (EPI == 2) ? (Bt + (size_t)(INNER + n0 + brow) * ldb + scol) : Bg0;

    auto stage = [&](int buf, int kk) {
        gl_lds16(Ag0 + kk, &A_lds[buf][wid * 1024]);
        gl_lds16(Ag0 + kk + (size_t)16 * lda, &A_lds[buf][wid * 1024 + 512]);
        if constexpr (EPI == 2) {
            gl_lds16(Bg0 + kk, &B_lds[buf][wid * 512]);
            gl_lds16(Gg0 + kk, &G_lds[buf * 2048 + wid * 512]);
        } else {
            gl_lds16(Bg0 + kk, &B_lds[buf][wid * 1024]);
            gl_lds16(Bg0 + kk + (size_t)16 * ldb, &B_lds[buf][wid * 1024 + 512]);
        }
    };

    stage(0, 0);
    __syncthreads();
    int buf = 0;
    for (int k0 = 0; k0 < K; k0 += 32, buf ^= 1) {
        if (k0 + 32 < K) stage(buf ^ 1, k0 + 32);   // prefetch next tile

        s8v af[MI], bfr[4];
#pragma unroll
        for (int i = 0; i < MI; i++)
            af[i] = *(const s8v*)&A_lds[buf][(wm + i * 16 + lrow) * 32 + lgrp * 8];
#pragma unroll
        for (int j = 0; j < 4; j++)
            bfr[j] = *(const s8v*)&B_lds[buf][(wn + j * 16 + lrow) * 32 + lgrp * 8];
#pragma unroll
        for (int i = 0; i < MI; i++)
#pragma unroll
            for (int j = 0; j < 4; j++)
                acc[i][j] = __builtin_amdgcn_mfma_f32_16x16x32_bf16(af[i], bfr[j], acc[i][j], 0, 0, 0);
        if constexpr (EPI == 2) {
            s8v gfr[4];
#pragma unroll
            for (int j = 0; j < 4; j++)
                gfr[j] = *(const s8v*)&G_lds[buf * 2048 + (j * 16 + lrow) * 32 + lgrp * 8];
#pragma unroll
            for (int i = 0; i < MI; i++)
#pragma unroll
                for (int j = 0; j < 4; j++)
                    accg[i][j] = __builtin_amdgcn_mfma_f32_16x16x32_bf16(af[i], gfr[j], accg[i][j], 0, 0, 0);
        }
        __syncthreads();   // prefetch drained + all reads of buf done
    }

    // ---- epilogue: C/D layout col=lane&15, row=(lane>>4)*4+reg ----
#pragma unroll
    for (int i = 0; i < MI; i++) {
#pragma unroll
        for (int r = 0; r < 4; r++) {
            int m = m0 + wm + i * 16 + lgrp * 4 + r;
#pragma unroll
            for (int j = 0; j < 4; j++) {
                int n = n0 + wn + j * 16 + lrow;
                float v = acc[i][j][r];
                if (EPI == 0) {
                    ((bf16*)C)[(size_t)m * ldc + n] = f2b(v);
                } else if (EPI == 1) {
                    v += bias[n] + res[(size_t)m * ldres + n];
                    ((float*)C)[(size_t)m * ldc + n] = v;
                } else {
                    float p = v + bias[n];
                    float g = accg[i][j][r] + bias[INNER + n];
                    float gl = 0.5f * g * (1.f + erff(g * 0.70710678118654752f));
                    ((bf16*)C)[(size_t)m * ldc + n] = f2b(p * gl);
                }
            }
        }
    }
}

// =====================================================================
// LEGACY kernels (fallback when workspace too small for weight scratch)
// =====================================================================
template <int EPI>
__global__ __launch_bounds__(256) void gemm_mfma(
    const bf16* __restrict__ A, int lda,
    const float* __restrict__ B, int ldb,
    void* __restrict__ C, int ldc,
    const float* __restrict__ bias,
    const float* __restrict__ res, int ldres,
    int M, int N, int K) {
    constexpr int LR = 40;
    __shared__ short A_lds[128 * LR];
    __shared__ short B_lds[128 * LR];
    __shared__ short G_lds[EPI == 2 ? 128 * LR : 4];

    const int t    = threadIdx.x;
    const int wid  = t >> 6, lane = t & 63;
    const int lrow = lane & 15, lgrp = lane >> 4;
    const int m0   = blockIdx.y * 128, n0 = blockIdx.x * 128;
    const int wm   = (wid & 1) * 64, wn = (wid >> 1) * 64;

    f4v acc[4][4];
    f4v accg[4][4];
#pragma unroll
    for (int i = 0; i < 4; i++)
#pragma unroll
        for (int j = 0; j < 4; j++) {
            acc[i][j] = (f4v){0.f, 0.f, 0.f, 0.f};
            if (EPI == 2) accg[i][j] = (f4v){0.f, 0.f, 0.f, 0.f};
        }

    const int b_np = (t & 31) * 4;
    const int b_kp = (t >> 5) * 4;

    for (int k0 = 0; k0 < K; k0 += 32) {
#pragma unroll
        for (int c = 0; c < 2; c++) {
            int idx = t + c * 256;
            int row = idx >> 2, g = (idx & 3) * 8;
            uint4 v = *(const uint4*)(A + (size_t)(m0 + row) * lda + k0 + g);
            *(uint4*)&A_lds[row * LR + g] = v;
        }
        {
            const float* bp = B + (size_t)(k0 + b_kp) * ldb + n0 + b_np;
            float4 r0 = *(const float4*)(bp);
            float4 r1 = *(const float4*)(bp + ldb);
            float4 r2 = *(const float4*)(bp + 2 * ldb);
            float4 r3 = *(const float4*)(bp + 3 * ldb);
            *(s4v*)&B_lds[(b_np + 0) * LR + b_kp] = (s4v){f2s(r0.x), f2s(r1.x), f2s(r2.x), f2s(r3.x)};
            *(s4v*)&B_lds[(b_np + 1) * LR + b_kp] = (s4v){f2s(r0.y), f2s(r1.y), f2s(r2.y), f2s(r3.y)};
            *(s4v*)&B_lds[(b_np + 2) * LR + b_kp] = (s4v){f2s(r0.z), f2s(r1.z), f2s(r2.z), f2s(r3.z)};
            *(s4v*)&B_lds[(b_np + 3) * LR + b_kp] = (s4v){f2s(r0.w), f2s(r1.w), f2s(r2.w), f2s(r3.w)};
        }
        if (EPI == 2) {
            const float* gp = B + (size_t)(k0 + b_kp) * ldb + INNER + n0 + b_np;
            float4 r0 = *(const float4*)(gp);
            float4 r1 = *(const float4*)(gp + ldb);
            float4 r2 = *(const float4*)(gp + 2 * ldb);
            float4 r3 = *(const float4*)(gp + 3 * ldb);
            *(s4v*)&G_lds[(b_np + 0) * LR + b_kp] = (s4v){f2s(r0.x), f2s(r1.x), f2s(r2.x), f2s(r3.x)};
            *(s4v*)&G_lds[(b_np + 1) * LR + b_kp] = (s4v){f2s(r0.y), f2s(r1.y), f2s(r2.y), f2s(r3.y)};
            *(s4v*)&G_lds[(b_np + 2) * LR + b_kp] = (s4v){f2s(r0.z), f2s(r1.z), f2s(r2.z), f2s(r3.z)};
            *(s4v*)&G_lds[(b_np + 3) * LR + b_kp] = (s4v){f2s(r0.w), f2s(r1.w), f2s(r2.w), f2s(r3.w)};
        }
        __syncthreads();
        s8v af[4], bfr[4];
#pragma unroll
        for (int i = 0; i < 4; i++)
            af[i] = *(const s8v*)&A_lds[(wm + i * 16 + lrow) * LR + lgrp * 8];
#pragma unroll
        for (int j = 0; j < 4; j++)
            bfr[j] = *(const s8v*)&B_lds[(wn + j * 16 + lrow) * LR + lgrp * 8];
#pragma unroll
        for (int i = 0; i < 4; i++)
#pragma unroll
            for (int j = 0; j < 4; j++)
                acc[i][j] = __builtin_amdgcn_mfma_f32_16x16x32_bf16(af[i], bfr[j], acc[i][j], 0, 0, 0);
        if (EPI == 2) {
            s8v gfr[4];
#pragma unroll
            for (int j = 0; j < 4; j++)
                gfr[j] = *(const s8v*)&G_lds[(wn + j * 16 + lrow) * LR + lgrp * 8];
#pragma unroll
            for (int i = 0; i < 4; i++)
#pragma unroll
                for (int j = 0; j < 4; j++)
                    accg[i][j] = __builtin_amdgcn_mfma_f32_16x16x32_bf16(af[i], gfr[j], accg[i][j], 0, 0, 0);
        }
        __syncthreads();
    }
#pragma unroll
    for (int i = 0; i < 4; i++) {
#pragma unroll
        for (int r = 0; r < 4; r++) {
            int m = m0 + wm + i * 16 + lgrp * 4 + r;
#pragma unroll
            for (int j = 0; j < 4; j++) {
                int n = n0 + wn + j * 16 + lrow;
                float v = acc[i][j][r];
                if (EPI == 0) {
                    ((bf16*)C)[(size_t)m * ldc + n] = f2b(v);
                } else if (EPI == 1) {
                    v += bias[n] + res[(size_t)m * ldres + n];
                    ((float*)C)[(size_t)m * ldc + n] = v;
                } else {
                    float p = v + bias[n];
                    float g = accg[i][j][r] + bias[INNER + n];
                    float gl = 0.5f * g * (1.f + erff(g * 0.70710678118654752f));
                    ((bf16*)C)[(size_t)m * ldc + n] = f2b(p * gl);
                }
            }
        }
    }
}

__global__ __launch_bounds__(256) void gemm_valu(
    const float* __restrict__ A, int lda,
    const float* __restrict__ B, int ldb,
    bf16* __restrict__ C, int ldc,
    int M, int N, int K) {
    __shared__ float As[16][65];
    __shared__ float Bs[16][65];
    const int t  = threadIdx.x;
    const int m0 = blockIdx.y * 64, n0 = blockIdx.x * 64;
    const int ar = t >> 2, ak = (t & 3) * 4;
    const int bk = t >> 4, bn = (t & 15) * 4;
    const int ty = t >> 4, tx = t & 15;
    float acc[4][4];
#pragma unroll
    for (int i = 0; i < 4; i++)
#pragma unroll
        for (int j = 0; j < 4; j++) acc[i][j] = 0.f;

    for (int k0 = 0; k0 < K; k0 += 16) {
        {
            int m = m0 + ar;
            float tmp[4];
            if (m < M) load4(A + (size_t)m * lda + k0 + ak, tmp);
            else { tmp[0] = tmp[1] = tmp[2] = tmp[3] = 0.f; }
            As[ak + 0][ar] = tmp[0]; As[ak + 1][ar] = tmp[1];
            As[ak + 2][ar] = tmp[2]; As[ak + 3][ar] = tmp[3];
        }
        {
            float tmp[4];
            load4(B + (size_t)(k0 + bk) * ldb + n0 + bn, tmp);
            Bs[bk][bn + 0] = tmp[0]; Bs[bk][bn + 1] = tmp[1];
            Bs[bk][bn + 2] = tmp[2]; Bs[bk][bn + 3] = tmp[3];
        }
        __syncthreads();
#pragma unroll
        for (int k = 0; k < 16; k++) {
            float a[4], b[4];
#pragma unroll
            for (int i = 0; i < 4; i++) a[i] = As[k][ty * 4 + i];
#pragma unroll
            for (int j = 0; j < 4; j++) b[j] = Bs[k][tx * 4 + j];
#pragma unroll
            for (int i = 0; i < 4; i++)
#pragma unroll
                for (int j = 0; j < 4; j++) acc[i][j] += a[i] * b[j];
        }
        __syncthreads();
    }
#pragma unroll
    for (int i = 0; i < 4; i++) {
        int m = m0 + ty * 4 + i;
        if (m >= M) continue;
#pragma unroll
        for (int j = 0; j < 4; j++) {
            int n = n0 + tx * 4 + j;
            C[(size_t)m * ldc + n] = f2b(acc[i][j]);
        }
    }
}

#define SOFTMAX_SCALE 0.07905694150420949f  // 1/sqrt(160)

// =====================================================================
// attn1 (sparse-causal, 512 keys) — MFMA flash-attention.
// q/k/v may live in a fused QKV buffer: row stride = ldq. Output stride DIM.
// =====================================================================
#define A1_KP 168   // K LDS pitch (shorts): 160 + 8 pad
#define A1_VP 72    // V^T pitch (shorts):   64 + 8 pad
#define A1_PP 72    // P  pitch (shorts)

__global__ __launch_bounds__(256) void attn1_mfma(const bf16* __restrict__ q,
                                                  const bf16* __restrict__ k,
                                                  const bf16* __restrict__ v,
                                                  int ldq,
                                                  bf16* __restrict__ o) {
    __shared__ short K_lds[64 * A1_KP];
    __shared__ short Vt_lds[160 * A1_VP];
    __shared__ short P_lds[4 * 16 * A1_PP];

    const int t = threadIdx.x;
    const int wid = t >> 6, lane = t & 63;
    const int lrow = lane & 15, lgrp = lane >> 4;
    const int bx = blockIdx.x, hd = blockIdx.y, bfi = blockIdx.z;
    const int bi = bfi >> 4, fi = bfi & 15;
    const int former = fi > 0 ? fi - 1 : 0;
    const int qrow0 = bfi * TOK + bx * 64 + wid * 16;

    s8v qf[5];
    {
        const bf16* qp = q + (size_t)(qrow0 + lrow) * ldq + hd * DH + lgrp * 8;
#pragma unroll
        for (int ks = 0; ks < 5; ks++)
            qf[ks] = *(const s8v*)(qp + ks * 32);
    }

    f4v oacc[10];
#pragma unroll
    for (int dg = 0; dg < 10; dg++) oacc[dg] = (f4v){0.f, 0.f, 0.f, 0.f};
    float m_run[4], l_run[4];
#pragma unroll
    for (int r = 0; r < 4; r++) { m_run[r] = -1e30f; l_run[r] = 0.f; }

    short* P_w = P_lds + wid * 16 * A1_PP;

    for (int c = 0; c < 8; c++) {
        const int kf = (c < 4) ? 0 : former;
        const size_t krow0 = (size_t)(bi * FRAMES + kf) * TOK + (c & 3) * 64;

        __syncthreads();
#pragma unroll
        for (int it = 0; it < 5; it++) {
            int idx = t + it * 256;
            int jr = idx / 20, g = idx % 20;
            const bf16* kp = k + (krow0 + jr) * ldq + hd * DH + g * 8;
            *(uint4*)&K_lds[jr * A1_KP + g * 8] = *(const uint4*)kp;
            s8v vv = *(const s8v*)(v + (krow0 + jr) * ldq + hd * DH + g * 8);
#pragma unroll
            for (int i = 0; i < 8; i++) {
                int d = g * 8 + i;
                Vt_lds[d * A1_VP + (jr ^ (d & 56))] = vv[i];
            }
        }
        __syncthreads();

        f4v sacc[4];
#pragma unroll
        for (int kg = 0; kg < 4; kg++) {
            sacc[kg] = (f4v){0.f, 0.f, 0.f, 0.f};
#pragma unroll
            for (int ks = 0; ks < 5; ks++) {
                s8v kfr = *(const s8v*)&K_lds[(kg * 16 + lrow) * A1_KP + ks * 32 + lgrp * 8];
                sacc[kg] = __builtin_amdgcn_mfma_f32_16x16x32_bf16(qf[ks], kfr, sacc[kg], 0, 0, 0);
            }
        }

        float mc[4];
#pragma unroll
        for (int r = 0; r < 4; r++) {
            float mm = fmaxf(fmaxf(sacc[0][r], sacc[1][r]), fmaxf(sacc[2][r], sacc[3][r]));
            mc[r] = mm * SOFTMAX_SCALE;
        }
#pragma unroll
        for (int x = 1; x < 16; x <<= 1)
#pragma unroll
            for (int r = 0; r < 4; r++)
                mc[r] = fmaxf(mc[r], __shfl_xor(mc[r], x));

        float p[4][4], rs[4];
#pragma unroll
        for (int r = 0; r < 4; r++) {
            float mn = fmaxf(m_run[r], mc[r]);
            float sc = __expf(m_run[r] - mn);
            m_run[r] = mn;
            l_run[r] *= sc;
#pragma unroll
            for (int dg = 0; dg < 10; dg++) oacc[dg][r] *= sc;
            float acc = 0.f;
#pragma unroll
            for (int kg = 0; kg < 4; kg++) {
                float e = __expf(sacc[kg][r] * SOFTMAX_SCALE - mn);
                p[kg][r] = e; acc += e;
            }
            rs[r] = acc;
        }
#pragma unroll
        for (int x = 1; x < 16; x <<= 1)
#pragma unroll
            for (int r = 0; r < 4; r++)
                rs[r] += __shfl_xor(rs[r], x);
#pragma unroll
        for (int r = 0; r < 4; r++) l_run[r] += rs[r];

#pragma unroll
        for (int kg = 0; kg < 4; kg++)
#pragma unroll
            for (int r = 0; r < 4; r++)
                P_w[(lgrp * 4 + r) * A1_PP + kg * 16 + lrow] = f2s(p[kg][r]);
        __syncthreads();

        s8v pa[2];
#pragma unroll
        for (int ks2 = 0; ks2 < 2; ks2++)
            pa[ks2] = *(const s8v*)&P_w[lrow * A1_PP + ks2 * 32 + lgrp * 8];
#pragma unroll
        for (int dg = 0; dg < 10; dg++) {
            int dd = dg * 16 + lrow;
#pragma unroll
            for (int ks2 = 0; ks2 < 2; ks2++) {
                s8v vfr = *(const s8v*)&Vt_lds[dd * A1_VP + ((ks2 * 32 + lgrp * 8) ^ (dd & 56))];
                oacc[dg] = __builtin_amdgcn_mfma_f32_16x16x32_bf16(pa[ks2], vfr, oacc[dg], 0, 0, 0);
            }
        }
    }

    float invl[4];
#pragma unroll
    for (int r = 0; r < 4; r++) invl[r] = 1.f / l_run[r];
#pragma unroll
    for (int dg = 0; dg < 10; dg++) {
#pragma unroll
        for (int r = 0; r < 4; r++) {
            int qq = qrow0 + lgrp * 4 + r;
            o[(size_t)qq * DIM + hd * DH + dg * 16 + lrow] = f2b(oacc[dg][r] * invl[r]);
        }
    }
}

// =====================================================================
// attn2 (cross, 77 keys) — MFMA flash-attention, 2 key-chunks, masked.
// k/v are dense [EPAD][DIM] buffers (rows >= EROWS are exact zeros).
// =====================================================================
__global__ __launch_bounds__(256) void attn2_mfma(const bf16* __restrict__ q,
                                                  const bf16* __restrict__ k,
                                                  const bf16* __restrict__ v,
                                                  bf16* __restrict__ o) {
    __shared__ short K_lds[64 * A1_KP];
    __shared__ short Vt_lds[160 * A1_VP];
    __shared__ short P_lds[4 * 16 * A1_PP];

    const int t = threadIdx.x;
    const int wid = t >> 6, lane = t & 63;
    const int lrow = lane & 15, lgrp = lane >> 4;
    const int bx = blockIdx.x, hd = blockIdx.y, bfi = blockIdx.z;
    const int qrow0 = bfi * TOK + bx * 64 + wid * 16;

    s8v qf[5];
    {
        const bf16* qp = q + (size_t)(qrow0 + lrow) * DIM + hd * DH + lgrp * 8;
#pragma unroll
        for (int ks = 0; ks < 5; ks++)
            qf[ks] = *(const s8v*)(qp + ks * 32);
    }

    f4v oacc[10];
#pragma unroll
    for (int dg = 0; dg < 10; dg++) oacc[dg] = (f4v){0.f, 0.f, 0.f, 0.f};
    float m_run[4], l_run[4];
#pragma unroll
    for (int r = 0; r < 4; r++) { m_run[r] = -1e30f; l_run[r] = 0.f; }

    short* P_w = P_lds + wid * 16 * A1_PP;

    for (int c = 0; c < 2; c++) {
        // key rows c*64 .. c*64+63; global row = bfi*ESEQ + key (stays < EPAD)
        const size_t krow0 = (size_t)bfi * ESEQ + c * 64;

        __syncthreads();
#pragma unroll
        for (int it = 0; it < 5; it++) {
            int idx = t + it * 256;
            int jr = idx / 20, g = idx % 20;
            const bf16* kp = k + (krow0 + jr) * DIM + hd * DH + g * 8;
            *(uint4*)&K_lds[jr * A1_KP + g * 8] = *(const uint4*)kp;
            s8v vv = *(const s8v*)(v + (krow0 + jr) * DIM + hd * DH + g * 8);
#pragma unroll
            for (int i = 0; i < 8; i++) {
                int d = g * 8 + i;
                Vt_lds[d * A1_VP + (jr ^ (d & 56))] = vv[i];
            }
        }
        __syncthreads();

        f4v sacc[4];
#pragma unroll
        for (int kg = 0; kg < 4; kg++) {
            sacc[kg] = (f4v){0.f, 0.f, 0.f, 0.f};
#pragma unroll
            for (int ks = 0; ks < 5; ks++) {
                s8v kfr = *(const s8v*)&K_lds[(kg * 16 + lrow) * A1_KP + ks * 32 + lgrp * 8];
                sacc[kg] = __builtin_amdgcn_mfma_f32_16x16x32_bf16(qf[ks], kfr, sacc[kg], 0, 0, 0);
            }
            // mask keys >= ESEQ (chunk 1: key = 64 + kg*16 + lrow)
            if (c == 1 && (kg > 0 || lrow >= 13))
                sacc[kg] = (f4v){-1e30f, -1e30f, -1e30f, -1e30f};
        }

        float mc[4];
#pragma unroll
        for (int r = 0; r < 4; r++) {
            float mm = fmaxf(fmaxf(sacc[0][r], sacc[1][r]), fmaxf(sacc[2][r], sacc[3][r]));
            mc[r] = mm * SOFTMAX_SCALE;
        }
#pragma unroll
        for (int x = 1; x < 16; x <<= 1)
#pragma unroll
            for (int r = 0; r < 4; r++)
                mc[r] = fmaxf(mc[r], __shfl_xor(mc[r], x));

        float p[4][4], rs[4];
#pragma unroll
        for (int r = 0; r < 4; r++) {
            float mn = fmaxf(m_run[r], mc[r]);
            float sc = __expf(m_run[r] - mn);
            m_run[r] = mn;
            l_run[r] *= sc;
#pragma unroll
            for (int dg = 0; dg < 10; dg++) oacc[dg][r] *= sc;
            float acc = 0.f;
#pragma unroll
            for (int kg = 0; kg < 4; kg++) {
                float e = __expf(sacc[kg][r] * SOFTMAX_SCALE - mn);
                p[kg][r] = e; acc += e;
            }
            rs[r] = acc;
        }
#pragma unroll
        for (int x = 1; x < 16; x <<= 1)
#pragma unroll
            for (int r = 0; r < 4; r++)
                rs[r] += __shfl_xor(rs[r], x);
#pragma unroll
        for (int r = 0; r < 4; r++) l_run[r] += rs[r];

#pragma unroll
        for (int kg = 0; kg < 4; kg++)
#pragma unroll
            for (int r = 0; r < 4; r++)
                P_w[(lgrp * 4 + r) * A1_PP + kg * 16 + lrow] = f2s(p[kg][r]);
        __syncthreads();

        s8v pa[2];
#pragma unroll
        for (int ks2 = 0; ks2 < 2; ks2++)
            pa[ks2] = *(const s8v*)&P_w[lrow * A1_PP + ks2 * 32 + lgrp * 8];
#pragma unroll
        for (int dg = 0; dg < 10; dg++) {
            int dd = dg * 16 + lrow;
#pragma unroll
            for (int ks2 = 0; ks2 < 2; ks2++) {
                s8v vfr = *(const s8v*)&Vt_lds[dd * A1_VP + ((ks2 * 32 + lgrp * 8) ^ (dd & 56))];
                oacc[dg] = __builtin_amdgcn_mfma_f32_16x16x32_bf16(pa[ks2], vfr, oacc[dg], 0, 0, 0);
            }
        }
    }

    float invl[4];
#pragma unroll
    for (int r = 0; r < 4; r++) invl[r] = 1.f / l_run[r];
#pragma unroll
    for (int dg = 0; dg < 10; dg++) {
#pragma unroll
        for (int r = 0; r < 4; r++) {
            int qq = qrow0 + lgrp * 4 + r;
            o[(size_t)qq * DIM + hd * DH + dg * 16 + lrow] = f2b(oacc[dg][r] * invl[r]);
        }
    }
}

// ---- attn2 legacy scalar (tier0 fallback) ----
__global__ __launch_bounds__(256) void attn2_kernel(const bf16* __restrict__ q,
                                                    const bf16* __restrict__ k,
                                                    const bf16* __restrict__ v,
                                                    bf16* __restrict__ o) {
    __shared__ float sQ[DH];
    __shared__ float sS[128];
    __shared__ float red[256];
    int t = threadIdx.x;
    int qi = blockIdx.x, hd = blockIdx.y, bfi = blockIdx.z;
    size_t qbase = ((size_t)(bfi * TOK + qi)) * DIM + hd * DH;
    if (t < DH) sQ[t] = b2f(q[qbase + t]);
    __syncthreads();
    if (t < ESEQ) {
        size_t kbase = ((size_t)(bfi * ESEQ + t)) * DIM + hd * DH;
        float acc = 0.f;
        for (int d = 0; d < DH; d++) acc += sQ[d] * b2f(k[kbase + d]);
        sS[t] = acc * SOFTMAX_SCALE;
    }
    __syncthreads();
    float lm = (t < ESEQ) ? sS[t] : -1e30f;
    red[t] = lm; __syncthreads();
    for (int s = 128; s > 0; s >>= 1) { if (t < s) red[t] = fmaxf(red[t], red[t + s]); __syncthreads(); }
    float mx = red[0]; __syncthreads();
    float ls = 0.f;
    if (t < ESEQ) { float e = __expf(sS[t] - mx); sS[t] = e; ls = e; }
    red[t] = ls; __syncthreads();
    for (int s = 128; s > 0; s >>= 1) { if (t < s) red[t] += red[t + s]; __syncthreads(); }
    float inv = 1.f / red[0];
    __syncthreads();
    if (t < DH) {
        float acc = 0.f;
        for (int j = 0; j < ESEQ; j++) {
            size_t vbase = ((size_t)(bfi * ESEQ + j)) * DIM + hd * DH;
            acc += sS[j] * b2f(v[vbase + t]);
        }
        o[qbase + t] = f2b(acc * inv);
    }
}

// ---- temporal self-attn: 16 keys (frames) per (batch, token); ldq stride ----
__global__ __launch_bounds__(256) void attnt_kernel(const bf16* __restrict__ q,
                                                    const bf16* __restrict__ k,
                                                    const bf16* __restrict__ v,
                                                    int ldq,
                                                    bf16* __restrict__ o) {
    __shared__ float sQ[DH];
    __shared__ float sS[16];
    __shared__ float red[256];
    int t = threadIdx.x;
    int qfi = blockIdx.x, hd = blockIdx.y, z = blockIdx.z;
    int bi = z >> 8, ti = z & 255;
    size_t qrow = (size_t)(bi * FRAMES + qfi) * TOK + ti;
    if (t < DH) sQ[t] = b2f(q[qrow * ldq + hd * DH + t]);
    __syncthreads();
    if (t < FRAMES) {
        size_t krow = (size_t)(bi * FRAMES + t) * TOK + ti;
        float acc = 0.f;
        for (int d = 0; d < DH; d++) acc += sQ[d] * b2f(k[krow * ldq + hd * DH + d]);
        sS[t] = acc * SOFTMAX_SCALE;
    }
    __syncthreads();
    float lm = (t < FRAMES) ? sS[t] : -1e30f;
    red[t] = lm; __syncthreads();
    for (int s = 128; s > 0; s >>= 1) { if (t < s) red[t] = fmaxf(red[t], red[t + s]); __syncthreads(); }
    float mx = red[0]; __syncthreads();
    float ls = 0.f;
    if (t < FRAMES) { float e = __expf(sS[t] - mx); sS[t] = e; ls = e; }
    red[t] = ls; __syncthreads();
    for (int s = 128; s > 0; s >>= 1) { if (t < s) red[t] += red[t + s]; __syncthreads(); }
    float inv = 1.f / red[0];
    __syncthreads();
    if (t < DH) {
        float acc = 0.f;
        for (int j = 0; j < FRAMES; j++) {
            size_t vrow = (size_t)(bi * FRAMES + j) * TOK + ti;
            acc += sS[j] * b2f(v[vrow * ldq + hd * DH + t]);
        }
        o[qrow * DIM + hd * DH + t] = f2b(acc * inv);
    }
}

extern "C" void kernel_launch(void* const* d_in, const int* in_sizes, int n_in,
                              void* d_out, int out_size, void* d_ws, size_t ws_size,
                              hipStream_t stream) {
    (void)in_sizes; (void)n_in; (void)out_size;
    const float* hs   = (const float*)d_in[0];
    const float* enc  = (const float*)d_in[1];
    const float* n1w  = (const float*)d_in[2];
    const float* n1b  = (const float*)d_in[3];
    const float* a1wq = (const float*)d_in[4];
    const float* a1wk = (const float*)d_in[5];
    const float* a1wv = (const float*)d_in[6];
    const float* a1wo = (const float*)d_in[7];
    const float* a1bo = (const float*)d_in[8];
    const float* n2w  = (const float*)d_in[9];
    const float* n2b  = (const float*)d_in[10];
    const float* a2wq = (const float*)d_in[11];
    const float* a2wk = (const float*)d_in[12];
    const float* a2wv = (const float*)d_in[13];
    const float* a2wo = (const float*)d_in[14];
    const float* a2bo = (const float*)d_in[15];
    const float* n3w  = (const float*)d_in[16];
    const float* n3b  = (const float*)d_in[17];
    const float* ffw1 = (const float*)d_in[18];
    const float* ffb1 = (const float*)d_in[19];
    const float* ffw2 = (const float*)d_in[20];
    const float* ffb2 = (const float*)d_in[21];
    const float* ntw  = (const float*)d_in[22];
    const float* ntb  = (const float*)d_in[23];
    const float* atwq = (const float*)d_in[24];
    const float* atwk = (const float*)d_in[25];
    const float* atwv = (const float*)d_in[26];
    const float* atwo = (const float*)d_in[27];
    const float* atbo = (const float*)d_in[28];

    char* wp = (char*)d_ws;
    auto carve = [&](size_t bytes) -> char* {
        char* p = wp; wp += (bytes + 255) & ~((size_t)255); return p;
    };
    const size_t BUF = (size_t)ROWS * DIM * 2;   // 20,971,520
    const size_t W_FULL = 26214400;              // ffw1t: 10240x1280 bf16
    float* out = (float*)d_out;                  // f32 residual stream in d_out
    dim3 blk(256);

    bf16* nh = (bf16*)carve(BUF);

    bool full = (ws_size >= 5 * BUF + W_FULL + 4096);
    if (!full) {
        // ------- legacy path (R1 kernel, known-good at 105 MB ws) -------
        bf16* qb = (bf16*)carve(BUF);
        bf16* kb = (bf16*)carve(BUF);
        bf16* vb = (bf16*)carve(BUF);
        bf16* ob = (bf16*)carve(BUF);
        bf16* Pb = qb;
        auto proj = [&](const bf16* A, int lda, const float* B, int ldb,
                        bf16* C, int ldc, int M, int N, int K) {
            gemm_mfma<0><<<dim3(N / 128, M / 128), blk, 0, stream>>>(
                A, lda, B, ldb, C, ldc, nullptr, nullptr, 0, M, N, K);
        };
        auto outproj = [&](const bf16* A, int lda, const float* B,
                           const float* bias, const float* res, int K) {
            gemm_mfma<1><<<dim3(DIM / 128, ROWS / 128), blk, 0, stream>>>(
                A, lda, B, DIM, out, DIM, bias, res, DIM, ROWS, DIM, K);
        };
        ln_kernel<<<dim3(ROWS), blk, 0, stream>>>(hs, n1w, n1b, nh);
        proj(nh, DIM, a1wq, DIM, qb, DIM, ROWS, DIM, DIM);
        proj(nh, DIM, a1wk, DIM, kb, DIM, ROWS, DIM, DIM);
        proj(nh, DIM, a1wv, DIM, vb, DIM, ROWS, DIM, DIM);
        attn1_mfma<<<dim3(TOK / 64, HEADS, BF), blk, 0, stream>>>(qb, kb, vb, DIM, ob);
        outproj(ob, DIM, a1wo, a1bo, hs, DIM);

        ln_kernel<<<dim3(ROWS), blk, 0, stream>>>(out, n2w, n2b, nh);
        proj(nh, DIM, a2wq, DIM, qb, DIM, ROWS, DIM, DIM);
        gemm_valu<<<dim3(DIM / 64, (EROWS + 63) / 64), blk, 0, stream>>>(enc, CROSS, a2wk, DIM, kb, DIM, EROWS, DIM, CROSS);
        gemm_valu<<<dim3(DIM / 64, (EROWS + 63) / 64), blk, 0, stream>>>(enc, CROSS, a2wv, DIM, vb, DIM, EROWS, DIM, CROSS);
        attn2_kernel<<<dim3(TOK, HEADS, BF), blk, 0, stream>>>(qb, kb, vb, ob);
        outproj(ob, DIM, a2wo, a2bo, out, DIM);

        ln_kernel<<<dim3(ROWS), blk, 0, stream>>>(out, n3w, n3b, nh);
        gemm_mfma<2><<<dim3(INNER / 128, ROWS / 128), blk, 0, stream>>>(
            nh, DIM, ffw1, 2 * INNER, Pb, INNER, ffb1, nullptr, 0, ROWS, INNER, DIM);
        outproj(Pb, INNER, ffw2, ffb2, out, INNER);

        ln_kernel<<<dim3(ROWS), blk, 0, stream>>>(out, ntw, ntb, nh);
        proj(nh, DIM, atwq, DIM, qb, DIM, ROWS, DIM, DIM);
        proj(nh, DIM, atwk, DIM, kb, DIM, ROWS, DIM, DIM);
        proj(nh, DIM, atwv, DIM, vb, DIM, ROWS, DIM, DIM);
        attnt_kernel<<<dim3(FRAMES, HEADS, BATCH * TOK), blk, 0, stream>>>(qb, kb, vb, DIM, ob);
        outproj(ob, DIM, atwo, atbo, out, DIM);
        return;
    }

    // ------- full path: bf16 B^T weights + prefetch gemm_bt + fused QKV -------
    bf16* C3 = (bf16*)carve(3 * BUF);            // fused QKV [ROWS][3840]
    bf16* ob = (bf16*)carve(BUF);
    bf16* Ws = (bf16*)carve(W_FULL);
    bf16* Pb = C3;                               // FFN intermediate spans C3+ob (84 MB)
    const size_t WQ = (size_t)DIM * DIM;
    const size_t WC = (size_t)DIM * CROSS;
    const int LDQ3 = 3 * DIM;                    // 3840

    auto convW = [&](const float* w, bf16* wt, int N, int K) {
        wconv_t<<<dim3(N / 64, K / 64), blk, 0, stream>>>(w, wt, N, K);
    };
    auto projN = [&](const bf16* A, int lda, const bf16* Bt, int ldb,
                     bf16* C, int ldc, int M, int N, int K) {
        gemm_bt<0><<<dim3(N / 128, M / 128), blk, 0, stream>>>(
            A, lda, Bt, ldb, C, ldc, nullptr, nullptr, 0, M, N, K);
    };
    auto outprojN = [&](const bf16* A, int lda, const bf16* Bt, int ldb,
                        const float* bias, const float* res, int K) {
        gemm_bt<1><<<dim3(DIM / 128, ROWS / 128), blk, 0, stream>>>(
            A, lda, Bt, ldb, out, DIM, bias, res, DIM, ROWS, DIM, K);
    };

    // ---- attn1: sparse-causal self-attention (fused QKV proj, N=3840) ----
    convW(a1wq, Ws,          DIM, DIM);
    convW(a1wk, Ws + WQ,     DIM, DIM);
    convW(a1wv, Ws + 2 * WQ, DIM, DIM);
    convW(a1wo, Ws + 3 * WQ, DIM, DIM);
    ln_kernel<<<dim3(ROWS), blk, 0, stream>>>(hs, n1w, n1b, nh);
    projN(nh, DIM, Ws, DIM, C3, LDQ3, ROWS, 3 * DIM, DIM);
    attn1_mfma<<<dim3(TOK / 64, HEADS, BF), blk, 0, stream>>>(
        C3, C3 + DIM, C3 + 2 * DIM, LDQ3, ob);
    outprojN(ob, DIM, Ws + 3 * WQ, DIM, a1bo, hs, DIM);

    // ---- attn2: cross-attention (MFMA attn, padded encoder) ----
    {
        bf16* w2q  = Ws;
        bf16* w2k  = Ws + WQ;
        bf16* w2v  = w2k + WC;
        bf16* w2o  = w2v + WC;
        bf16* encb = w2o + WQ;                   // [EPAD][CROSS]
        bf16* qb2  = C3;                         // [ROWS][DIM]
        bf16* kb2  = C3 + (size_t)ROWS * DIM;    // [EPAD][DIM]
        bf16* vb2  = kb2 + (size_t)EPAD * DIM;   // [EPAD][DIM]
        convW(a2wq, w2q, DIM, DIM);
        convW(a2wk, w2k, DIM, CROSS);
        convW(a2wv, w2v, DIM, CROSS);
        convW(a2wo, w2o, DIM, DIM);
        encconv<<<dim3(EPAD * CROSS / 1024), blk, 0, stream>>>(enc, encb);
        ln_kernel<<<dim3(ROWS), blk, 0, stream>>>(out, n2w, n2b, nh);
        projN(nh, DIM, w2q, DIM, qb2, DIM, ROWS, DIM, DIM);
        projN(encb, CROSS, w2k, CROSS, kb2, DIM, EPAD, DIM, CROSS);
        projN(encb, CROSS, w2v, CROSS, vb2, DIM, EPAD, DIM, CROSS);
        attn2_mfma<<<dim3(TOK / 64, HEADS, BF), blk, 0, stream>>>(qb2, kb2, vb2, ob);
        outprojN(ob, DIM, w2o, DIM, a2bo, out, DIM);
    }

    // ---- geglu FFN ----
    convW(ffw1, Ws, 2 * INNER, DIM);             // [10240][1280] bf16
    ln_kernel<<<dim3(ROWS), blk, 0, stream>>>(out, n3w, n3b, nh);
    gemm_bt<2><<<dim3(INNER / 64, ROWS / 128), blk, 0, stream>>>(
        nh, DIM, Ws, DIM, Pb, INNER, ffb1, nullptr, 0, ROWS, INNER, DIM);
    convW(ffw2, Ws, DIM, INNER);                 // [1280][5120] bf16
    gemm_bt<1><<<dim3(DIM / 128, ROWS / 128), blk, 0, stream>>>(
        Pb, INNER, Ws, INNER, out, DIM, ffb2, out, DIM, ROWS, DIM, INNER);

    // ---- temporal self-attention (fused QKV proj) ----
    convW(atwq, Ws,          DIM, DIM);
    convW(atwk, Ws + WQ,     DIM, DIM);
    convW(atwv, Ws + 2 * WQ, DIM, DIM);
    convW(atwo, Ws + 3 * WQ, DIM, DIM);
    ln_kernel<<<dim3(ROWS), blk, 0, stream>>>(out, ntw, ntb, nh);
    projN(nh, DIM, Ws, DIM, C3, LDQ3, ROWS, 3 * DIM, DIM);
    attnt_kernel<<<dim3(FRAMES, HEADS, BATCH * TOK), blk, 0, stream>>>(
        C3, C3 + DIM, C3 + 2 * DIM, LDQ3, ob);
    outprojN(ob, DIM, Ws + 3 * WQ, DIM, atbo, out, DIM);
}

// Round 4
// 1391.404 us; speedup vs baseline: 3.7659x; 1.1525x over previous
//
#include <hip/hip_runtime.h>
#include <hip/hip_bf16.h>
#include <math.h>

// ---- problem constants (from reference) ----
#define DIM    1280
#define HEADS  8
#define DH     160            // DIM / HEADS
#define FRAMES 16
#define BATCH  2
#define TOK    256
#define ESEQ   77
#define INNER  5120           // 4*DIM
#define CROSS  768
#define BF     (BATCH*FRAMES) // 32
#define ROWS   (BF*TOK)       // 8192
#define EROWS  (BF*ESEQ)      // 2464
#define EPAD   2560           // EROWS padded to %128

typedef __hip_bfloat16 bf16;
typedef __attribute__((ext_vector_type(8))) short s8v;
typedef __attribute__((ext_vector_type(4))) short s4v;
typedef __attribute__((ext_vector_type(4))) float f4v;

__device__ __forceinline__ float us2f(unsigned short u) {
    union { float f; unsigned int i; } c; c.i = ((unsigned int)u) << 16; return c.f;
}
__device__ __forceinline__ float b2f(bf16 x) { return __bfloat162float(x); }
__device__ __forceinline__ bf16  f2b(float x) { return __float2bfloat16(x); }
// f32 -> bf16 bits (RNE), as short
__device__ __forceinline__ short f2s(float x) {
    union { float f; unsigned int u; } c; c.f = x;
    unsigned int r = c.u + 0x7FFF + ((c.u >> 16) & 1);
    return (short)(r >> 16);
}
__device__ __forceinline__ void load4(const float* p, float* d) {
    float4 v = *(const float4*)p; d[0] = v.x; d[1] = v.y; d[2] = v.z; d[3] = v.w;
}
// async global->LDS, 16B per lane; LDS dest is wave-uniform base + lane*16
__device__ __forceinline__ void gl_lds16(const bf16* g, short* l) {
    __builtin_amdgcn_global_load_lds(
        (const __attribute__((address_space(1))) void*)g,
        (__attribute__((address_space(3))) void*)l, 16, 0, 0);
}

// ---- LayerNorm: one block per row of DIM=1280 (256 thr x 5 elems) ----
__global__ __launch_bounds__(256) void ln_kernel(const float* __restrict__ x,
                                                 const float* __restrict__ w,
                                                 const float* __restrict__ b,
                                                 bf16* __restrict__ out) {
    __shared__ float r1[256], r2[256];
    int row = blockIdx.x, t = threadIdx.x;
    const float* xp = x + (size_t)row * DIM;
    float v[5], s = 0.f, s2 = 0.f;
#pragma unroll
    for (int i = 0; i < 5; i++) {
        float xv = xp[t + 256 * i];
        v[i] = xv; s += xv; s2 += xv * xv;
    }
    r1[t] = s; r2[t] = s2; __syncthreads();
    for (int st = 128; st > 0; st >>= 1) {
        if (t < st) { r1[t] += r1[t + st]; r2[t] += r2[t + st]; }
        __syncthreads();
    }
    float mean = r1[0] * (1.f / DIM);
    float var  = r2[0] * (1.f / DIM) - mean * mean;
    float rstd = rsqrtf(var + 1e-5f);
    bf16* op = out + (size_t)row * DIM;
#pragma unroll
    for (int i = 0; i < 5; i++) {
        int c = t + 256 * i;
        op[c] = f2b((v[i] - mean) * rstd * w[c] + b[c]);
    }
}

// ---- transpose-convert: W f32 [K][N] -> Wt bf16 [N][K]; N,K % 64 == 0 ----
__global__ __launch_bounds__(256) void wconv_t(const float* __restrict__ w,
                                               bf16* __restrict__ wt,
                                               int N, int K) {
    __shared__ float tile[64][65];
    const int n0 = blockIdx.x * 64, k0 = blockIdx.y * 64;
    const int t = threadIdx.x;
    const int tr = t >> 4;          // 0..15
    const int tc = (t & 15) * 4;    // 0..60
#pragma unroll
    for (int i = 0; i < 4; i++) {
        int kk = tr + i * 16;
        float4 vv = *(const float4*)(w + (size_t)(k0 + kk) * N + n0 + tc);
        tile[kk][tc + 0] = vv.x; tile[kk][tc + 1] = vv.y;
        tile[kk][tc + 2] = vv.z; tile[kk][tc + 3] = vv.w;
    }
    __syncthreads();
#pragma unroll
    for (int i = 0; i < 4; i++) {
        int nn = tr + i * 16;
        s4v o4 = (s4v){ f2s(tile[tc + 0][nn]), f2s(tile[tc + 1][nn]),
                        f2s(tile[tc + 2][nn]), f2s(tile[tc + 3][nn]) };
        *(s4v*)(wt + (size_t)(n0 + nn) * K + k0 + tc) = o4;
    }
}

// ---- batched transpose-convert: up to 4 same-shape weights, grid.z selects ----
__global__ __launch_bounds__(256) void wconv_t4(const float* __restrict__ w0,
                                                const float* __restrict__ w1,
                                                const float* __restrict__ w2,
                                                const float* __restrict__ w3,
                                                bf16* __restrict__ wt, size_t dstride,
                                                int N, int K) {
    const float* w = blockIdx.z == 0 ? w0 : blockIdx.z == 1 ? w1
                   : blockIdx.z == 2 ? w2 : w3;
    bf16* dst = wt + (size_t)blockIdx.z * dstride;
    __shared__ float tile[64][65];
    const int n0 = blockIdx.x * 64, k0 = blockIdx.y * 64;
    const int t = threadIdx.x;
    const int tr = t >> 4;
    const int tc = (t & 15) * 4;
#pragma unroll
    for (int i = 0; i < 4; i++) {
        int kk = tr + i * 16;
        float4 vv = *(const float4*)(w + (size_t)(k0 + kk) * N + n0 + tc);
        tile[kk][tc + 0] = vv.x; tile[kk][tc + 1] = vv.y;
        tile[kk][tc + 2] = vv.z; tile[kk][tc + 3] = vv.w;
    }
    __syncthreads();
#pragma unroll
    for (int i = 0; i < 4; i++) {
        int nn = tr + i * 16;
        s4v o4 = (s4v){ f2s(tile[tc + 0][nn]), f2s(tile[tc + 1][nn]),
                        f2s(tile[tc + 2][nn]), f2s(tile[tc + 3][nn]) };
        *(s4v*)(dst + (size_t)(n0 + nn) * K + k0 + tc) = o4;
    }
}

// ---- encoder f32 [EROWS][CROSS] -> bf16 [EPAD][CROSS], zero-padded rows ----
__global__ __launch_bounds__(256) void encconv(const float* __restrict__ e,
                                               bf16* __restrict__ eb) {
    int idx = blockIdx.x * 256 + threadIdx.x;   // 4 elems each
    int base = idx * 4;
    int row = base / CROSS;
    s4v o4;
    if (row < EROWS) {
        float4 vv = *(const float4*)(e + (size_t)base);
        o4 = (s4v){ f2s(vv.x), f2s(vv.y), f2s(vv.z), f2s(vv.w) };
    } else {
        o4 = (s4v){ 0, 0, 0, 0 };
    }
    *(s4v*)(eb + base) = o4;
}

// =====================================================================
// MFMA GEMM: C[M,N] = A[M,K](bf16) @ Bt[N,K](bf16, pre-transposed).
// Prefetch double-buffered LDS (stage k+1 before computing k; ONE barrier
// per iter), global_load_lds width-16 staging, 4 waves.
// EPI 0/1: 128x128 tile, waves 64x64.  EPI 2 (geglu): 128x64 tile, waves
// 32x64 of BOTH P and G strips (acc+accg = 64 regs -> 2 blocks/CU).
// M%128==0, N%(EPI==2?64:128)==0, K%32==0.
// =====================================================================
template <int EPI>
__global__ __launch_bounds__(256) void gemm_bt(
    const bf16* __restrict__ A, int lda,
    const bf16* __restrict__ Bt, int ldb,
    void* __restrict__ C, int ldc,
    const float* __restrict__ bias,
    const float* __restrict__ res, int ldres,
    int M, int N, int K) {
    constexpr int BN = (EPI == 2) ? 64 : 128;
    constexpr int MI = (EPI == 2) ? 2 : 4;
    __shared__ short A_lds[2][128 * 32];
    __shared__ short B_lds[2][BN * 32];
    __shared__ short G_lds[EPI == 2 ? 2 * 64 * 32 : 8];

    const int t = threadIdx.x;
    const int wid = t >> 6, lane = t & 63;
    const int lrow = lane & 15, lgrp = lane >> 4;
    const int m0 = blockIdx.y * 128, n0 = blockIdx.x * BN;
    const int wm = (EPI == 2) ? wid * 32 : (wid & 1) * 64;
    const int wn = (EPI == 2) ? 0 : (wid >> 1) * 64;

    f4v acc[MI][4];
    f4v accg[EPI == 2 ? MI : 1][4];
#pragma unroll
    for (int i = 0; i < MI; i++)
#pragma unroll
        for (int j = 0; j < 4; j++) {
            acc[i][j] = (f4v){0.f, 0.f, 0.f, 0.f};
            if (EPI == 2) accg[i][j] = (f4v){0.f, 0.f, 0.f, 0.f};
        }

    // staging: lane covers row (wid*R + (lane>>2)), 16B col chunk (lane&3)
    const int scol = (lane & 3) * 8;
    const int arow = wid * 32 + (lane >> 2);
    const int brow = (EPI == 2) ? (wid * 16 + (lane >> 2)) : arow;
    const bf16* Ag0 = A + (size_t)(m0 + arow) * lda + scol;
    const bf16* Bg0 = Bt + (size_t)(n0 + brow) * ldb + scol;
    const bf16* Gg0 = (EPI == 2) ? (Bt + (size_t)(INNER + n0 + brow) * ldb + scol) : Bg0;

    auto stage = [&](int buf, int kk) {
        gl_lds16(Ag0 + kk, &A_lds[buf][wid * 1024]);
        gl_lds16(Ag0 + kk + (size_t)16 * lda, &A_lds[buf][wid * 1024 + 512]);
        if constexpr (EPI == 2) {
            gl_lds16(Bg0 + kk, &B_lds[buf][wid * 512]);
            gl_lds16(Gg0 + kk, &G_lds[buf * 2048 + wid * 512]);
        } else {
            gl_lds16(Bg0 + kk, &B_lds[buf][wid * 1024]);
            gl_lds16(Bg0 + kk + (size_t)16 * ldb, &B_lds[buf][wid * 1024 + 512]);
        }
    };

    stage(0, 0);
    __syncthreads();
    int buf = 0;
    for (int k0 = 0; k0 < K; k0 += 32, buf ^= 1) {
        if (k0 + 32 < K) stage(buf ^ 1, k0 + 32);   // prefetch next tile

        s8v af[MI], bfr[4];
#pragma unroll
        for (int i = 0; i < MI; i++)
            af[i] = *(const s8v*)&A_lds[buf][(wm + i * 16 + lrow) * 32 + lgrp * 8];
#pragma unroll
        for (int j = 0; j < 4; j++)
            bfr[j] = *(const s8v*)&B_lds[buf][(wn + j * 16 + lrow) * 32 + lgrp * 8];
#pragma unroll
        for (int i = 0; i < MI; i++)
#pragma unroll
            for (int j = 0; j < 4; j++)
                acc[i][j] = __builtin_amdgcn_mfma_f32_16x16x32_bf16(af[i], bfr[j], acc[i][j], 0, 0, 0);
        if constexpr (EPI == 2) {
            s8v gfr[4];
#pragma unroll
            for (int j = 0; j < 4; j++)
                gfr[j] = *(const s8v*)&G_lds[buf * 2048 + (j * 16 + lrow) * 32 + lgrp * 8];
#pragma unroll
            for (int i = 0; i < MI; i++)
#pragma unroll
                for (int j = 0; j < 4; j++)
                    accg[i][j] = __builtin_amdgcn_mfma_f32_16x16x32_bf16(af[i], gfr[j], accg[i][j], 0, 0, 0);
        }
        __syncthreads();   // prefetch drained + all reads of buf done
    }

    // ---- epilogue: C/D layout col=lane&15, row=(lane>>4)*4+reg ----
#pragma unroll
    for (int i = 0; i < MI; i++) {
#pragma unroll
        for (int r = 0; r < 4; r++) {
            int m = m0 + wm + i * 16 + lgrp * 4 + r;
#pragma unroll
            for (int j = 0; j < 4; j++) {
                int n = n0 + wn + j * 16 + lrow;
                float v = acc[i][j][r];
                if (EPI == 0) {
                    ((bf16*)C)[(size_t)m * ldc + n] = f2b(v);
                } else if (EPI == 1) {
                    v += bias[n] + res[(size_t)m * ldres + n];
                    ((float*)C)[(size_t)m * ldc + n] = v;
                } else {
                    float p = v + bias[n];
                    float g = accg[i][j][r] + bias[INNER + n];
                    float gl = 0.5f * g * (1.f + erff(g * 0.70710678118654752f));
                    ((bf16*)C)[(size_t)m * ldc + n] = f2b(p * gl);
                }
            }
        }
    }
}

// =====================================================================
// LEGACY kernels (fallback when workspace too small for weight scratch)
// =====================================================================
template <int EPI>
__global__ __launch_bounds__(256) void gemm_mfma(
    const bf16* __restrict__ A, int lda,
    const float* __restrict__ B, int ldb,
    void* __restrict__ C, int ldc,
    const float* __restrict__ bias,
    const float* __restrict__ res, int ldres,
    int M, int N, int K) {
    constexpr int LR = 40;
    __shared__ short A_lds[128 * LR];
    __shared__ short B_lds[128 * LR];
    __shared__ short G_lds[EPI == 2 ? 128 * LR : 4];

    const int t    = threadIdx.x;
    const int wid  = t >> 6, lane = t & 63;
    const int lrow = lane & 15, lgrp = lane >> 4;
    const int m0   = blockIdx.y * 128, n0 = blockIdx.x * 128;
    const int wm   = (wid & 1) * 64, wn = (wid >> 1) * 64;

    f4v acc[4][4];
    f4v accg[4][4];
#pragma unroll
    for (int i = 0; i < 4; i++)
#pragma unroll
        for (int j = 0; j < 4; j++) {
            acc[i][j] = (f4v){0.f, 0.f, 0.f, 0.f};
            if (EPI == 2) accg[i][j] = (f4v){0.f, 0.f, 0.f, 0.f};
        }

    const int b_np = (t & 31) * 4;
    const int b_kp = (t >> 5) * 4;

    for (int k0 = 0; k0 < K; k0 += 32) {
#pragma unroll
        for (int c = 0; c < 2; c++) {
            int idx = t + c * 256;
            int row = idx >> 2, g = (idx & 3) * 8;
            uint4 v = *(const uint4*)(A + (size_t)(m0 + row) * lda + k0 + g);
            *(uint4*)&A_lds[row * LR + g] = v;
        }
        {
            const float* bp = B + (size_t)(k0 + b_kp) * ldb + n0 + b_np;
            float4 r0 = *(const float4*)(bp);
            float4 r1 = *(const float4*)(bp + ldb);
            float4 r2 = *(const float4*)(bp + 2 * ldb);
            float4 r3 = *(const float4*)(bp + 3 * ldb);
            *(s4v*)&B_lds[(b_np + 0) * LR + b_kp] = (s4v){f2s(r0.x), f2s(r1.x), f2s(r2.x), f2s(r3.x)};
            *(s4v*)&B_lds[(b_np + 1) * LR + b_kp] = (s4v){f2s(r0.y), f2s(r1.y), f2s(r2.y), f2s(r3.y)};
            *(s4v*)&B_lds[(b_np + 2) * LR + b_kp] = (s4v){f2s(r0.z), f2s(r1.z), f2s(r2.z), f2s(r3.z)};
            *(s4v*)&B_lds[(b_np + 3) * LR + b_kp] = (s4v){f2s(r0.w), f2s(r1.w), f2s(r2.w), f2s(r3.w)};
        }
        if (EPI == 2) {
            const float* gp = B + (size_t)(k0 + b_kp) * ldb + INNER + n0 + b_np;
            float4 r0 = *(const float4*)(gp);
            float4 r1 = *(const float4*)(gp + ldb);
            float4 r2 = *(const float4*)(gp + 2 * ldb);
            float4 r3 = *(const float4*)(gp + 3 * ldb);
            *(s4v*)&G_lds[(b_np + 0) * LR + b_kp] = (s4v){f2s(r0.x), f2s(r1.x), f2s(r2.x), f2s(r3.x)};
            *(s4v*)&G_lds[(b_np + 1) * LR + b_kp] = (s4v){f2s(r0.y), f2s(r1.y), f2s(r2.y), f2s(r3.y)};
            *(s4v*)&G_lds[(b_np + 2) * LR + b_kp] = (s4v){f2s(r0.z), f2s(r1.z), f2s(r2.z), f2s(r3.z)};
            *(s4v*)&G_lds[(b_np + 3) * LR + b_kp] = (s4v){f2s(r0.w), f2s(r1.w), f2s(r2.w), f2s(r3.w)};
        }
        __syncthreads();
        s8v af[4], bfr[4];
#pragma unroll
        for (int i = 0; i < 4; i++)
            af[i] = *(const s8v*)&A_lds[(wm + i * 16 + lrow) * LR + lgrp * 8];
#pragma unroll
        for (int j = 0; j < 4; j++)
            bfr[j] = *(const s8v*)&B_lds[(wn + j * 16 + lrow) * LR + lgrp * 8];
#pragma unroll
        for (int i = 0; i < 4; i++)
#pragma unroll
            for (int j = 0; j < 4; j++)
                acc[i][j] = __builtin_amdgcn_mfma_f32_16x16x32_bf16(af[i], bfr[j], acc[i][j], 0, 0, 0);
        if (EPI == 2) {
            s8v gfr[4];
#pragma unroll
            for (int j = 0; j < 4; j++)
                gfr[j] = *(const s8v*)&G_lds[(wn + j * 16 + lrow) * LR + lgrp * 8];
#pragma unroll
            for (int i = 0; i < 4; i++)
#pragma unroll
                for (int j = 0; j < 4; j++)
                    accg[i][j] = __builtin_amdgcn_mfma_f32_16x16x32_bf16(af[i], gfr[j], accg[i][j], 0, 0, 0);
        }
        __syncthreads();
    }
#pragma unroll
    for (int i = 0; i < 4; i++) {
#pragma unroll
        for (int r = 0; r < 4; r++) {
            int m = m0 + wm + i * 16 + lgrp * 4 + r;
#pragma unroll
            for (int j = 0; j < 4; j++) {
                int n = n0 + wn + j * 16 + lrow;
                float v = acc[i][j][r];
                if (EPI == 0) {
                    ((bf16*)C)[(size_t)m * ldc + n] = f2b(v);
                } else if (EPI == 1) {
                    v += bias[n] + res[(size_t)m * ldres + n];
                    ((float*)C)[(size_t)m * ldc + n] = v;
                } else {
                    float p = v + bias[n];
                    float g = accg[i][j][r] + bias[INNER + n];
                    float gl = 0.5f * g * (1.f + erff(g * 0.70710678118654752f));
                    ((bf16*)C)[(size_t)m * ldc + n] = f2b(p * gl);
                }
            }
        }
    }
}

__global__ __launch_bounds__(256) void gemm_valu(
    const float* __restrict__ A, int lda,
    const float* __restrict__ B, int ldb,
    bf16* __restrict__ C, int ldc,
    int M, int N, int K) {
    __shared__ float As[16][65];
    __shared__ float Bs[16][65];
    const int t  = threadIdx.x;
    const int m0 = blockIdx.y * 64, n0 = blockIdx.x * 64;
    const int ar = t >> 2, ak = (t & 3) * 4;
    const int bk = t >> 4, bn = (t & 15) * 4;
    const int ty = t >> 4, tx = t & 15;
    float acc[4][4];
#pragma unroll
    for (int i = 0; i < 4; i++)
#pragma unroll
        for (int j = 0; j < 4; j++) acc[i][j] = 0.f;

    for (int k0 = 0; k0 < K; k0 += 16) {
        {
            int m = m0 + ar;
            float tmp[4];
            if (m < M) load4(A + (size_t)m * lda + k0 + ak, tmp);
            else { tmp[0] = tmp[1] = tmp[2] = tmp[3] = 0.f; }
            As[ak + 0][ar] = tmp[0]; As[ak + 1][ar] = tmp[1];
            As[ak + 2][ar] = tmp[2]; As[ak + 3][ar] = tmp[3];
        }
        {
            float tmp[4];
            load4(B + (size_t)(k0 + bk) * ldb + n0 + bn, tmp);
            Bs[bk][bn + 0] = tmp[0]; Bs[bk][bn + 1] = tmp[1];
            Bs[bk][bn + 2] = tmp[2]; Bs[bk][bn + 3] = tmp[3];
        }
        __syncthreads();
#pragma unroll
        for (int k = 0; k < 16; k++) {
            float a[4], b[4];
#pragma unroll
            for (int i = 0; i < 4; i++) a[i] = As[k][ty * 4 + i];
#pragma unroll
            for (int j = 0; j < 4; j++) b[j] = Bs[k][tx * 4 + j];
#pragma unroll
            for (int i = 0; i < 4; i++)
#pragma unroll
                for (int j = 0; j < 4; j++) acc[i][j] += a[i] * b[j];
        }
        __syncthreads();
    }
#pragma unroll
    for (int i = 0; i < 4; i++) {
        int m = m0 + ty * 4 + i;
        if (m >= M) continue;
#pragma unroll
        for (int j = 0; j < 4; j++) {
            int n = n0 + tx * 4 + j;
            C[(size_t)m * ldc + n] = f2b(acc[i][j]);
        }
    }
}

#define SOFTMAX_SCALE 0.07905694150420949f  // 1/sqrt(160)

// =====================================================================
// attn1 (sparse-causal, 512 keys) — MFMA flash-attention.
// q/k/v may live in a fused QKV buffer: row stride = ldq. Output stride DIM.
// =====================================================================
#define A1_KP 168   // K LDS pitch (shorts): 160 + 8 pad
#define A1_VP 72    // V^T pitch (shorts):   64 + 8 pad
#define A1_PP 72    // P  pitch (shorts)

__global__ __launch_bounds__(256) void attn1_mfma(const bf16* __restrict__ q,
                                                  const bf16* __restrict__ k,
                                                  const bf16* __restrict__ v,
                                                  int ldq,
                                                  bf16* __restrict__ o) {
    __shared__ short K_lds[64 * A1_KP];
    __shared__ short Vt_lds[160 * A1_VP];
    __shared__ short P_lds[4 * 16 * A1_PP];

    const int t = threadIdx.x;
    const int wid = t >> 6, lane = t & 63;
    const int lrow = lane & 15, lgrp = lane >> 4;
    const int bx = blockIdx.x, hd = blockIdx.y, bfi = blockIdx.z;
    const int bi = bfi >> 4, fi = bfi & 15;
    const int former = fi > 0 ? fi - 1 : 0;
    const int qrow0 = bfi * TOK + bx * 64 + wid * 16;

    s8v qf[5];
    {
        const bf16* qp = q + (size_t)(qrow0 + lrow) * ldq + hd * DH + lgrp * 8;
#pragma unroll
        for (int ks = 0; ks < 5; ks++)
            qf[ks] = *(const s8v*)(qp + ks * 32);
    }

    f4v oacc[10];
#pragma unroll
    for (int dg = 0; dg < 10; dg++) oacc[dg] = (f4v){0.f, 0.f, 0.f, 0.f};
    float m_run[4], l_run[4];
#pragma unroll
    for (int r = 0; r < 4; r++) { m_run[r] = -1e30f; l_run[r] = 0.f; }

    short* P_w = P_lds + wid * 16 * A1_PP;

    for (int c = 0; c < 8; c++) {
        const int kf = (c < 4) ? 0 : former;
        const size_t krow0 = (size_t)(bi * FRAMES + kf) * TOK + (c & 3) * 64;

        __syncthreads();
#pragma unroll
        for (int it = 0; it < 5; it++) {
            int idx = t + it * 256;
            int jr = idx / 20, g = idx % 20;
            const bf16* kp = k + (krow0 + jr) * ldq + hd * DH + g * 8;
            *(uint4*)&K_lds[jr * A1_KP + g * 8] = *(const uint4*)kp;
            s8v vv = *(const s8v*)(v + (krow0 + jr) * ldq + hd * DH + g * 8);
#pragma unroll
            for (int i = 0; i < 8; i++) {
                int d = g * 8 + i;
                Vt_lds[d * A1_VP + (jr ^ (d & 56))] = vv[i];
            }
        }
        __syncthreads();

        f4v sacc[4];
#pragma unroll
        for (int kg = 0; kg < 4; kg++) {
            sacc[kg] = (f4v){0.f, 0.f, 0.f, 0.f};
#pragma unroll
            for (int ks = 0; ks < 5; ks++) {
                s8v kfr = *(const s8v*)&K_lds[(kg * 16 + lrow) * A1_KP + ks * 32 + lgrp * 8];
                sacc[kg] = __builtin_amdgcn_mfma_f32_16x16x32_bf16(qf[ks], kfr, sacc[kg], 0, 0, 0);
            }
        }

        float mc[4];
#pragma unroll
        for (int r = 0; r < 4; r++) {
            float mm = fmaxf(fmaxf(sacc[0][r], sacc[1][r]), fmaxf(sacc[2][r], sacc[3][r]));
            mc[r] = mm * SOFTMAX_SCALE;
        }
#pragma unroll
        for (int x = 1; x < 16; x <<= 1)
#pragma unroll
            for (int r = 0; r < 4; r++)
                mc[r] = fmaxf(mc[r], __shfl_xor(mc[r], x));

        float p[4][4], rs[4];
#pragma unroll
        for (int r = 0; r < 4; r++) {
            float mn = fmaxf(m_run[r], mc[r]);
            float sc = __expf(m_run[r] - mn);
            m_run[r] = mn;
            l_run[r] *= sc;
#pragma unroll
            for (int dg = 0; dg < 10; dg++) oacc[dg][r] *= sc;
            float acc = 0.f;
#pragma unroll
            for (int kg = 0; kg < 4; kg++) {
                float e = __expf(sacc[kg][r] * SOFTMAX_SCALE - mn);
                p[kg][r] = e; acc += e;
            }
            rs[r] = acc;
        }
#pragma unroll
        for (int x = 1; x < 16; x <<= 1)
#pragma unroll
            for (int r = 0; r < 4; r++)
                rs[r] += __shfl_xor(rs[r], x);
#pragma unroll
        for (int r = 0; r < 4; r++) l_run[r] += rs[r];

#pragma unroll
        for (int kg = 0; kg < 4; kg++)
#pragma unroll
            for (int r = 0; r < 4; r++)
                P_w[(lgrp * 4 + r) * A1_PP + kg * 16 + lrow] = f2s(p[kg][r]);
        __syncthreads();

        s8v pa[2];
#pragma unroll
        for (int ks2 = 0; ks2 < 2; ks2++)
            pa[ks2] = *(const s8v*)&P_w[lrow * A1_PP + ks2 * 32 + lgrp * 8];
#pragma unroll
        for (int dg = 0; dg < 10; dg++) {
            int dd = dg * 16 + lrow;
#pragma unroll
            for (int ks2 = 0; ks2 < 2; ks2++) {
                s8v vfr = *(const s8v*)&Vt_lds[dd * A1_VP + ((ks2 * 32 + lgrp * 8) ^ (dd & 56))];
                oacc[dg] = __builtin_amdgcn_mfma_f32_16x16x32_bf16(pa[ks2], vfr, oacc[dg], 0, 0, 0);
            }
        }
    }

    float invl[4];
#pragma unroll
    for (int r = 0; r < 4; r++) invl[r] = 1.f / l_run[r];
#pragma unroll
    for (int dg = 0; dg < 10; dg++) {
#pragma unroll
        for (int r = 0; r < 4; r++) {
            int qq = qrow0 + lgrp * 4 + r;
            o[(size_t)qq * DIM + hd * DH + dg * 16 + lrow] = f2b(oacc[dg][r] * invl[r]);
        }
    }
}

// =====================================================================
// attn2 (cross, 77 keys) — MFMA flash-attention, 2 key-chunks, masked.
// k/v have row stride ldk (fused KV buffer); pad rows are exact zeros.
// =====================================================================
__global__ __launch_bounds__(256) void attn2_mfma(const bf16* __restrict__ q,
                                                  const bf16* __restrict__ k,
                                                  const bf16* __restrict__ v,
                                                  int ldk,
                                                  bf16* __restrict__ o) {
    __shared__ short K_lds[64 * A1_KP];
    __shared__ short Vt_lds[160 * A1_VP];
    __shared__ short P_lds[4 * 16 * A1_PP];

    const int t = threadIdx.x;
    const int wid = t >> 6, lane = t & 63;
    const int lrow = lane & 15, lgrp = lane >> 4;
    const int bx = blockIdx.x, hd = blockIdx.y, bfi = blockIdx.z;
    const int qrow0 = bfi * TOK + bx * 64 + wid * 16;

    s8v qf[5];
    {
        const bf16* qp = q + (size_t)(qrow0 + lrow) * DIM + hd * DH + lgrp * 8;
#pragma unroll
        for (int ks = 0; ks < 5; ks++)
            qf[ks] = *(const s8v*)(qp + ks * 32);
    }

    f4v oacc[10];
#pragma unroll
    for (int dg = 0; dg < 10; dg++) oacc[dg] = (f4v){0.f, 0.f, 0.f, 0.f};
    float m_run[4], l_run[4];
#pragma unroll
    for (int r = 0; r < 4; r++) { m_run[r] = -1e30f; l_run[r] = 0.f; }

    short* P_w = P_lds + wid * 16 * A1_PP;

    for (int c = 0; c < 2; c++) {
        // key rows c*64 .. c*64+63; global row = bfi*ESEQ + key (stays < EPAD)
        const size_t krow0 = (size_t)bfi * ESEQ + c * 64;

        __syncthreads();
#pragma unroll
        for (int it = 0; it < 5; it++) {
            int idx = t + it * 256;
            int jr = idx / 20, g = idx % 20;
            const bf16* kp = k + (krow0 + jr) * ldk + hd * DH + g * 8;
            *(uint4*)&K_lds[jr * A1_KP + g * 8] = *(const uint4*)kp;
            s8v vv = *(const s8v*)(v + (krow0 + jr) * ldk + hd * DH + g * 8);
#pragma unroll
            for (int i = 0; i < 8; i++) {
                int d = g * 8 + i;
                Vt_lds[d * A1_VP + (jr ^ (d & 56))] = vv[i];
            }
        }
        __syncthreads();

        f4v sacc[4];
#pragma unroll
        for (int kg = 0; kg < 4; kg++) {
            sacc[kg] = (f4v){0.f, 0.f, 0.f, 0.f};
#pragma unroll
            for (int ks = 0; ks < 5; ks++) {
                s8v kfr = *(const s8v*)&K_lds[(kg * 16 + lrow) * A1_KP + ks * 32 + lgrp * 8];
                sacc[kg] = __builtin_amdgcn_mfma_f32_16x16x32_bf16(qf[ks], kfr, sacc[kg], 0, 0, 0);
            }
            // mask keys >= ESEQ (chunk 1: key = 64 + kg*16 + lrow)
            if (c == 1 && (kg > 0 || lrow >= 13))
                sacc[kg] = (f4v){-1e30f, -1e30f, -1e30f, -1e30f};
        }

        float mc[4];
#pragma unroll
        for (int r = 0; r < 4; r++) {
            float mm = fmaxf(fmaxf(sacc[0][r], sacc[1][r]), fmaxf(sacc[2][r], sacc[3][r]));
            mc[r] = mm * SOFTMAX_SCALE;
        }
#pragma unroll
        for (int x = 1; x < 16; x <<= 1)
#pragma unroll
            for (int r = 0; r < 4; r++)
                mc[r] = fmaxf(mc[r], __shfl_xor(mc[r], x));

        float p[4][4], rs[4];
#pragma unroll
        for (int r = 0; r < 4; r++) {
            float mn = fmaxf(m_run[r], mc[r]);
            float sc = __expf(m_run[r] - mn);
            m_run[r] = mn;
            l_run[r] *= sc;
#pragma unroll
            for (int dg = 0; dg < 10; dg++) oacc[dg][r] *= sc;
            float acc = 0.f;
#pragma unroll
            for (int kg = 0; kg < 4; kg++) {
                float e = __expf(sacc[kg][r] * SOFTMAX_SCALE - mn);
                p[kg][r] = e; acc += e;
            }
            rs[r] = acc;
        }
#pragma unroll
        for (int x = 1; x < 16; x <<= 1)
#pragma unroll
            for (int r = 0; r < 4; r++)
                rs[r] += __shfl_xor(rs[r], x);
#pragma unroll
        for (int r = 0; r < 4; r++) l_run[r] += rs[r];

#pragma unroll
        for (int kg = 0; kg < 4; kg++)
#pragma unroll
            for (int r = 0; r < 4; r++)
                P_w[(lgrp * 4 + r) * A1_PP + kg * 16 + lrow] = f2s(p[kg][r]);
        __syncthreads();

        s8v pa[2];
#pragma unroll
        for (int ks2 = 0; ks2 < 2; ks2++)
            pa[ks2] = *(const s8v*)&P_w[lrow * A1_PP + ks2 * 32 + lgrp * 8];
#pragma unroll
        for (int dg = 0; dg < 10; dg++) {
            int dd = dg * 16 + lrow;
#pragma unroll
            for (int ks2 = 0; ks2 < 2; ks2++) {
                s8v vfr = *(const s8v*)&Vt_lds[dd * A1_VP + ((ks2 * 32 + lgrp * 8) ^ (dd & 56))];
                oacc[dg] = __builtin_amdgcn_mfma_f32_16x16x32_bf16(pa[ks2], vfr, oacc[dg], 0, 0, 0);
            }
        }
    }

    float invl[4];
#pragma unroll
    for (int r = 0; r < 4; r++) invl[r] = 1.f / l_run[r];
#pragma unroll
    for (int dg = 0; dg < 10; dg++) {
#pragma unroll
        for (int r = 0; r < 4; r++) {
            int qq = qrow0 + lgrp * 4 + r;
            o[(size_t)qq * DIM + hd * DH + dg * 16 + lrow] = f2b(oacc[dg][r] * invl[r]);
        }
    }
}

// ---- attn2 legacy scalar (tier0 fallback) ----
__global__ __launch_bounds__(256) void attn2_kernel(const bf16* __restrict__ q,
                                                    const bf16* __restrict__ k,
                                                    const bf16* __restrict__ v,
                                                    bf16* __restrict__ o) {
    __shared__ float sQ[DH];
    __shared__ float sS[128];
    __shared__ float red[256];
    int t = threadIdx.x;
    int qi = blockIdx.x, hd = blockIdx.y, bfi = blockIdx.z;
    size_t qbase = ((size_t)(bfi * TOK + qi)) * DIM + hd * DH;
    if (t < DH) sQ[t] = b2f(q[qbase + t]);
    __syncthreads();
    if (t < ESEQ) {
        size_t kbase = ((size_t)(bfi * ESEQ + t)) * DIM + hd * DH;
        float acc = 0.f;
        for (int d = 0; d < DH; d++) acc += sQ[d] * b2f(k[kbase + d]);
        sS[t] = acc * SOFTMAX_SCALE;
    }
    __syncthreads();
    float lm = (t < ESEQ) ? sS[t] : -1e30f;
    red[t] = lm; __syncthreads();
    for (int s = 128; s > 0; s >>= 1) { if (t < s) red[t] = fmaxf(red[t], red[t + s]); __syncthreads(); }
    float mx = red[0]; __syncthreads();
    float ls = 0.f;
    if (t < ESEQ) { float e = __expf(sS[t] - mx); sS[t] = e; ls = e; }
    red[t] = ls; __syncthreads();
    for (int s = 128; s > 0; s >>= 1) { if (t < s) red[t] += red[t + s]; __syncthreads(); }
    float inv = 1.f / red[0];
    __syncthreads();
    if (t < DH) {
        float acc = 0.f;
        for (int j = 0; j < ESEQ; j++) {
            size_t vbase = ((size_t)(bfi * ESEQ + j)) * DIM + hd * DH;
            acc += sS[j] * b2f(v[vbase + t]);
        }
        o[qbase + t] = f2b(acc * inv);
    }
}

// =====================================================================
// attnt (temporal, 16 keys) — vectorized full-block kernel.
// Grid (BATCH*TOK, HEADS), 256 thr. Stage Q/K/V (16x160, pitch 168) via
// b128; scores on a 16x16 thread grid with shfl-group softmax; PV as 320
// (query, d-group-of-8) assignments with b128 V reads + one 16B store.
// =====================================================================
#define AT_P 168
__global__ __launch_bounds__(256) void attnt_vec(const bf16* __restrict__ q,
                                                 const bf16* __restrict__ k,
                                                 const bf16* __restrict__ v,
                                                 int ldq,
                                                 bf16* __restrict__ o) {
    __shared__ short Q_l[16 * AT_P], K_l[16 * AT_P], V_l[16 * AT_P];
    __shared__ float P_l[16][17];
    const int t = threadIdx.x;
    const int hd = blockIdx.y;
    const int z = blockIdx.x;
    const int bi = z >> 8, ti = z & 255;

#pragma unroll
    for (int it = 0; it < 2; it++) {
        int c = t + it * 256;
        if (c < 320) {
            int f = c / 20, g = c % 20;
            size_t row = (size_t)(bi * FRAMES + f) * TOK + ti;
            const bf16* qp = q + row * ldq + hd * DH + g * 8;
            const bf16* kp = k + row * ldq + hd * DH + g * 8;
            const bf16* vp = v + row * ldq + hd * DH + g * 8;
            *(uint4*)&Q_l[f * AT_P + g * 8] = *(const uint4*)qp;
            *(uint4*)&K_l[f * AT_P + g * 8] = *(const uint4*)kp;
            *(uint4*)&V_l[f * AT_P + g * 8] = *(const uint4*)vp;
        }
    }
    __syncthreads();

    // ---- scores: thread (fq = t>>4, fk = t&15) ----
    const int fq = t >> 4, fk = t & 15;
    float acc = 0.f;
#pragma unroll
    for (int dg = 0; dg < 20; dg++) {
        s8v qv = *(const s8v*)&Q_l[fq * AT_P + dg * 8];
        s8v kv = *(const s8v*)&K_l[fk * AT_P + dg * 8];
#pragma unroll
        for (int e = 0; e < 8; e++)
            acc += us2f((unsigned short)qv[e]) * us2f((unsigned short)kv[e]);
    }
    acc *= SOFTMAX_SCALE;
    float mx = acc;
#pragma unroll
    for (int x = 1; x < 16; x <<= 1) mx = fmaxf(mx, __shfl_xor(mx, x));
    float ex = __expf(acc - mx);
    float sm = ex;
#pragma unroll
    for (int x = 1; x < 16; x <<= 1) sm += __shfl_xor(sm, x);
    P_l[fq][fk] = ex / sm;
    __syncthreads();

    // ---- PV: assignments a = (dg = a>>4, pq = a&15), 320 total ----
#pragma unroll
    for (int it = 0; it < 2; it++) {
        int a = t + it * 256;
        if (a < 320) {
            int pq = a & 15, dg = a >> 4;
            float pr[16];
#pragma unroll
            for (int j = 0; j < 16; j++) pr[j] = P_l[pq][j];
            float ov[8] = {0.f, 0.f, 0.f, 0.f, 0.f, 0.f, 0.f, 0.f};
#pragma unroll
            for (int j = 0; j < 16; j++) {
                s8v vv = *(const s8v*)&V_l[j * AT_P + dg * 8];
#pragma unroll
                for (int i = 0; i < 8; i++)
                    ov[i] += pr[j] * us2f((unsigned short)vv[i]);
            }
            s8v o8;
#pragma unroll
            for (int i = 0; i < 8; i++) o8[i] = f2s(ov[i]);
            size_t orow = (size_t)(bi * FRAMES + pq) * TOK + ti;
            *(s8v*)(o + orow * DIM + hd * DH + dg * 8) = o8;
        }
    }
}

// ---- temporal self-attn legacy scalar (tier0 fallback) ----
__global__ __launch_bounds__(256) void attnt_kernel(const bf16* __restrict__ q,
                                                    const bf16* __restrict__ k,
                                                    const bf16* __restrict__ v,
                                                    int ldq,
                                                    bf16* __restrict__ o) {
    __shared__ float sQ[DH];
    __shared__ float sS[16];
    __shared__ float red[256];
    int t = threadIdx.x;
    int qfi = blockIdx.x, hd = blockIdx.y, z = blockIdx.z;
    int bi = z >> 8, ti = z & 255;
    size_t qrow = (size_t)(bi * FRAMES + qfi) * TOK + ti;
    if (t < DH) sQ[t] = b2f(q[qrow * ldq + hd * DH + t]);
    __syncthreads();
    if (t < FRAMES) {
        size_t krow = (size_t)(bi * FRAMES + t) * TOK + ti;
        float acc = 0.f;
        for (int d = 0; d < DH; d++) acc += sQ[d] * b2f(k[krow * ldq + hd * DH + d]);
        sS[t] = acc * SOFTMAX_SCALE;
    }
    __syncthreads();
    float lm = (t < FRAMES) ? sS[t] : -1e30f;
    red[t] = lm; __syncthreads();
    for (int s = 128; s > 0; s >>= 1) { if (t < s) red[t] = fmaxf(red[t], red[t + s]); __syncthreads(); }
    float mx = red[0]; __syncthreads();
    float ls = 0.f;
    if (t < FRAMES) { float e = __expf(sS[t] - mx); sS[t] = e; ls = e; }
    red[t] = ls; __syncthreads();
    for (int s = 128; s > 0; s >>= 1) { if (t < s) red[t] += red[t + s]; __syncthreads(); }
    float inv = 1.f / red[0];
    __syncthreads();
    if (t < DH) {
        float acc = 0.f;
        for (int j = 0; j < FRAMES; j++) {
            size_t vrow = (size_t)(bi * FRAMES + j) * TOK + ti;
            acc += sS[j] * b2f(v[vrow * ldq + hd * DH + t]);
        }
        o[qrow * DIM + hd * DH + t] = f2b(acc * inv);
    }
}

extern "C" void kernel_launch(void* const* d_in, const int* in_sizes, int n_in,
                              void* d_out, int out_size, void* d_ws, size_t ws_size,
                              hipStream_t stream) {
    (void)in_sizes; (void)n_in; (void)out_size;
    const float* hs   = (const float*)d_in[0];
    const float* enc  = (const float*)d_in[1];
    const float* n1w  = (const float*)d_in[2];
    const float* n1b  = (const float*)d_in[3];
    const float* a1wq = (const float*)d_in[4];
    const float* a1wk = (const float*)d_in[5];
    const float* a1wv = (const float*)d_in[6];
    const float* a1wo = (const float*)d_in[7];
    const float* a1bo = (const float*)d_in[8];
    const float* n2w  = (const float*)d_in[9];
    const float* n2b  = (const float*)d_in[10];
    const float* a2wq = (const float*)d_in[11];
    const float* a2wk = (const float*)d_in[12];
    const float* a2wv = (const float*)d_in[13];
    const float* a2wo = (const float*)d_in[14];
    const float* a2bo = (const float*)d_in[15];
    const float* n3w  = (const float*)d_in[16];
    const float* n3b  = (const float*)d_in[17];
    const float* ffw1 = (const float*)d_in[18];
    const float* ffb1 = (const float*)d_in[19];
    const float* ffw2 = (const float*)d_in[20];
    const float* ffb2 = (const float*)d_in[21];
    const float* ntw  = (const float*)d_in[22];
    const float* ntb  = (const float*)d_in[23];
    const float* atwq = (const float*)d_in[24];
    const float* atwk = (const float*)d_in[25];
    const float* atwv = (const float*)d_in[26];
    const float* atwo = (const float*)d_in[27];
    const float* atbo = (const float*)d_in[28];

    char* wp = (char*)d_ws;
    auto carve = [&](size_t bytes) -> char* {
        char* p = wp; wp += (bytes + 255) & ~((size_t)255); return p;
    };
    const size_t BUF = (size_t)ROWS * DIM * 2;   // 20,971,520
    const size_t W_FULL = 26214400;              // ffw1t: 10240x1280 bf16
    float* out = (float*)d_out;                  // f32 residual stream in d_out
    dim3 blk(256);

    bf16* nh = (bf16*)carve(BUF);

    bool full = (ws_size >= 5 * BUF + W_FULL + 4096);
    if (!full) {
        // ------- legacy path (R1 kernel, known-good at 105 MB ws) -------
        bf16* qb = (bf16*)carve(BUF);
        bf16* kb = (bf16*)carve(BUF);
        bf16* vb = (bf16*)carve(BUF);
        bf16* ob = (bf16*)carve(BUF);
        bf16* Pb = qb;
        auto proj = [&](const bf16* A, int lda, const float* B, int ldb,
                        bf16* C, int ldc, int M, int N, int K) {
            gemm_mfma<0><<<dim3(N / 128, M / 128), blk, 0, stream>>>(
                A, lda, B, ldb, C, ldc, nullptr, nullptr, 0, M, N, K);
        };
        auto outproj = [&](const bf16* A, int lda, const float* B,
                           const float* bias, const float* res, int K) {
            gemm_mfma<1><<<dim3(DIM / 128, ROWS / 128), blk, 0, stream>>>(
                A, lda, B, DIM, out, DIM, bias, res, DIM, ROWS, DIM, K);
        };
        ln_kernel<<<dim3(ROWS), blk, 0, stream>>>(hs, n1w, n1b, nh);
        proj(nh, DIM, a1wq, DIM, qb, DIM, ROWS, DIM, DIM);
        proj(nh, DIM, a1wk, DIM, kb, DIM, ROWS, DIM, DIM);
        proj(nh, DIM, a1wv, DIM, vb, DIM, ROWS, DIM, DIM);
        attn1_mfma<<<dim3(TOK / 64, HEADS, BF), blk, 0, stream>>>(qb, kb, vb, DIM, ob);
        outproj(ob, DIM, a1wo, a1bo, hs, DIM);

        ln_kernel<<<dim3(ROWS), blk, 0, stream>>>(out, n2w, n2b, nh);
        proj(nh, DIM, a2wq, DIM, qb, DIM, ROWS, DIM, DIM);
        gemm_valu<<<dim3(DIM / 64, (EROWS + 63) / 64), blk, 0, stream>>>(enc, CROSS, a2wk, DIM, kb, DIM, EROWS, DIM, CROSS);
        gemm_valu<<<dim3(DIM / 64, (EROWS + 63) / 64), blk, 0, stream>>>(enc, CROSS, a2wv, DIM, vb, DIM, EROWS, DIM, CROSS);
        attn2_kernel<<<dim3(TOK, HEADS, BF), blk, 0, stream>>>(qb, kb, vb, ob);
        outproj(ob, DIM, a2wo, a2bo, out, DIM);

        ln_kernel<<<dim3(ROWS), blk, 0, stream>>>(out, n3w, n3b, nh);
        gemm_mfma<2><<<dim3(INNER / 128, ROWS / 128), blk, 0, stream>>>(
            nh, DIM, ffw1, 2 * INNER, Pb, INNER, ffb1, nullptr, 0, ROWS, INNER, DIM);
        outproj(Pb, INNER, ffw2, ffb2, out, INNER);

        ln_kernel<<<dim3(ROWS), blk, 0, stream>>>(out, ntw, ntb, nh);
        proj(nh, DIM, atwq, DIM, qb, DIM, ROWS, DIM, DIM);
        proj(nh, DIM, atwk, DIM, kb, DIM, ROWS, DIM, DIM);
        proj(nh, DIM, atwv, DIM, vb, DIM, ROWS, DIM, DIM);
        attnt_kernel<<<dim3(FRAMES, HEADS, BATCH * TOK), blk, 0, stream>>>(qb, kb, vb, DIM, ob);
        outproj(ob, DIM, atwo, atbo, out, DIM);
        return;
    }

    // ------- full path: bf16 B^T weights + prefetch gemm_bt + fused QKV -------
    bf16* C3 = (bf16*)carve(3 * BUF);            // fused QKV [ROWS][3840]
    bf16* ob = (bf16*)carve(BUF);
    bf16* Ws = (bf16*)carve(W_FULL);
    bf16* Pb = C3;                               // FFN intermediate spans C3+ob (84 MB)
    const size_t WQ = (size_t)DIM * DIM;
    const size_t WC = (size_t)DIM * CROSS;
    const int LDQ3 = 3 * DIM;                    // 3840

    auto projN = [&](const bf16* A, int lda, const bf16* Bt, int ldb,
                     bf16* C, int ldc, int M, int N, int K) {
        gemm_bt<0><<<dim3(N / 128, M / 128), blk, 0, stream>>>(
            A, lda, Bt, ldb, C, ldc, nullptr, nullptr, 0, M, N, K);
    };
    auto outprojN = [&](const bf16* A, int lda, const bf16* Bt, int ldb,
                        const float* bias, const float* res, int K) {
        gemm_bt<1><<<dim3(DIM / 128, ROWS / 128), blk, 0, stream>>>(
            A, lda, Bt, ldb, out, DIM, bias, res, DIM, ROWS, DIM, K);
    };

    // ---- attn1: sparse-causal self-attention (fused QKV proj, N=3840) ----
    wconv_t4<<<dim3(DIM / 64, DIM / 64, 4), blk, 0, stream>>>(
        a1wq, a1wk, a1wv, a1wo, Ws, WQ, DIM, DIM);
    ln_kernel<<<dim3(ROWS), blk, 0, stream>>>(hs, n1w, n1b, nh);
    projN(nh, DIM, Ws, DIM, C3, LDQ3, ROWS, 3 * DIM, DIM);
    attn1_mfma<<<dim3(TOK / 64, HEADS, BF), blk, 0, stream>>>(
        C3, C3 + DIM, C3 + 2 * DIM, LDQ3, ob);
    outprojN(ob, DIM, Ws + 3 * WQ, DIM, a1bo, hs, DIM);

    // ---- attn2: cross-attention (MFMA attn, padded encoder, fused KV) ----
    {
        bf16* w2q  = Ws;                         // [DIM][DIM]
        bf16* w2o  = Ws + WQ;                    // [DIM][DIM]
        bf16* w2k  = Ws + 2 * WQ;                // [DIM][CROSS]
        bf16* w2v  = w2k + WC;                   // [DIM][CROSS] (contiguous after w2k)
        bf16* encb = w2v + WC;                   // [EPAD][CROSS]
        bf16* qb2  = C3;                         // [ROWS][DIM]
        bf16* kv2  = C3 + (size_t)ROWS * DIM;    // [EPAD][2560] fused K|V
        wconv_t4<<<dim3(DIM / 64, DIM / 64, 2), blk, 0, stream>>>(
            a2wq, a2wo, nullptr, nullptr, w2q, WQ, DIM, DIM);
        wconv_t4<<<dim3(DIM / 64, CROSS / 64, 2), blk, 0, stream>>>(
            a2wk, a2wv, nullptr, nullptr, w2k, WC, DIM, CROSS);
        encconv<<<dim3(EPAD * CROSS / 1024), blk, 0, stream>>>(enc, encb);
        ln_kernel<<<dim3(ROWS), blk, 0, stream>>>(out, n2w, n2b, nh);
        projN(nh, DIM, w2q, DIM, qb2, DIM, ROWS, DIM, DIM);
        projN(encb, CROSS, w2k, CROSS, kv2, 2 * DIM, EPAD, 2 * DIM, CROSS);
        attn2_mfma<<<dim3(TOK / 64, HEADS, BF), blk, 0, stream>>>(
            qb2, kv2, kv2 + DIM, 2 * DIM, ob);
        outprojN(ob, DIM, w2o, DIM, a2bo, out, DIM);
    }

    // ---- geglu FFN ----
    wconv_t<<<dim3(2 * INNER / 64, DIM / 64), blk, 0, stream>>>(ffw1, Ws, 2 * INNER, DIM);
    ln_kernel<<<dim3(ROWS), blk, 0, stream>>>(out, n3w, n3b, nh);
    gemm_bt<2><<<dim3(INNER / 64, ROWS / 128), blk, 0, stream>>>(
        nh, DIM, Ws, DIM, Pb, INNER, ffb1, nullptr, 0, ROWS, INNER, DIM);
    wconv_t<<<dim3(DIM / 64, INNER / 64), blk, 0, stream>>>(ffw2, Ws, DIM, INNER);
    gemm_bt<1><<<dim3(DIM / 128, ROWS / 128), blk, 0, stream>>>(
        Pb, INNER, Ws, INNER, out, DIM, ffb2, out, DIM, ROWS, DIM, INNER);

    // ---- temporal self-attention (fused QKV proj + vectorized attn) ----
    wconv_t4<<<dim3(DIM / 64, DIM / 64, 4), blk, 0, stream>>>(
        atwq, atwk, atwv, atwo, Ws, WQ, DIM, DIM);
    ln_kernel<<<dim3(ROWS), blk, 0, stream>>>(out, ntw, ntb, nh);
    projN(nh, DIM, Ws, DIM, C3, LDQ3, ROWS, 3 * DIM, DIM);
    attnt_vec<<<dim3(BATCH * TOK, HEADS), blk, 0, stream>>>(
        C3, C3 + DIM, C3 + 2 * DIM, LDQ3, ob);
    outprojN(ob, DIM, Ws + 3 * WQ, DIM, atbo, out, DIM);
}

// Round 5
// 1190.988 us; speedup vs baseline: 4.3996x; 1.1683x over previous
//
#include <hip/hip_runtime.h>
#include <hip/hip_bf16.h>
#include <math.h>

// ---- problem constants (from reference) ----
#define DIM    1280
#define HEADS  8
#define DH     160            // DIM / HEADS
#define FRAMES 16
#define BATCH  2
#define TOK    256
#define ESEQ   77
#define INNER  5120           // 4*DIM
#define CROSS  768
#define BF     (BATCH*FRAMES) // 32
#define ROWS   (BF*TOK)       // 8192
#define EROWS  (BF*ESEQ)      // 2464
#define EPAD   2560           // EROWS padded to %128

typedef __hip_bfloat16 bf16;
typedef __attribute__((ext_vector_type(8))) short s8v;
typedef __attribute__((ext_vector_type(4))) short s4v;
typedef __attribute__((ext_vector_type(4))) float f4v;

__device__ __forceinline__ float us2f(unsigned short u) {
    union { float f; unsigned int i; } c; c.i = ((unsigned int)u) << 16; return c.f;
}
__device__ __forceinline__ float b2f(bf16 x) { return __bfloat162float(x); }
__device__ __forceinline__ bf16  f2b(float x) { return __float2bfloat16(x); }
// f32 -> bf16 bits (RNE), as short
__device__ __forceinline__ short f2s(float x) {
    union { float f; unsigned int u; } c; c.f = x;
    unsigned int r = c.u + 0x7FFF + ((c.u >> 16) & 1);
    return (short)(r >> 16);
}
__device__ __forceinline__ void load4(const float* p, float* d) {
    float4 v = *(const float4*)p; d[0] = v.x; d[1] = v.y; d[2] = v.z; d[3] = v.w;
}
// async global->LDS, 16B per lane; LDS dest is wave-uniform base + lane*16
__device__ __forceinline__ void gl_lds16(const bf16* g, short* l) {
    __builtin_amdgcn_global_load_lds(
        (const __attribute__((address_space(1))) void*)g,
        (__attribute__((address_space(3))) void*)l, 16, 0, 0);
}

// ---- LayerNorm: one block per row of DIM=1280 (256 thr x 5 elems) ----
__global__ __launch_bounds__(256) void ln_kernel(const float* __restrict__ x,
                                                 const float* __restrict__ w,
                                                 const float* __restrict__ b,
                                                 bf16* __restrict__ out) {
    __shared__ float r1[256], r2[256];
    int row = blockIdx.x, t = threadIdx.x;
    const float* xp = x + (size_t)row * DIM;
    float v[5], s = 0.f, s2 = 0.f;
#pragma unroll
    for (int i = 0; i < 5; i++) {
        float xv = xp[t + 256 * i];
        v[i] = xv; s += xv; s2 += xv * xv;
    }
    r1[t] = s; r2[t] = s2; __syncthreads();
    for (int st = 128; st > 0; st >>= 1) {
        if (t < st) { r1[t] += r1[t + st]; r2[t] += r2[t + st]; }
        __syncthreads();
    }
    float mean = r1[0] * (1.f / DIM);
    float var  = r2[0] * (1.f / DIM) - mean * mean;
    float rstd = rsqrtf(var + 1e-5f);
    bf16* op = out + (size_t)row * DIM;
#pragma unroll
    for (int i = 0; i < 5; i++) {
        int c = t + 256 * i;
        op[c] = f2b((v[i] - mean) * rstd * w[c] + b[c]);
    }
}

// ---- transpose-convert: W f32 [K][N] -> Wt bf16 [N][K]; N,K % 64 == 0 ----
__global__ __launch_bounds__(256) void wconv_t(const float* __restrict__ w,
                                               bf16* __restrict__ wt,
                                               int N, int K) {
    __shared__ float tile[64][65];
    const int n0 = blockIdx.x * 64, k0 = blockIdx.y * 64;
    const int t = threadIdx.x;
    const int tr = t >> 4;          // 0..15
    const int tc = (t & 15) * 4;    // 0..60
#pragma unroll
    for (int i = 0; i < 4; i++) {
        int kk = tr + i * 16;
        float4 vv = *(const float4*)(w + (size_t)(k0 + kk) * N + n0 + tc);
        tile[kk][tc + 0] = vv.x; tile[kk][tc + 1] = vv.y;
        tile[kk][tc + 2] = vv.z; tile[kk][tc + 3] = vv.w;
    }
    __syncthreads();
#pragma unroll
    for (int i = 0; i < 4; i++) {
        int nn = tr + i * 16;
        s4v o4 = (s4v){ f2s(tile[tc + 0][nn]), f2s(tile[tc + 1][nn]),
                        f2s(tile[tc + 2][nn]), f2s(tile[tc + 3][nn]) };
        *(s4v*)(wt + (size_t)(n0 + nn) * K + k0 + tc) = o4;
    }
}

// ---- batched transpose-convert: up to 4 same-shape weights, grid.z selects ----
__global__ __launch_bounds__(256) void wconv_t4(const float* __restrict__ w0,
                                                const float* __restrict__ w1,
                                                const float* __restrict__ w2,
                                                const float* __restrict__ w3,
                                                bf16* __restrict__ wt, size_t dstride,
                                                int N, int K) {
    const float* w = blockIdx.z == 0 ? w0 : blockIdx.z == 1 ? w1
                   : blockIdx.z == 2 ? w2 : w3;
    bf16* dst = wt + (size_t)blockIdx.z * dstride;
    __shared__ float tile[64][65];
    const int n0 = blockIdx.x * 64, k0 = blockIdx.y * 64;
    const int t = threadIdx.x;
    const int tr = t >> 4;
    const int tc = (t & 15) * 4;
#pragma unroll
    for (int i = 0; i < 4; i++) {
        int kk = tr + i * 16;
        float4 vv = *(const float4*)(w + (size_t)(k0 + kk) * N + n0 + tc);
        tile[kk][tc + 0] = vv.x; tile[kk][tc + 1] = vv.y;
        tile[kk][tc + 2] = vv.z; tile[kk][tc + 3] = vv.w;
    }
    __syncthreads();
#pragma unroll
    for (int i = 0; i < 4; i++) {
        int nn = tr + i * 16;
        s4v o4 = (s4v){ f2s(tile[tc + 0][nn]), f2s(tile[tc + 1][nn]),
                        f2s(tile[tc + 2][nn]), f2s(tile[tc + 3][nn]) };
        *(s4v*)(dst + (size_t)(n0 + nn) * K + k0 + tc) = o4;
    }
}

// ---- encoder f32 [EROWS][CROSS] -> bf16 [EPAD][CROSS], zero-padded rows ----
__global__ __launch_bounds__(256) void encconv(const float* __restrict__ e,
                                               bf16* __restrict__ eb) {
    int idx = blockIdx.x * 256 + threadIdx.x;   // 4 elems each
    int base = idx * 4;
    int row = base / CROSS;
    s4v o4;
    if (row < EROWS) {
        float4 vv = *(const float4*)(e + (size_t)base);
        o4 = (s4v){ f2s(vv.x), f2s(vv.y), f2s(vv.z), f2s(vv.w) };
    } else {
        o4 = (s4v){ 0, 0, 0, 0 };
    }
    *(s4v*)(eb + base) = o4;
}

// =====================================================================
// gemm_bt8: 256x256 tile, BK=64, 512 thr = 8 waves (2m x 4n, 128x64 each),
// double-buffered LDS (128 KB), global_load_lds staging with
// rotation-swizzled source (chunk' = (chunk+row)&7 within each 128B row)
// and matching rotated ds_read columns -> conflict-managed b128 reads.
// Prefetch-at-top + __syncthreads-at-end (proven-safe sync structure).
// EPI 0: bf16 out.  EPI 1: f32 out = acc + bias[n] + res[m][n].
// Requires M%256==0, N%256==0, K%64==0.
// =====================================================================
template <int EPI>
__global__ __launch_bounds__(512, 2) void gemm_bt8(
    const bf16* __restrict__ A, int lda,
    const bf16* __restrict__ Bt, int ldb,
    void* __restrict__ C, int ldc,
    const float* __restrict__ bias,
    const float* __restrict__ res, int ldres,
    int M, int N, int K) {
    __shared__ short lds[2][2][256 * 64];   // [buf][mat A/B][row*64 + col]

    const int t = threadIdx.x;
    const int wid = t >> 6, lane = t & 63;
    const int lrow = lane & 15, lgrp = lane >> 4;
    const int wr = wid >> 2, wc = wid & 3;
    const int m0 = blockIdx.y * 256, n0 = blockIdx.x * 256;

    f4v acc[8][4];
#pragma unroll
    for (int i = 0; i < 8; i++)
#pragma unroll
        for (int j = 0; j < 4; j++) acc[i][j] = (f4v){0.f, 0.f, 0.f, 0.f};

    // staging: wave wid covers rows [wid*32, +32), 4 insts of 8 rows per mat.
    // LDS dest linear: lane l writes bytes [l*16,+16) of its inst's 1KB slab
    // (rows r: r&7 == l>>3, chunk d == l&7). Source column pre-rotated so
    // LDS[r][d] holds logical chunk (d - r)&7.
    const int srow = wid * 32 + (lane >> 3);
    const int scol = (((lane & 7) - (lane >> 3)) & 7) * 8;   // elems
    const bf16* Ag = A + (size_t)(m0 + srow) * lda + scol;
    const bf16* Bg = Bt + (size_t)(n0 + srow) * ldb + scol;

    auto stage = [&](int b, int kt) {
#pragma unroll
        for (int s = 0; s < 4; s++) {
            gl_lds16(Ag + (size_t)kt * 64 + (size_t)(s * 8) * lda,
                     &lds[b][0][wid * 2048 + s * 512]);
            gl_lds16(Bg + (size_t)kt * 64 + (size_t)(s * 8) * ldb,
                     &lds[b][1][wid * 2048 + s * 512]);
        }
    };

    const int KT = K >> 6;
    stage(0, 0);
    __syncthreads();
    int buf = 0;
    for (int kt = 0; kt < KT; kt++, buf ^= 1) {
        if (kt + 1 < KT) stage(buf ^ 1, kt + 1);   // prefetch next K-tile
#pragma unroll
        for (int ks = 0; ks < 2; ks++) {
            // logical chunk ks*4+lgrp at row r -> stored chunk (c + r)&7; r&7 == lrow&7
            const int cc = ((ks * 4 + lgrp + lrow) & 7) * 8;
            s8v bfr[4];
#pragma unroll
            for (int j = 0; j < 4; j++)
                bfr[j] = *(const s8v*)&lds[buf][1][(wc * 64 + j * 16 + lrow) * 64 + cc];
#pragma unroll
            for (int i = 0; i < 8; i++) {
                s8v af = *(const s8v*)&lds[buf][0][(wr * 128 + i * 16 + lrow) * 64 + cc];
#pragma unroll
                for (int j = 0; j < 4; j++)
                    acc[i][j] = __builtin_amdgcn_mfma_f32_16x16x32_bf16(af, bfr[j], acc[i][j], 0, 0, 0);
            }
        }
        __syncthreads();   // prefetch drained + all reads of buf done
    }

    // ---- epilogue: C/D layout col=lane&15, row=(lane>>4)*4+reg ----
    float bs[4];
    if (EPI == 1) {
#pragma unroll
        for (int j = 0; j < 4; j++) bs[j] = bias[n0 + wc * 64 + j * 16 + lrow];
    }
#pragma unroll
    for (int i = 0; i < 8; i++) {
#pragma unroll
        for (int r = 0; r < 4; r++) {
            int m = m0 + wr * 128 + i * 16 + lgrp * 4 + r;
#pragma unroll
            for (int j = 0; j < 4; j++) {
                int n = n0 + wc * 64 + j * 16 + lrow;
                float v = acc[i][j][r];
                if (EPI == 0) {
                    ((bf16*)C)[(size_t)m * ldc + n] = f2b(v);
                } else {
                    ((float*)C)[(size_t)m * ldc + n] = v + bs[j] + res[(size_t)m * ldres + n];
                }
            }
        }
    }
}

// =====================================================================
// gemm_bt (128-tile, 2-phase prefetch) — used for the geglu GEMM (EPI 2)
// and available for EPI 0/1 odd shapes.
// =====================================================================
template <int EPI>
__global__ __launch_bounds__(256) void gemm_bt(
    const bf16* __restrict__ A, int lda,
    const bf16* __restrict__ Bt, int ldb,
    void* __restrict__ C, int ldc,
    const float* __restrict__ bias,
    const float* __restrict__ res, int ldres,
    int M, int N, int K) {
    constexpr int BN = (EPI == 2) ? 64 : 128;
    constexpr int MI = (EPI == 2) ? 2 : 4;
    __shared__ short A_lds[2][128 * 32];
    __shared__ short B_lds[2][BN * 32];
    __shared__ short G_lds[EPI == 2 ? 2 * 64 * 32 : 8];

    const int t = threadIdx.x;
    const int wid = t >> 6, lane = t & 63;
    const int lrow = lane & 15, lgrp = lane >> 4;
    const int m0 = blockIdx.y * 128, n0 = blockIdx.x * BN;
    const int wm = (EPI == 2) ? wid * 32 : (wid & 1) * 64;
    const int wn = (EPI == 2) ? 0 : (wid >> 1) * 64;

    f4v acc[MI][4];
    f4v accg[EPI == 2 ? MI : 1][4];
#pragma unroll
    for (int i = 0; i < MI; i++)
#pragma unroll
        for (int j = 0; j < 4; j++) {
            acc[i][j] = (f4v){0.f, 0.f, 0.f, 0.f};
            if (EPI == 2) accg[i][j] = (f4v){0.f, 0.f, 0.f, 0.f};
        }

    const int scol = (lane & 3) * 8;
    const int arow = wid * 32 + (lane >> 2);
    const int brow = (EPI == 2) ? (wid * 16 + (lane >> 2)) : arow;
    const bf16* Ag0 = A + (size_t)(m0 + arow) * lda + scol;
    const bf16* Bg0 = Bt + (size_t)(n0 + brow) * ldb + scol;
    const bf16* Gg0 = (EPI == 2) ? (Bt + (size_t)(INNER + n0 + brow) * ldb + scol) : Bg0;

    auto stage = [&](int buf, int kk) {
        gl_lds16(Ag0 + kk, &A_lds[buf][wid * 1024]);
        gl_lds16(Ag0 + kk + (size_t)16 * lda, &A_lds[buf][wid * 1024 + 512]);
        if constexpr (EPI == 2) {
            gl_lds16(Bg0 + kk, &B_lds[buf][wid * 512]);
            gl_lds16(Gg0 + kk, &G_lds[buf * 2048 + wid * 512]);
        } else {
            gl_lds16(Bg0 + kk, &B_lds[buf][wid * 1024]);
            gl_lds16(Bg0 + kk + (size_t)16 * ldb, &B_lds[buf][wid * 1024 + 512]);
        }
    };

    stage(0, 0);
    __syncthreads();
    int buf = 0;
    for (int k0 = 0; k0 < K; k0 += 32, buf ^= 1) {
        if (k0 + 32 < K) stage(buf ^ 1, k0 + 32);

        s8v af[MI], bfr[4];
#pragma unroll
        for (int i = 0; i < MI; i++)
            af[i] = *(const s8v*)&A_lds[buf][(wm + i * 16 + lrow) * 32 + lgrp * 8];
#pragma unroll
        for (int j = 0; j < 4; j++)
            bfr[j] = *(const s8v*)&B_lds[buf][(wn + j * 16 + lrow) * 32 + lgrp * 8];
#pragma unroll
        for (int i = 0; i < MI; i++)
#pragma unroll
            for (int j = 0; j < 4; j++)
                acc[i][j] = __builtin_amdgcn_mfma_f32_16x16x32_bf16(af[i], bfr[j], acc[i][j], 0, 0, 0);
        if constexpr (EPI == 2) {
            s8v gfr[4];
#pragma unroll
            for (int j = 0; j < 4; j++)
                gfr[j] = *(const s8v*)&G_lds[buf * 2048 + (j * 16 + lrow) * 32 + lgrp * 8];
#pragma unroll
            for (int i = 0; i < MI; i++)
#pragma unroll
                for (int j = 0; j < 4; j++)
                    accg[i][j] = __builtin_amdgcn_mfma_f32_16x16x32_bf16(af[i], gfr[j], accg[i][j], 0, 0, 0);
        }
        __syncthreads();
    }

#pragma unroll
    for (int i = 0; i < MI; i++) {
#pragma unroll
        for (int r = 0; r < 4; r++) {
            int m = m0 + wm + i * 16 + lgrp * 4 + r;
#pragma unroll
            for (int j = 0; j < 4; j++) {
                int n = n0 + wn + j * 16 + lrow;
                float v = acc[i][j][r];
                if (EPI == 0) {
                    ((bf16*)C)[(size_t)m * ldc + n] = f2b(v);
                } else if (EPI == 1) {
                    v += bias[n] + res[(size_t)m * ldres + n];
                    ((float*)C)[(size_t)m * ldc + n] = v;
                } else {
                    float p = v + bias[n];
                    float g = accg[i][j][r] + bias[INNER + n];
                    float gl = 0.5f * g * (1.f + erff(g * 0.70710678118654752f));
                    ((bf16*)C)[(size_t)m * ldc + n] = f2b(p * gl);
                }
            }
        }
    }
}

// =====================================================================
// LEGACY kernels (fallback when workspace too small for weight scratch)
// =====================================================================
template <int EPI>
__global__ __launch_bounds__(256) void gemm_mfma(
    const bf16* __restrict__ A, int lda,
    const float* __restrict__ B, int ldb,
    void* __restrict__ C, int ldc,
    const float* __restrict__ bias,
    const float* __restrict__ res, int ldres,
    int M, int N, int K) {
    constexpr int LR = 40;
    __shared__ short A_lds[128 * LR];
    __shared__ short B_lds[128 * LR];
    __shared__ short G_lds[EPI == 2 ? 128 * LR : 4];

    const int t    = threadIdx.x;
    const int wid  = t >> 6, lane = t & 63;
    const int lrow = lane & 15, lgrp = lane >> 4;
    const int m0   = blockIdx.y * 128, n0 = blockIdx.x * 128;
    const int wm   = (wid & 1) * 64, wn = (wid >> 1) * 64;

    f4v acc[4][4];
    f4v accg[4][4];
#pragma unroll
    for (int i = 0; i < 4; i++)
#pragma unroll
        for (int j = 0; j < 4; j++) {
            acc[i][j] = (f4v){0.f, 0.f, 0.f, 0.f};
            if (EPI == 2) accg[i][j] = (f4v){0.f, 0.f, 0.f, 0.f};
        }

    const int b_np = (t & 31) * 4;
    const int b_kp = (t >> 5) * 4;

    for (int k0 = 0; k0 < K; k0 += 32) {
#pragma unroll
        for (int c = 0; c < 2; c++) {
            int idx = t + c * 256;
            int row = idx >> 2, g = (idx & 3) * 8;
            uint4 v = *(const uint4*)(A + (size_t)(m0 + row) * lda + k0 + g);
            *(uint4*)&A_lds[row * LR + g] = v;
        }
        {
            const float* bp = B + (size_t)(k0 + b_kp) * ldb + n0 + b_np;
            float4 r0 = *(const float4*)(bp);
            float4 r1 = *(const float4*)(bp + ldb);
            float4 r2 = *(const float4*)(bp + 2 * ldb);
            float4 r3 = *(const float4*)(bp + 3 * ldb);
            *(s4v*)&B_lds[(b_np + 0) * LR + b_kp] = (s4v){f2s(r0.x), f2s(r1.x), f2s(r2.x), f2s(r3.x)};
            *(s4v*)&B_lds[(b_np + 1) * LR + b_kp] = (s4v){f2s(r0.y), f2s(r1.y), f2s(r2.y), f2s(r3.y)};
            *(s4v*)&B_lds[(b_np + 2) * LR + b_kp] = (s4v){f2s(r0.z), f2s(r1.z), f2s(r2.z), f2s(r3.z)};
            *(s4v*)&B_lds[(b_np + 3) * LR + b_kp] = (s4v){f2s(r0.w), f2s(r1.w), f2s(r2.w), f2s(r3.w)};
        }
        if (EPI == 2) {
            const float* gp = B + (size_t)(k0 + b_kp) * ldb + INNER + n0 + b_np;
            float4 r0 = *(const float4*)(gp);
            float4 r1 = *(const float4*)(gp + ldb);
            float4 r2 = *(const float4*)(gp + 2 * ldb);
            float4 r3 = *(const float4*)(gp + 3 * ldb);
            *(s4v*)&G_lds[(b_np + 0) * LR + b_kp] = (s4v){f2s(r0.x), f2s(r1.x), f2s(r2.x), f2s(r3.x)};
            *(s4v*)&G_lds[(b_np + 1) * LR + b_kp] = (s4v){f2s(r0.y), f2s(r1.y), f2s(r2.y), f2s(r3.y)};
            *(s4v*)&G_lds[(b_np + 2) * LR + b_kp] = (s4v){f2s(r0.z), f2s(r1.z), f2s(r2.z), f2s(r3.z)};
            *(s4v*)&G_lds[(b_np + 3) * LR + b_kp] = (s4v){f2s(r0.w), f2s(r1.w), f2s(r2.w), f2s(r3.w)};
        }
        __syncthreads();
        s8v af[4], bfr[4];
#pragma unroll
        for (int i = 0; i < 4; i++)
            af[i] = *(const s8v*)&A_lds[(wm + i * 16 + lrow) * LR + lgrp * 8];
#pragma unroll
        for (int j = 0; j < 4; j++)
            bfr[j] = *(const s8v*)&B_lds[(wn + j * 16 + lrow) * LR + lgrp * 8];
#pragma unroll
        for (int i = 0; i < 4; i++)
#pragma unroll
            for (int j = 0; j < 4; j++)
                acc[i][j] = __builtin_amdgcn_mfma_f32_16x16x32_bf16(af[i], bfr[j], acc[i][j], 0, 0, 0);
        if (EPI == 2) {
            s8v gfr[4];
#pragma unroll
            for (int j = 0; j < 4; j++)
                gfr[j] = *(const s8v*)&G_lds[(wn + j * 16 + lrow) * LR + lgrp * 8];
#pragma unroll
            for (int i = 0; i < 4; i++)
#pragma unroll
                for (int j = 0; j < 4; j++)
                    accg[i][j] = __builtin_amdgcn_mfma_f32_16x16x32_bf16(af[i], gfr[j], accg[i][j], 0, 0, 0);
        }
        __syncthreads();
    }
#pragma unroll
    for (int i = 0; i < 4; i++) {
#pragma unroll
        for (int r = 0; r < 4; r++) {
            int m = m0 + wm + i * 16 + lgrp * 4 + r;
#pragma unroll
            for (int j = 0; j < 4; j++) {
                int n = n0 + wn + j * 16 + lrow;
                float v = acc[i][j][r];
                if (EPI == 0) {
                    ((bf16*)C)[(size_t)m * ldc + n] = f2b(v);
                } else if (EPI == 1) {
                    v += bias[n] + res[(size_t)m * ldres + n];
                    ((float*)C)[(size_t)m * ldc + n] = v;
                } else {
                    float p = v + bias[n];
                    float g = accg[i][j][r] + bias[INNER + n];
                    float gl = 0.5f * g * (1.f + erff(g * 0.70710678118654752f));
                    ((bf16*)C)[(size_t)m * ldc + n] = f2b(p * gl);
                }
            }
        }
    }
}

__global__ __launch_bounds__(256) void gemm_valu(
    const float* __restrict__ A, int lda,
    const float* __restrict__ B, int ldb,
    bf16* __restrict__ C, int ldc,
    int M, int N, int K) {
    __shared__ float As[16][65];
    __shared__ float Bs[16][65];
    const int t  = threadIdx.x;
    const int m0 = blockIdx.y * 64, n0 = blockIdx.x * 64;
    const int ar = t >> 2, ak = (t & 3) * 4;
    const int bk = t >> 4, bn = (t & 15) * 4;
    const int ty = t >> 4, tx = t & 15;
    float acc[4][4];
#pragma unroll
    for (int i = 0; i < 4; i++)
#pragma unroll
        for (int j = 0; j < 4; j++) acc[i][j] = 0.f;

    for (int k0 = 0; k0 < K; k0 += 16) {
        {
            int m = m0 + ar;
            float tmp[4];
            if (m < M) load4(A + (size_t)m * lda + k0 + ak, tmp);
            else { tmp[0] = tmp[1] = tmp[2] = tmp[3] = 0.f; }
            As[ak + 0][ar] = tmp[0]; As[ak + 1][ar] = tmp[1];
            As[ak + 2][ar] = tmp[2]; As[ak + 3][ar] = tmp[3];
        }
        {
            float tmp[4];
            load4(B + (size_t)(k0 + bk) * ldb + n0 + bn, tmp);
            Bs[bk][bn + 0] = tmp[0]; Bs[bk][bn + 1] = tmp[1];
            Bs[bk][bn + 2] = tmp[2]; Bs[bk][bn + 3] = tmp[3];
        }
        __syncthreads();
#pragma unroll
        for (int k = 0; k < 16; k++) {
            float a[4], b[4];
#pragma unroll
            for (int i = 0; i < 4; i++) a[i] = As[k][ty * 4 + i];
#pragma unroll
            for (int j = 0; j < 4; j++) b[j] = Bs[k][tx * 4 + j];
#pragma unroll
            for (int i = 0; i < 4; i++)
#pragma unroll
                for (int j = 0; j < 4; j++) acc[i][j] += a[i] * b[j];
        }
        __syncthreads();
    }
#pragma unroll
    for (int i = 0; i < 4; i++) {
        int m = m0 + ty * 4 + i;
        if (m >= M) continue;
#pragma unroll
        for (int j = 0; j < 4; j++) {
            int n = n0 + tx * 4 + j;
            C[(size_t)m * ldc + n] = f2b(acc[i][j]);
        }
    }
}

#define SOFTMAX_SCALE 0.07905694150420949f  // 1/sqrt(160)

// =====================================================================
// attn1 (sparse-causal, 512 keys) — MFMA flash-attention.
// q/k/v may live in a fused QKV buffer: row stride = ldq. Output stride DIM.
// =====================================================================
#define A1_KP 168   // K LDS pitch (shorts): 160 + 8 pad
#define A1_VP 72    // V^T pitch (shorts):   64 + 8 pad
#define A1_PP 72    // P  pitch (shorts)

__global__ __launch_bounds__(256) void attn1_mfma(const bf16* __restrict__ q,
                                                  const bf16* __restrict__ k,
                                                  const bf16* __restrict__ v,
                                                  int ldq,
                                                  bf16* __restrict__ o) {
    __shared__ short K_lds[64 * A1_KP];
    __shared__ short Vt_lds[160 * A1_VP];
    __shared__ short P_lds[4 * 16 * A1_PP];

    const int t = threadIdx.x;
    const int wid = t >> 6, lane = t & 63;
    const int lrow = lane & 15, lgrp = lane >> 4;
    const int bx = blockIdx.x, hd = blockIdx.y, bfi = blockIdx.z;
    const int bi = bfi >> 4, fi = bfi & 15;
    const int former = fi > 0 ? fi - 1 : 0;
    const int qrow0 = bfi * TOK + bx * 64 + wid * 16;

    s8v qf[5];
    {
        const bf16* qp = q + (size_t)(qrow0 + lrow) * ldq + hd * DH + lgrp * 8;
#pragma unroll
        for (int ks = 0; ks < 5; ks++)
            qf[ks] = *(const s8v*)(qp + ks * 32);
    }

    f4v oacc[10];
#pragma unroll
    for (int dg = 0; dg < 10; dg++) oacc[dg] = (f4v){0.f, 0.f, 0.f, 0.f};
    float m_run[4], l_run[4];
#pragma unroll
    for (int r = 0; r < 4; r++) { m_run[r] = -1e30f; l_run[r] = 0.f; }

    short* P_w = P_lds + wid * 16 * A1_PP;

    for (int c = 0; c < 8; c++) {
        const int kf = (c < 4) ? 0 : former;
        const size_t krow0 = (size_t)(bi * FRAMES + kf) * TOK + (c & 3) * 64;

        __syncthreads();
#pragma unroll
        for (int it = 0; it < 5; it++) {
            int idx = t + it * 256;
            int jr = idx / 20, g = idx % 20;
            const bf16* kp = k + (krow0 + jr) * ldq + hd * DH + g * 8;
            *(uint4*)&K_lds[jr * A1_KP + g * 8] = *(const uint4*)kp;
            s8v vv = *(const s8v*)(v + (krow0 + jr) * ldq + hd * DH + g * 8);
#pragma unroll
            for (int i = 0; i < 8; i++) {
                int d = g * 8 + i;
                Vt_lds[d * A1_VP + (jr ^ (d & 56))] = vv[i];
            }
        }
        __syncthreads();

        f4v sacc[4];
#pragma unroll
        for (int kg = 0; kg < 4; kg++) {
            sacc[kg] = (f4v){0.f, 0.f, 0.f, 0.f};
#pragma unroll
            for (int ks = 0; ks < 5; ks++) {
                s8v kfr = *(const s8v*)&K_lds[(kg * 16 + lrow) * A1_KP + ks * 32 + lgrp * 8];
                sacc[kg] = __builtin_amdgcn_mfma_f32_16x16x32_bf16(qf[ks], kfr, sacc[kg], 0, 0, 0);
            }
        }

        float mc[4];
#pragma unroll
        for (int r = 0; r < 4; r++) {
            float mm = fmaxf(fmaxf(sacc[0][r], sacc[1][r]), fmaxf(sacc[2][r], sacc[3][r]));
            mc[r] = mm * SOFTMAX_SCALE;
        }
#pragma unroll
        for (int x = 1; x < 16; x <<= 1)
#pragma unroll
            for (int r = 0; r < 4; r++)
                mc[r] = fmaxf(mc[r], __shfl_xor(mc[r], x));

        float p[4][4], rs[4];
#pragma unroll
        for (int r = 0; r < 4; r++) {
            float mn = fmaxf(m_run[r], mc[r]);
            float sc = __expf(m_run[r] - mn);
            m_run[r] = mn;
            l_run[r] *= sc;
#pragma unroll
            for (int dg = 0; dg < 10; dg++) oacc[dg][r] *= sc;
            float acc = 0.f;
#pragma unroll
            for (int kg = 0; kg < 4; kg++) {
                float e = __expf(sacc[kg][r] * SOFTMAX_SCALE - mn);
                p[kg][r] = e; acc += e;
            }
            rs[r] = acc;
        }
#pragma unroll
        for (int x = 1; x < 16; x <<= 1)
#pragma unroll
            for (int r = 0; r < 4; r++)
                rs[r] += __shfl_xor(rs[r], x);
#pragma unroll
        for (int r = 0; r < 4; r++) l_run[r] += rs[r];

#pragma unroll
        for (int kg = 0; kg < 4; kg++)
#pragma unroll
            for (int r = 0; r < 4; r++)
                P_w[(lgrp * 4 + r) * A1_PP + kg * 16 + lrow] = f2s(p[kg][r]);
        __syncthreads();

        s8v pa[2];
#pragma unroll
        for (int ks2 = 0; ks2 < 2; ks2++)
            pa[ks2] = *(const s8v*)&P_w[lrow * A1_PP + ks2 * 32 + lgrp * 8];
#pragma unroll
        for (int dg = 0; dg < 10; dg++) {
            int dd = dg * 16 + lrow;
#pragma unroll
            for (int ks2 = 0; ks2 < 2; ks2++) {
                s8v vfr = *(const s8v*)&Vt_lds[dd * A1_VP + ((ks2 * 32 + lgrp * 8) ^ (dd & 56))];
                oacc[dg] = __builtin_amdgcn_mfma_f32_16x16x32_bf16(pa[ks2], vfr, oacc[dg], 0, 0, 0);
            }
        }
    }

    float invl[4];
#pragma unroll
    for (int r = 0; r < 4; r++) invl[r] = 1.f / l_run[r];
#pragma unroll
    for (int dg = 0; dg < 10; dg++) {
#pragma unroll
        for (int r = 0; r < 4; r++) {
            int qq = qrow0 + lgrp * 4 + r;
            o[(size_t)qq * DIM + hd * DH + dg * 16 + lrow] = f2b(oacc[dg][r] * invl[r]);
        }
    }
}

// =====================================================================
// attn2 (cross, 77 keys) — MFMA flash-attention, 2 key-chunks, masked.
// k/v have row stride ldk (fused KV buffer); pad rows are exact zeros.
// =====================================================================
__global__ __launch_bounds__(256) void attn2_mfma(const bf16* __restrict__ q,
                                                  const bf16* __restrict__ k,
                                                  const bf16* __restrict__ v,
                                                  int ldk,
                                                  bf16* __restrict__ o) {
    __shared__ short K_lds[64 * A1_KP];
    __shared__ short Vt_lds[160 * A1_VP];
    __shared__ short P_lds[4 * 16 * A1_PP];

    const int t = threadIdx.x;
    const int wid = t >> 6, lane = t & 63;
    const int lrow = lane & 15, lgrp = lane >> 4;
    const int bx = blockIdx.x, hd = blockIdx.y, bfi = blockIdx.z;
    const int qrow0 = bfi * TOK + bx * 64 + wid * 16;

    s8v qf[5];
    {
        const bf16* qp = q + (size_t)(qrow0 + lrow) * DIM + hd * DH + lgrp * 8;
#pragma unroll
        for (int ks = 0; ks < 5; ks++)
            qf[ks] = *(const s8v*)(qp + ks * 32);
    }

    f4v oacc[10];
#pragma unroll
    for (int dg = 0; dg < 10; dg++) oacc[dg] = (f4v){0.f, 0.f, 0.f, 0.f};
    float m_run[4], l_run[4];
#pragma unroll
    for (int r = 0; r < 4; r++) { m_run[r] = -1e30f; l_run[r] = 0.f; }

    short* P_w = P_lds + wid * 16 * A1_PP;

    for (int c = 0; c < 2; c++) {
        const size_t krow0 = (size_t)bfi * ESEQ + c * 64;

        __syncthreads();
#pragma unroll
        for (int it = 0; it < 5; it++) {
            int idx = t + it * 256;
            int jr = idx / 20, g = idx % 20;
            const bf16* kp = k + (krow0 + jr) * ldk + hd * DH + g * 8;
            *(uint4*)&K_lds[jr * A1_KP + g * 8] = *(const uint4*)kp;
            s8v vv = *(const s8v*)(v + (krow0 + jr) * ldk + hd * DH + g * 8);
#pragma unroll
            for (int i = 0; i < 8; i++) {
                int d = g * 8 + i;
                Vt_lds[d * A1_VP + (jr ^ (d & 56))] = vv[i];
            }
        }
        __syncthreads();

        f4v sacc[4];
#pragma unroll
        for (int kg = 0; kg < 4; kg++) {
            sacc[kg] = (f4v){0.f, 0.f, 0.f, 0.f};
#pragma unroll
            for (int ks = 0; ks < 5; ks++) {
                s8v kfr = *(const s8v*)&K_lds[(kg * 16 + lrow) * A1_KP + ks * 32 + lgrp * 8];
                sacc[kg] = __builtin_amdgcn_mfma_f32_16x16x32_bf16(qf[ks], kfr, sacc[kg], 0, 0, 0);
            }
            if (c == 1 && (kg > 0 || lrow >= 13))
                sacc[kg] = (f4v){-1e30f, -1e30f, -1e30f, -1e30f};
        }

        float mc[4];
#pragma unroll
        for (int r = 0; r < 4; r++) {
            float mm = fmaxf(fmaxf(sacc[0][r], sacc[1][r]), fmaxf(sacc[2][r], sacc[3][r]));
            mc[r] = mm * SOFTMAX_SCALE;
        }
#pragma unroll
        for (int x = 1; x < 16; x <<= 1)
#pragma unroll
            for (int r = 0; r < 4; r++)
                mc[r] = fmaxf(mc[r], __shfl_xor(mc[r], x));

        float p[4][4], rs[4];
#pragma unroll
        for (int r = 0; r < 4; r++) {
            float mn = fmaxf(m_run[r], mc[r]);
            float sc = __expf(m_run[r] - mn);
            m_run[r] = mn;
            l_run[r] *= sc;
#pragma unroll
            for (int dg = 0; dg < 10; dg++) oacc[dg][r] *= sc;
            float acc = 0.f;
#pragma unroll
            for (int kg = 0; kg < 4; kg++) {
                float e = __expf(sacc[kg][r] * SOFTMAX_SCALE - mn);
                p[kg][r] = e; acc += e;
            }
            rs[r] = acc;
        }
#pragma unroll
        for (int x = 1; x < 16; x <<= 1)
#pragma unroll
            for (int r = 0; r < 4; r++)
                rs[r] += __shfl_xor(rs[r], x);
#pragma unroll
        for (int r = 0; r < 4; r++) l_run[r] += rs[r];

#pragma unroll
        for (int kg = 0; kg < 4; kg++)
#pragma unroll
            for (int r = 0; r < 4; r++)
                P_w[(lgrp * 4 + r) * A1_PP + kg * 16 + lrow] = f2s(p[kg][r]);
        __syncthreads();

        s8v pa[2];
#pragma unroll
        for (int ks2 = 0; ks2 < 2; ks2++)
            pa[ks2] = *(const s8v*)&P_w[lrow * A1_PP + ks2 * 32 + lgrp * 8];
#pragma unroll
        for (int dg = 0; dg < 10; dg++) {
            int dd = dg * 16 + lrow;
#pragma unroll
            for (int ks2 = 0; ks2 < 2; ks2++) {
                s8v vfr = *(const s8v*)&Vt_lds[dd * A1_VP + ((ks2 * 32 + lgrp * 8) ^ (dd & 56))];
                oacc[dg] = __builtin_amdgcn_mfma_f32_16x16x32_bf16(pa[ks2], vfr, oacc[dg], 0, 0, 0);
            }
        }
    }

    float invl[4];
#pragma unroll
    for (int r = 0; r < 4; r++) invl[r] = 1.f / l_run[r];
#pragma unroll
    for (int dg = 0; dg < 10; dg++) {
#pragma unroll
        for (int r = 0; r < 4; r++) {
            int qq = qrow0 + lgrp * 4 + r;
            o[(size_t)qq * DIM + hd * DH + dg * 16 + lrow] = f2b(oacc[dg][r] * invl[r]);
        }
    }
}

// ---- attn2 legacy scalar (tier0 fallback) ----
__global__ __launch_bounds__(256) void attn2_kernel(const bf16* __restrict__ q,
                                                    const bf16* __restrict__ k,
                                                    const bf16* __restrict__ v,
                                                    bf16* __restrict__ o) {
    __shared__ float sQ[DH];
    __shared__ float sS[128];
    __shared__ float red[256];
    int t = threadIdx.x;
    int qi = blockIdx.x, hd = blockIdx.y, bfi = blockIdx.z;
    size_t qbase = ((size_t)(bfi * TOK + qi)) * DIM + hd * DH;
    if (t < DH) sQ[t] = b2f(q[qbase + t]);
    __syncthreads();
    if (t < ESEQ) {
        size_t kbase = ((size_t)(bfi * ESEQ + t)) * DIM + hd * DH;
        float acc = 0.f;
        for (int d = 0; d < DH; d++) acc += sQ[d] * b2f(k[kbase + d]);
        sS[t] = acc * SOFTMAX_SCALE;
    }
    __syncthreads();
    float lm = (t < ESEQ) ? sS[t] : -1e30f;
    red[t] = lm; __syncthreads();
    for (int s = 128; s > 0; s >>= 1) { if (t < s) red[t] = fmaxf(red[t], red[t + s]); __syncthreads(); }
    float mx = red[0]; __syncthreads();
    float ls = 0.f;
    if (t < ESEQ) { float e = __expf(sS[t] - mx); sS[t] = e; ls = e; }
    red[t] = ls; __syncthreads();
    for (int s = 128; s > 0; s >>= 1) { if (t < s) red[t] += red[t + s]; __syncthreads(); }
    float inv = 1.f / red[0];
    __syncthreads();
    if (t < DH) {
        float acc = 0.f;
        for (int j = 0; j < ESEQ; j++) {
            size_t vbase = ((size_t)(bfi * ESEQ + j)) * DIM + hd * DH;
            acc += sS[j] * b2f(v[vbase + t]);
        }
        o[qbase + t] = f2b(acc * inv);
    }
}

// =====================================================================
// attnt (temporal, 16 keys) — vectorized full-block kernel.
// =====================================================================
#define AT_P 168
__global__ __launch_bounds__(256) void attnt_vec(const bf16* __restrict__ q,
                                                 const bf16* __restrict__ k,
                                                 const bf16* __restrict__ v,
                                                 int ldq,
                                                 bf16* __restrict__ o) {
    __shared__ short Q_l[16 * AT_P], K_l[16 * AT_P], V_l[16 * AT_P];
    __shared__ float P_l[16][17];
    const int t = threadIdx.x;
    const int hd = blockIdx.y;
    const int z = blockIdx.x;
    const int bi = z >> 8, ti = z & 255;

#pragma unroll
    for (int it = 0; it < 2; it++) {
        int c = t + it * 256;
        if (c < 320) {
            int f = c / 20, g = c % 20;
            size_t row = (size_t)(bi * FRAMES + f) * TOK + ti;
            const bf16* qp = q + row * ldq + hd * DH + g * 8;
            const bf16* kp = k + row * ldq + hd * DH + g * 8;
            const bf16* vp = v + row * ldq + hd * DH + g * 8;
            *(uint4*)&Q_l[f * AT_P + g * 8] = *(const uint4*)qp;
            *(uint4*)&K_l[f * AT_P + g * 8] = *(const uint4*)kp;
            *(uint4*)&V_l[f * AT_P + g * 8] = *(const uint4*)vp;
        }
    }
    __syncthreads();

    const int fq = t >> 4, fk = t & 15;
    float acc = 0.f;
#pragma unroll
    for (int dg = 0; dg < 20; dg++) {
        s8v qv = *(const s8v*)&Q_l[fq * AT_P + dg * 8];
        s8v kv = *(const s8v*)&K_l[fk * AT_P + dg * 8];
#pragma unroll
        for (int e = 0; e < 8; e++)
            acc += us2f((unsigned short)qv[e]) * us2f((unsigned short)kv[e]);
    }
    acc *= SOFTMAX_SCALE;
    float mx = acc;
#pragma unroll
    for (int x = 1; x < 16; x <<= 1) mx = fmaxf(mx, __shfl_xor(mx, x));
    float ex = __expf(acc - mx);
    float sm = ex;
#pragma unroll
    for (int x = 1; x < 16; x <<= 1) sm += __shfl_xor(sm, x);
    P_l[fq][fk] = ex / sm;
    __syncthreads();

#pragma unroll
    for (int it = 0; it < 2; it++) {
        int a = t + it * 256;
        if (a < 320) {
            int pq = a & 15, dg = a >> 4;
            float pr[16];
#pragma unroll
            for (int j = 0; j < 16; j++) pr[j] = P_l[pq][j];
            float ov[8] = {0.f, 0.f, 0.f, 0.f, 0.f, 0.f, 0.f, 0.f};
#pragma unroll
            for (int j = 0; j < 16; j++) {
                s8v vv = *(const s8v*)&V_l[j * AT_P + dg * 8];
#pragma unroll
                for (int i = 0; i < 8; i++)
                    ov[i] += pr[j] * us2f((unsigned short)vv[i]);
            }
            s8v o8;
#pragma unroll
            for (int i = 0; i < 8; i++) o8[i] = f2s(ov[i]);
            size_t orow = (size_t)(bi * FRAMES + pq) * TOK + ti;
            *(s8v*)(o + orow * DIM + hd * DH + dg * 8) = o8;
        }
    }
}

// ---- temporal self-attn legacy scalar (tier0 fallback) ----
__global__ __launch_bounds__(256) void attnt_kernel(const bf16* __restrict__ q,
                                                    const bf16* __restrict__ k,
                                                    const bf16* __restrict__ v,
                                                    int ldq,
                                                    bf16* __restrict__ o) {
    __shared__ float sQ[DH];
    __shared__ float sS[16];
    __shared__ float red[256];
    int t = threadIdx.x;
    int qfi = blockIdx.x, hd = blockIdx.y, z = blockIdx.z;
    int bi = z >> 8, ti = z & 255;
    size_t qrow = (size_t)(bi * FRAMES + qfi) * TOK + ti;
    if (t < DH) sQ[t] = b2f(q[qrow * ldq + hd * DH + t]);
    __syncthreads();
    if (t < FRAMES) {
        size_t krow = (size_t)(bi * FRAMES + t) * TOK + ti;
        float acc = 0.f;
        for (int d = 0; d < DH; d++) acc += sQ[d] * b2f(k[krow * ldq + hd * DH + d]);
        sS[t] = acc * SOFTMAX_SCALE;
    }
    __syncthreads();
    float lm = (t < FRAMES) ? sS[t] : -1e30f;
    red[t] = lm; __syncthreads();
    for (int s = 128; s > 0; s >>= 1) { if (t < s) red[t] = fmaxf(red[t], red[t + s]); __syncthreads(); }
    float mx = red[0]; __syncthreads();
    float ls = 0.f;
    if (t < FRAMES) { float e = __expf(sS[t] - mx); sS[t] = e; ls = e; }
    red[t] = ls; __syncthreads();
    for (int s = 128; s > 0; s >>= 1) { if (t < s) red[t] += red[t + s]; __syncthreads(); }
    float inv = 1.f / red[0];
    __syncthreads();
    if (t < DH) {
        float acc = 0.f;
        for (int j = 0; j < FRAMES; j++) {
            size_t vrow = (size_t)(bi * FRAMES + j) * TOK + ti;
            acc += sS[j] * b2f(v[vrow * ldq + hd * DH + t]);
        }
        o[qrow * DIM + hd * DH + t] = f2b(acc * inv);
    }
}

extern "C" void kernel_launch(void* const* d_in, const int* in_sizes, int n_in,
                              void* d_out, int out_size, void* d_ws, size_t ws_size,
                              hipStream_t stream) {
    (void)in_sizes; (void)n_in; (void)out_size;
    const float* hs   = (const float*)d_in[0];
    const float* enc  = (const float*)d_in[1];
    const float* n1w  = (const float*)d_in[2];
    const float* n1b  = (const float*)d_in[3];
    const float* a1wq = (const float*)d_in[4];
    const float* a1wk = (const float*)d_in[5];
    const float* a1wv = (const float*)d_in[6];
    const float* a1wo = (const float*)d_in[7];
    const float* a1bo = (const float*)d_in[8];
    const float* n2w  = (const float*)d_in[9];
    const float* n2b  = (const float*)d_in[10];
    const float* a2wq = (const float*)d_in[11];
    const float* a2wk = (const float*)d_in[12];
    const float* a2wv = (const float*)d_in[13];
    const float* a2wo = (const float*)d_in[14];
    const float* a2bo = (const float*)d_in[15];
    const float* n3w  = (const float*)d_in[16];
    const float* n3b  = (const float*)d_in[17];
    const float* ffw1 = (const float*)d_in[18];
    const float* ffb1 = (const float*)d_in[19];
    const float* ffw2 = (const float*)d_in[20];
    const float* ffb2 = (const float*)d_in[21];
    const float* ntw  = (const float*)d_in[22];
    const float* ntb  = (const float*)d_in[23];
    const float* atwq = (const float*)d_in[24];
    const float* atwk = (const float*)d_in[25];
    const float* atwv = (const float*)d_in[26];
    const float* atwo = (const float*)d_in[27];
    const float* atbo = (const float*)d_in[28];

    char* wp = (char*)d_ws;
    auto carve = [&](size_t bytes) -> char* {
        char* p = wp; wp += (bytes + 255) & ~((size_t)255); return p;
    };
    const size_t BUF = (size_t)ROWS * DIM * 2;   // 20,971,520
    const size_t W_FULL = 26214400;              // ffw1t: 10240x1280 bf16
    float* out = (float*)d_out;                  // f32 residual stream in d_out
    dim3 blk(256);
    dim3 blk8(512);

    bf16* nh = (bf16*)carve(BUF);

    bool full = (ws_size >= 5 * BUF + W_FULL + 4096);
    if (!full) {
        // ------- legacy path (R1 kernel, known-good at 105 MB ws) -------
        bf16* qb = (bf16*)carve(BUF);
        bf16* kb = (bf16*)carve(BUF);
        bf16* vb = (bf16*)carve(BUF);
        bf16* ob = (bf16*)carve(BUF);
        bf16* Pb = qb;
        auto proj = [&](const bf16* A, int lda, const float* B, int ldb,
                        bf16* C, int ldc, int M, int N, int K) {
            gemm_mfma<0><<<dim3(N / 128, M / 128), blk, 0, stream>>>(
                A, lda, B, ldb, C, ldc, nullptr, nullptr, 0, M, N, K);
        };
        auto outproj = [&](const bf16* A, int lda, const float* B,
                           const float* bias, const float* res, int K) {
            gemm_mfma<1><<<dim3(DIM / 128, ROWS / 128), blk, 0, stream>>>(
                A, lda, B, DIM, out, DIM, bias, res, DIM, ROWS, DIM, K);
        };
        ln_kernel<<<dim3(ROWS), blk, 0, stream>>>(hs, n1w, n1b, nh);
        proj(nh, DIM, a1wq, DIM, qb, DIM, ROWS, DIM, DIM);
        proj(nh, DIM, a1wk, DIM, kb, DIM, ROWS, DIM, DIM);
        proj(nh, DIM, a1wv, DIM, vb, DIM, ROWS, DIM, DIM);
        attn1_mfma<<<dim3(TOK / 64, HEADS, BF), blk, 0, stream>>>(qb, kb, vb, DIM, ob);
        outproj(ob, DIM, a1wo, a1bo, hs, DIM);

        ln_kernel<<<dim3(ROWS), blk, 0, stream>>>(out, n2w, n2b, nh);
        proj(nh, DIM, a2wq, DIM, qb, DIM, ROWS, DIM, DIM);
        gemm_valu<<<dim3(DIM / 64, (EROWS + 63) / 64), blk, 0, stream>>>(enc, CROSS, a2wk, DIM, kb, DIM, EROWS, DIM, CROSS);
        gemm_valu<<<dim3(DIM / 64, (EROWS + 63) / 64), blk, 0, stream>>>(enc, CROSS, a2wv, DIM, vb, DIM, EROWS, DIM, CROSS);
        attn2_kernel<<<dim3(TOK, HEADS, BF), blk, 0, stream>>>(qb, kb, vb, ob);
        outproj(ob, DIM, a2wo, a2bo, out, DIM);

        ln_kernel<<<dim3(ROWS), blk, 0, stream>>>(out, n3w, n3b, nh);
        gemm_mfma<2><<<dim3(INNER / 128, ROWS / 128), blk, 0, stream>>>(
            nh, DIM, ffw1, 2 * INNER, Pb, INNER, ffb1, nullptr, 0, ROWS, INNER, DIM);
        outproj(Pb, INNER, ffw2, ffb2, out, INNER);

        ln_kernel<<<dim3(ROWS), blk, 0, stream>>>(out, ntw, ntb, nh);
        proj(nh, DIM, atwq, DIM, qb, DIM, ROWS, DIM, DIM);
        proj(nh, DIM, atwk, DIM, kb, DIM, ROWS, DIM, DIM);
        proj(nh, DIM, atwv, DIM, vb, DIM, ROWS, DIM, DIM);
        attnt_kernel<<<dim3(FRAMES, HEADS, BATCH * TOK), blk, 0, stream>>>(qb, kb, vb, DIM, ob);
        outproj(ob, DIM, atwo, atbo, out, DIM);
        return;
    }

    // ------- full path: bf16 B^T weights + 256^2 gemm_bt8 + fused QKV -------
    bf16* C3 = (bf16*)carve(3 * BUF);            // fused QKV [ROWS][3840]
    bf16* ob = (bf16*)carve(BUF);
    bf16* Ws = (bf16*)carve(W_FULL);
    bf16* Pb = C3;                               // FFN intermediate spans C3+ob (84 MB)
    const size_t WQ = (size_t)DIM * DIM;
    const size_t WC = (size_t)DIM * CROSS;
    const int LDQ3 = 3 * DIM;                    // 3840

    auto projN = [&](const bf16* A, int lda, const bf16* Bt, int ldb,
                     bf16* C, int ldc, int M, int N, int K) {
        gemm_bt8<0><<<dim3(N / 256, M / 256), blk8, 0, stream>>>(
            A, lda, Bt, ldb, C, ldc, nullptr, nullptr, 0, M, N, K);
    };
    auto outprojN = [&](const bf16* A, int lda, const bf16* Bt, int ldb,
                        const float* bias, const float* res, int K) {
        gemm_bt8<1><<<dim3(DIM / 256, ROWS / 256), blk8, 0, stream>>>(
            A, lda, Bt, ldb, out, DIM, bias, res, DIM, ROWS, DIM, K);
    };

    // ---- attn1: sparse-causal self-attention (fused QKV proj, N=3840) ----
    wconv_t4<<<dim3(DIM / 64, DIM / 64, 4), blk, 0, stream>>>(
        a1wq, a1wk, a1wv, a1wo, Ws, WQ, DIM, DIM);
    ln_kernel<<<dim3(ROWS), blk, 0, stream>>>(hs, n1w, n1b, nh);
    projN(nh, DIM, Ws, DIM, C3, LDQ3, ROWS, 3 * DIM, DIM);
    attn1_mfma<<<dim3(TOK / 64, HEADS, BF), blk, 0, stream>>>(
        C3, C3 + DIM, C3 + 2 * DIM, LDQ3, ob);
    outprojN(ob, DIM, Ws + 3 * WQ, DIM, a1bo, hs, DIM);

    // ---- attn2: cross-attention (MFMA attn, padded encoder, fused KV) ----
    {
        bf16* w2q  = Ws;                         // [DIM][DIM]
        bf16* w2o  = Ws + WQ;                    // [DIM][DIM]
        bf16* w2k  = Ws + 2 * WQ;                // [DIM][CROSS]
        bf16* w2v  = w2k + WC;                   // [DIM][CROSS] (contiguous after w2k)
        bf16* encb = w2v + WC;                   // [EPAD][CROSS]
        bf16* qb2  = C3;                         // [ROWS][DIM]
        bf16* kv2  = C3 + (size_t)ROWS * DIM;    // [EPAD][2560] fused K|V
        wconv_t4<<<dim3(DIM / 64, DIM / 64, 2), blk, 0, stream>>>(
            a2wq, a2wo, nullptr, nullptr, w2q, WQ, DIM, DIM);
        wconv_t4<<<dim3(DIM / 64, CROSS / 64, 2), blk, 0, stream>>>(
            a2wk, a2wv, nullptr, nullptr, w2k, WC, DIM, CROSS);
        encconv<<<dim3(EPAD * CROSS / 1024), blk, 0, stream>>>(enc, encb);
        ln_kernel<<<dim3(ROWS), blk, 0, stream>>>(out, n2w, n2b, nh);
        projN(nh, DIM, w2q, DIM, qb2, DIM, ROWS, DIM, DIM);
        projN(encb, CROSS, w2k, CROSS, kv2, 2 * DIM, EPAD, 2 * DIM, CROSS);
        attn2_mfma<<<dim3(TOK / 64, HEADS, BF), blk, 0, stream>>>(
            qb2, kv2, kv2 + DIM, 2 * DIM, ob);
        outprojN(ob, DIM, w2o, DIM, a2bo, out, DIM);
    }

    // ---- geglu FFN ----
    wconv_t<<<dim3(2 * INNER / 64, DIM / 64), blk, 0, stream>>>(ffw1, Ws, 2 * INNER, DIM);
    ln_kernel<<<dim3(ROWS), blk, 0, stream>>>(out, n3w, n3b, nh);
    gemm_bt<2><<<dim3(INNER / 64, ROWS / 128), blk, 0, stream>>>(
        nh, DIM, Ws, DIM, Pb, INNER, ffb1, nullptr, 0, ROWS, INNER, DIM);
    wconv_t<<<dim3(DIM / 64, INNER / 64), blk, 0, stream>>>(ffw2, Ws, DIM, INNER);
    gemm_bt8<1><<<dim3(DIM / 256, ROWS / 256), blk8, 0, stream>>>(
        Pb, INNER, Ws, INNER, out, DIM, ffb2, out, DIM, ROWS, DIM, INNER);

    // ---- temporal self-attention (fused QKV proj + vectorized attn) ----
    wconv_t4<<<dim3(DIM / 64, DIM / 64, 4), blk, 0, stream>>>(
        atwq, atwk, atwv, atwo, Ws, WQ, DIM, DIM);
    ln_kernel<<<dim3(ROWS), blk, 0, stream>>>(out, ntw, ntb, nh);
    projN(nh, DIM, Ws, DIM, C3, LDQ3, ROWS, 3 * DIM, DIM);
    attnt_vec<<<dim3(BATCH * TOK, HEADS), blk, 0, stream>>>(
        C3, C3 + DIM, C3 + 2 * DIM, LDQ3, ob);
    outprojN(ob, DIM, Ws + 3 * WQ, DIM, atbo, out, DIM);
}

// Round 6
// 1145.414 us; speedup vs baseline: 4.5747x; 1.0398x over previous
//
#include <hip/hip_runtime.h>
#include <hip/hip_bf16.h>
#include <math.h>

// ---- problem constants (from reference) ----
#define DIM    1280
#define HEADS  8
#define DH     160            // DIM / HEADS
#define FRAMES 16
#define BATCH  2
#define TOK    256
#define ESEQ   77
#define INNER  5120           // 4*DIM
#define CROSS  768
#define BF     (BATCH*FRAMES) // 32
#define ROWS   (BF*TOK)       // 8192
#define EROWS  (BF*ESEQ)      // 2464
#define EPAD   2560           // EROWS padded to %128

typedef __hip_bfloat16 bf16;
typedef __attribute__((ext_vector_type(8))) short s8v;
typedef __attribute__((ext_vector_type(4))) short s4v;
typedef __attribute__((ext_vector_type(4))) float f4v;

__device__ __forceinline__ float us2f(unsigned short u) {
    union { float f; unsigned int i; } c; c.i = ((unsigned int)u) << 16; return c.f;
}
__device__ __forceinline__ float b2f(bf16 x) { return __bfloat162float(x); }
__device__ __forceinline__ bf16  f2b(float x) { return __float2bfloat16(x); }
// f32 -> bf16 bits (RNE), as short
__device__ __forceinline__ short f2s(float x) {
    union { float f; unsigned int u; } c; c.f = x;
    unsigned int r = c.u + 0x7FFF + ((c.u >> 16) & 1);
    return (short)(r >> 16);
}
__device__ __forceinline__ void load4(const float* p, float* d) {
    float4 v = *(const float4*)p; d[0] = v.x; d[1] = v.y; d[2] = v.z; d[3] = v.w;
}
// async global->LDS, 16B per lane; LDS dest is wave-uniform base + lane*16
__device__ __forceinline__ void gl_lds16(const bf16* g, short* l) {
    __builtin_amdgcn_global_load_lds(
        (const __attribute__((address_space(1))) void*)g,
        (__attribute__((address_space(3))) void*)l, 16, 0, 0);
}

// ---- LayerNorm: one block per row of DIM=1280 (256 thr x 5 elems) ----
__global__ __launch_bounds__(256) void ln_kernel(const float* __restrict__ x,
                                                 const float* __restrict__ w,
                                                 const float* __restrict__ b,
                                                 bf16* __restrict__ out) {
    __shared__ float r1[256], r2[256];
    int row = blockIdx.x, t = threadIdx.x;
    const float* xp = x + (size_t)row * DIM;
    float v[5], s = 0.f, s2 = 0.f;
#pragma unroll
    for (int i = 0; i < 5; i++) {
        float xv = xp[t + 256 * i];
        v[i] = xv; s += xv; s2 += xv * xv;
    }
    r1[t] = s; r2[t] = s2; __syncthreads();
    for (int st = 128; st > 0; st >>= 1) {
        if (t < st) { r1[t] += r1[t + st]; r2[t] += r2[t + st]; }
        __syncthreads();
    }
    float mean = r1[0] * (1.f / DIM);
    float var  = r2[0] * (1.f / DIM) - mean * mean;
    float rstd = rsqrtf(var + 1e-5f);
    bf16* op = out + (size_t)row * DIM;
#pragma unroll
    for (int i = 0; i < 5; i++) {
        int c = t + 256 * i;
        op[c] = f2b((v[i] - mean) * rstd * w[c] + b[c]);
    }
}

// ---- transpose-convert: W f32 [K][N] -> Wt bf16 [N][K]; N,K % 64 == 0 ----
__global__ __launch_bounds__(256) void wconv_t(const float* __restrict__ w,
                                               bf16* __restrict__ wt,
                                               int N, int K) {
    __shared__ float tile[64][65];
    const int n0 = blockIdx.x * 64, k0 = blockIdx.y * 64;
    const int t = threadIdx.x;
    const int tr = t >> 4;          // 0..15
    const int tc = (t & 15) * 4;    // 0..60
#pragma unroll
    for (int i = 0; i < 4; i++) {
        int kk = tr + i * 16;
        float4 vv = *(const float4*)(w + (size_t)(k0 + kk) * N + n0 + tc);
        tile[kk][tc + 0] = vv.x; tile[kk][tc + 1] = vv.y;
        tile[kk][tc + 2] = vv.z; tile[kk][tc + 3] = vv.w;
    }
    __syncthreads();
#pragma unroll
    for (int i = 0; i < 4; i++) {
        int nn = tr + i * 16;
        s4v o4 = (s4v){ f2s(tile[tc + 0][nn]), f2s(tile[tc + 1][nn]),
                        f2s(tile[tc + 2][nn]), f2s(tile[tc + 3][nn]) };
        *(s4v*)(wt + (size_t)(n0 + nn) * K + k0 + tc) = o4;
    }
}

// ---- batched transpose-convert: up to 4 same-shape weights, grid.z selects ----
__global__ __launch_bounds__(256) void wconv_t4(const float* __restrict__ w0,
                                                const float* __restrict__ w1,
                                                const float* __restrict__ w2,
                                                const float* __restrict__ w3,
                                                bf16* __restrict__ wt, size_t dstride,
                                                int N, int K) {
    const float* w = blockIdx.z == 0 ? w0 : blockIdx.z == 1 ? w1
                   : blockIdx.z == 2 ? w2 : w3;
    bf16* dst = wt + (size_t)blockIdx.z * dstride;
    __shared__ float tile[64][65];
    const int n0 = blockIdx.x * 64, k0 = blockIdx.y * 64;
    const int t = threadIdx.x;
    const int tr = t >> 4;
    const int tc = (t & 15) * 4;
#pragma unroll
    for (int i = 0; i < 4; i++) {
        int kk = tr + i * 16;
        float4 vv = *(const float4*)(w + (size_t)(k0 + kk) * N + n0 + tc);
        tile[kk][tc + 0] = vv.x; tile[kk][tc + 1] = vv.y;
        tile[kk][tc + 2] = vv.z; tile[kk][tc + 3] = vv.w;
    }
    __syncthreads();
#pragma unroll
    for (int i = 0; i < 4; i++) {
        int nn = tr + i * 16;
        s4v o4 = (s4v){ f2s(tile[tc + 0][nn]), f2s(tile[tc + 1][nn]),
                        f2s(tile[tc + 2][nn]), f2s(tile[tc + 3][nn]) };
        *(s4v*)(dst + (size_t)(n0 + nn) * K + k0 + tc) = o4;
    }
}

// ---- encoder f32 [EROWS][CROSS] -> bf16 [EPAD][CROSS], zero-padded rows ----
__global__ __launch_bounds__(256) void encconv(const float* __restrict__ e,
                                               bf16* __restrict__ eb) {
    int idx = blockIdx.x * 256 + threadIdx.x;   // 4 elems each
    int base = idx * 4;
    int row = base / CROSS;
    s4v o4;
    if (row < EROWS) {
        float4 vv = *(const float4*)(e + (size_t)base);
        o4 = (s4v){ f2s(vv.x), f2s(vv.y), f2s(vv.z), f2s(vv.w) };
    } else {
        o4 = (s4v){ 0, 0, 0, 0 };
    }
    *(s4v*)(eb + base) = o4;
}

// =====================================================================
// gemm_bt8: 256x256 tile, BK=64, 512 thr = 8 waves (2m x 4n, 128x64 each),
// double-buffered LDS (128 KB), global_load_lds staging with
// rotation-swizzled source (chunk' = (chunk+row)&7 within each 128B row)
// and matching rotated ds_read columns -> conflict-managed b128 reads.
// Prefetch-at-top + __syncthreads-at-end (proven-safe sync structure).
// EPI 0: bf16 out.  EPI 1: f32 out = acc + bias[n] + res[m][n].
// Requires M%256==0, N%256==0, K%64==0.
// =====================================================================
template <int EPI>
__global__ __launch_bounds__(512, 2) void gemm_bt8(
    const bf16* __restrict__ A, int lda,
    const bf16* __restrict__ Bt, int ldb,
    void* __restrict__ C, int ldc,
    const float* __restrict__ bias,
    const float* __restrict__ res, int ldres,
    int M, int N, int K) {
    __shared__ short lds[2][2][256 * 64];   // [buf][mat A/B][row*64 + col]

    const int t = threadIdx.x;
    const int wid = t >> 6, lane = t & 63;
    const int lrow = lane & 15, lgrp = lane >> 4;
    const int wr = wid >> 2, wc = wid & 3;
    const int m0 = blockIdx.y * 256, n0 = blockIdx.x * 256;

    f4v acc[8][4];
#pragma unroll
    for (int i = 0; i < 8; i++)
#pragma unroll
        for (int j = 0; j < 4; j++) acc[i][j] = (f4v){0.f, 0.f, 0.f, 0.f};

    // staging: wave wid covers rows [wid*32, +32), 4 insts of 8 rows per mat.
    // LDS dest linear: lane l writes bytes [l*16,+16) of its inst's 1KB slab
    // (rows r: r&7 == l>>3, chunk d == l&7). Source column pre-rotated so
    // LDS[r][d] holds logical chunk (d - r)&7.
    const int srow = wid * 32 + (lane >> 3);
    const int scol = (((lane & 7) - (lane >> 3)) & 7) * 8;   // elems
    const bf16* Ag = A + (size_t)(m0 + srow) * lda + scol;
    const bf16* Bg = Bt + (size_t)(n0 + srow) * ldb + scol;

    auto stage = [&](int b, int kt) {
#pragma unroll
        for (int s = 0; s < 4; s++) {
            gl_lds16(Ag + (size_t)kt * 64 + (size_t)(s * 8) * lda,
                     &lds[b][0][wid * 2048 + s * 512]);
            gl_lds16(Bg + (size_t)kt * 64 + (size_t)(s * 8) * ldb,
                     &lds[b][1][wid * 2048 + s * 512]);
        }
    };

    const int KT = K >> 6;
    stage(0, 0);
    __syncthreads();
    int buf = 0;
    for (int kt = 0; kt < KT; kt++, buf ^= 1) {
        if (kt + 1 < KT) stage(buf ^ 1, kt + 1);   // prefetch next K-tile
#pragma unroll
        for (int ks = 0; ks < 2; ks++) {
            // logical chunk ks*4+lgrp at row r -> stored chunk (c + r)&7; r&7 == lrow&7
            const int cc = ((ks * 4 + lgrp + lrow) & 7) * 8;
            s8v bfr[4];
#pragma unroll
            for (int j = 0; j < 4; j++)
                bfr[j] = *(const s8v*)&lds[buf][1][(wc * 64 + j * 16 + lrow) * 64 + cc];
#pragma unroll
            for (int i = 0; i < 8; i++) {
                s8v af = *(const s8v*)&lds[buf][0][(wr * 128 + i * 16 + lrow) * 64 + cc];
#pragma unroll
                for (int j = 0; j < 4; j++)
                    acc[i][j] = __builtin_amdgcn_mfma_f32_16x16x32_bf16(af, bfr[j], acc[i][j], 0, 0, 0);
            }
        }
        __syncthreads();   // prefetch drained + all reads of buf done
    }

    // ---- epilogue: C/D layout col=lane&15, row=(lane>>4)*4+reg ----
    float bs[4];
    if (EPI == 1) {
#pragma unroll
        for (int j = 0; j < 4; j++) bs[j] = bias[n0 + wc * 64 + j * 16 + lrow];
    }
#pragma unroll
    for (int i = 0; i < 8; i++) {
#pragma unroll
        for (int r = 0; r < 4; r++) {
            int m = m0 + wr * 128 + i * 16 + lgrp * 4 + r;
#pragma unroll
            for (int j = 0; j < 4; j++) {
                int n = n0 + wc * 64 + j * 16 + lrow;
                float v = acc[i][j][r];
                if (EPI == 0) {
                    ((bf16*)C)[(size_t)m * ldc + n] = f2b(v);
                } else {
                    ((float*)C)[(size_t)m * ldc + n] = v + bs[j] + res[(size_t)m * ldres + n];
                }
            }
        }
    }
}

// =====================================================================
// gemm_bt8g: geglu GEMM on the bt8 skeleton. 256M x 128N tile, BK=64,
// 512 thr = 8 waves (2m x 4n; each 128x32 of BOTH P and G strips).
// LDS: A 256x64 + B_P 128x64 + B_G 128x64, double-buffered = 128 KB.
// Same rotation swizzle + prefetch/one-barrier sync as gemm_bt8.
// out bf16 = (accP+bias[n]) * gelu(accG+bias[INNER+n]); G strip at
// Bt rows +INNER. Requires M%256==0, N%128==0, K%64==0.
// =====================================================================
__global__ __launch_bounds__(512, 2) void gemm_bt8g(
    const bf16* __restrict__ A, int lda,
    const bf16* __restrict__ Bt, int ldb,
    bf16* __restrict__ C, int ldc,
    const float* __restrict__ bias,
    int M, int N, int K) {
    __shared__ short A_lds[2][256 * 64];    // 64 KB
    __shared__ short P_ldsb[2][128 * 64];   // 32 KB
    __shared__ short G_ldsb[2][128 * 64];   // 32 KB

    const int t = threadIdx.x;
    const int wid = t >> 6, lane = t & 63;
    const int lrow = lane & 15, lgrp = lane >> 4;
    const int wr = wid >> 2, wc = wid & 3;
    const int m0 = blockIdx.y * 256, n0 = blockIdx.x * 128;

    f4v accp[8][2], accg[8][2];
#pragma unroll
    for (int i = 0; i < 8; i++)
#pragma unroll
        for (int j = 0; j < 2; j++) {
            accp[i][j] = (f4v){0.f, 0.f, 0.f, 0.f};
            accg[i][j] = (f4v){0.f, 0.f, 0.f, 0.f};
        }

    const int scol = (((lane & 7) - (lane >> 3)) & 7) * 8;
    const int arow = wid * 32 + (lane >> 3);
    const int brow = wid * 16 + (lane >> 3);
    const bf16* Ag = A + (size_t)(m0 + arow) * lda + scol;
    const bf16* Pg = Bt + (size_t)(n0 + brow) * ldb + scol;
    const bf16* Gg = Bt + (size_t)(INNER + n0 + brow) * ldb + scol;

    auto stage = [&](int b, int kt) {
#pragma unroll
        for (int s = 0; s < 4; s++)
            gl_lds16(Ag + (size_t)kt * 64 + (size_t)(s * 8) * lda,
                     &A_lds[b][wid * 2048 + s * 512]);
#pragma unroll
        for (int s = 0; s < 2; s++) {
            gl_lds16(Pg + (size_t)kt * 64 + (size_t)(s * 8) * ldb,
                     &P_ldsb[b][wid * 1024 + s * 512]);
            gl_lds16(Gg + (size_t)kt * 64 + (size_t)(s * 8) * ldb,
                     &G_ldsb[b][wid * 1024 + s * 512]);
        }
    };

    const int KT = K >> 6;
    stage(0, 0);
    __syncthreads();
    int buf = 0;
    for (int kt = 0; kt < KT; kt++, buf ^= 1) {
        if (kt + 1 < KT) stage(buf ^ 1, kt + 1);
#pragma unroll
        for (int ks = 0; ks < 2; ks++) {
            const int cc = ((ks * 4 + lgrp + lrow) & 7) * 8;
            s8v pf[2], gf[2];
#pragma unroll
            for (int j = 0; j < 2; j++) {
                pf[j] = *(const s8v*)&P_ldsb[buf][(wc * 32 + j * 16 + lrow) * 64 + cc];
                gf[j] = *(const s8v*)&G_ldsb[buf][(wc * 32 + j * 16 + lrow) * 64 + cc];
            }
#pragma unroll
            for (int i = 0; i < 8; i++) {
                s8v af = *(const s8v*)&A_lds[buf][(wr * 128 + i * 16 + lrow) * 64 + cc];
#pragma unroll
                for (int j = 0; j < 2; j++) {
                    accp[i][j] = __builtin_amdgcn_mfma_f32_16x16x32_bf16(af, pf[j], accp[i][j], 0, 0, 0);
                    accg[i][j] = __builtin_amdgcn_mfma_f32_16x16x32_bf16(af, gf[j], accg[i][j], 0, 0, 0);
                }
            }
        }
        __syncthreads();
    }

    // ---- epilogue ----
    float bp[2], bg[2];
#pragma unroll
    for (int j = 0; j < 2; j++) {
        int n = n0 + wc * 32 + j * 16 + lrow;
        bp[j] = bias[n];
        bg[j] = bias[INNER + n];
    }
#pragma unroll
    for (int i = 0; i < 8; i++) {
#pragma unroll
        for (int r = 0; r < 4; r++) {
            int m = m0 + wr * 128 + i * 16 + lgrp * 4 + r;
#pragma unroll
            for (int j = 0; j < 2; j++) {
                int n = n0 + wc * 32 + j * 16 + lrow;
                float p = accp[i][j][r] + bp[j];
                float g = accg[i][j][r] + bg[j];
                float gl = 0.5f * g * (1.f + erff(g * 0.70710678118654752f));
                C[(size_t)m * ldc + n] = f2b(p * gl);
            }
        }
    }
}

// =====================================================================
// gemm_bt (128-tile, 2-phase prefetch) — legacy geglu + odd shapes.
// =====================================================================
template <int EPI>
__global__ __launch_bounds__(256) void gemm_bt(
    const bf16* __restrict__ A, int lda,
    const bf16* __restrict__ Bt, int ldb,
    void* __restrict__ C, int ldc,
    const float* __restrict__ bias,
    const float* __restrict__ res, int ldres,
    int M, int N, int K) {
    constexpr int BN = (EPI == 2) ? 64 : 128;
    constexpr int MI = (EPI == 2) ? 2 : 4;
    __shared__ short A_lds[2][128 * 32];
    __shared__ short B_lds[2][BN * 32];
    __shared__ short G_lds[EPI == 2 ? 2 * 64 * 32 : 8];

    const int t = threadIdx.x;
    const int wid = t >> 6, lane = t & 63;
    const int lrow = lane & 15, lgrp = lane >> 4;
    const int m0 = blockIdx.y * 128, n0 = blockIdx.x * BN;
    const int wm = (EPI == 2) ? wid * 32 : (wid & 1) * 64;
    const int wn = (EPI == 2) ? 0 : (wid >> 1) * 64;

    f4v acc[MI][4];
    f4v accg[EPI == 2 ? MI : 1][4];
#pragma unroll
    for (int i = 0; i < MI; i++)
#pragma unroll
        for (int j = 0; j < 4; j++) {
            acc[i][j] = (f4v){0.f, 0.f, 0.f, 0.f};
            if (EPI == 2) accg[i][j] = (f4v){0.f, 0.f, 0.f, 0.f};
        }

    const int scol = (lane & 3) * 8;
    const int arow = wid * 32 + (lane >> 2);
    const int brow = (EPI == 2) ? (wid * 16 + (lane >> 2)) : arow;
    const bf16* Ag0 = A + (size_t)(m0 + arow) * lda + scol;
    const bf16* Bg0 = Bt + (size_t)(n0 + brow) * ldb + scol;
    const bf16* Gg0 = (EPI == 2) ? (Bt + (size_t)(INNER + n0 + brow) * ldb + scol) : Bg0;

    auto stage = [&](int buf, int kk) {
        gl_lds16(Ag0 + kk, &A_lds[buf][wid * 1024]);
        gl_lds16(Ag0 + kk + (size_t)16 * lda, &A_lds[buf][wid * 1024 + 512]);
        if constexpr (EPI == 2) {
            gl_lds16(Bg0 + kk, &B_lds[buf][wid * 512]);
            gl_lds16(Gg0 + kk, &G_lds[buf * 2048 + wid * 512]);
        } else {
            gl_lds16(Bg0 + kk, &B_lds[buf][wid * 1024]);
            gl_lds16(Bg0 + kk + (size_t)16 * ldb, &B_lds[buf][wid * 1024 + 512]);
        }
    };

    stage(0, 0);
    __syncthreads();
    int buf = 0;
    for (int k0 = 0; k0 < K; k0 += 32, buf ^= 1) {
        if (k0 + 32 < K) stage(buf ^ 1, k0 + 32);

        s8v af[MI], bfr[4];
#pragma unroll
        for (int i = 0; i < MI; i++)
            af[i] = *(const s8v*)&A_lds[buf][(wm + i * 16 + lrow) * 32 + lgrp * 8];
#pragma unroll
        for (int j = 0; j < 4; j++)
            bfr[j] = *(const s8v*)&B_lds[buf][(wn + j * 16 + lrow) * 32 + lgrp * 8];
#pragma unroll
        for (int i = 0; i < MI; i++)
#pragma unroll
            for (int j = 0; j < 4; j++)
                acc[i][j] = __builtin_amdgcn_mfma_f32_16x16x32_bf16(af[i], bfr[j], acc[i][j], 0, 0, 0);
        if constexpr (EPI == 2) {
            s8v gfr[4];
#pragma unroll
            for (int j = 0; j < 4; j++)
                gfr[j] = *(const s8v*)&G_lds[buf * 2048 + (j * 16 + lrow) * 32 + lgrp * 8];
#pragma unroll
            for (int i = 0; i < MI; i++)
#pragma unroll
                for (int j = 0; j < 4; j++)
                    accg[i][j] = __builtin_amdgcn_mfma_f32_16x16x32_bf16(af[i], gfr[j], accg[i][j], 0, 0, 0);
        }
        __syncthreads();
    }

#pragma unroll
    for (int i = 0; i < MI; i++) {
#pragma unroll
        for (int r = 0; r < 4; r++) {
            int m = m0 + wm + i * 16 + lgrp * 4 + r;
#pragma unroll
            for (int j = 0; j < 4; j++) {
                int n = n0 + wn + j * 16 + lrow;
                float v = acc[i][j][r];
                if (EPI == 0) {
                    ((bf16*)C)[(size_t)m * ldc + n] = f2b(v);
                } else if (EPI == 1) {
                    v += bias[n] + res[(size_t)m * ldres + n];
                    ((float*)C)[(size_t)m * ldc + n] = v;
                } else {
                    float p = v + bias[n];
                    float g = accg[i][j][r] + bias[INNER + n];
                    float gl = 0.5f * g * (1.f + erff(g * 0.70710678118654752f));
                    ((bf16*)C)[(size_t)m * ldc + n] = f2b(p * gl);
                }
            }
        }
    }
}

// =====================================================================
// LEGACY kernels (fallback when workspace too small for weight scratch)
// =====================================================================
template <int EPI>
__global__ __launch_bounds__(256) void gemm_mfma(
    const bf16* __restrict__ A, int lda,
    const float* __restrict__ B, int ldb,
    void* __restrict__ C, int ldc,
    const float* __restrict__ bias,
    const float* __restrict__ res, int ldres,
    int M, int N, int K) {
    constexpr int LR = 40;
    __shared__ short A_lds[128 * LR];
    __shared__ short B_lds[128 * LR];
    __shared__ short G_lds[EPI == 2 ? 128 * LR : 4];

    const int t    = threadIdx.x;
    const int wid  = t >> 6, lane = t & 63;
    const int lrow = lane & 15, lgrp = lane >> 4;
    const int m0   = blockIdx.y * 128, n0 = blockIdx.x * 128;
    const int wm   = (wid & 1) * 64, wn = (wid >> 1) * 64;

    f4v acc[4][4];
    f4v accg[4][4];
#pragma unroll
    for (int i = 0; i < 4; i++)
#pragma unroll
        for (int j = 0; j < 4; j++) {
            acc[i][j] = (f4v){0.f, 0.f, 0.f, 0.f};
            if (EPI == 2) accg[i][j] = (f4v){0.f, 0.f, 0.f, 0.f};
        }

    const int b_np = (t & 31) * 4;
    const int b_kp = (t >> 5) * 4;

    for (int k0 = 0; k0 < K; k0 += 32) {
#pragma unroll
        for (int c = 0; c < 2; c++) {
            int idx = t + c * 256;
            int row = idx >> 2, g = (idx & 3) * 8;
            uint4 v = *(const uint4*)(A + (size_t)(m0 + row) * lda + k0 + g);
            *(uint4*)&A_lds[row * LR + g] = v;
        }
        {
            const float* bp = B + (size_t)(k0 + b_kp) * ldb + n0 + b_np;
            float4 r0 = *(const float4*)(bp);
            float4 r1 = *(const float4*)(bp + ldb);
            float4 r2 = *(const float4*)(bp + 2 * ldb);
            float4 r3 = *(const float4*)(bp + 3 * ldb);
            *(s4v*)&B_lds[(b_np + 0) * LR + b_kp] = (s4v){f2s(r0.x), f2s(r1.x), f2s(r2.x), f2s(r3.x)};
            *(s4v*)&B_lds[(b_np + 1) * LR + b_kp] = (s4v){f2s(r0.y), f2s(r1.y), f2s(r2.y), f2s(r3.y)};
            *(s4v*)&B_lds[(b_np + 2) * LR + b_kp] = (s4v){f2s(r0.z), f2s(r1.z), f2s(r2.z), f2s(r3.z)};
            *(s4v*)&B_lds[(b_np + 3) * LR + b_kp] = (s4v){f2s(r0.w), f2s(r1.w), f2s(r2.w), f2s(r3.w)};
        }
        if (EPI == 2) {
            const float* gp = B + (size_t)(k0 + b_kp) * ldb + INNER + n0 + b_np;
            float4 r0 = *(const float4*)(gp);
            float4 r1 = *(const float4*)(gp + ldb);
            float4 r2 = *(const float4*)(gp + 2 * ldb);
            float4 r3 = *(const float4*)(gp + 3 * ldb);
            *(s4v*)&G_lds[(b_np + 0) * LR + b_kp] = (s4v){f2s(r0.x), f2s(r1.x), f2s(r2.x), f2s(r3.x)};
            *(s4v*)&G_lds[(b_np + 1) * LR + b_kp] = (s4v){f2s(r0.y), f2s(r1.y), f2s(r2.y), f2s(r3.y)};
            *(s4v*)&G_lds[(b_np + 2) * LR + b_kp] = (s4v){f2s(r0.z), f2s(r1.z), f2s(r2.z), f2s(r3.z)};
            *(s4v*)&G_lds[(b_np + 3) * LR + b_kp] = (s4v){f2s(r0.w), f2s(r1.w), f2s(r2.w), f2s(r3.w)};
        }
        __syncthreads();
        s8v af[4], bfr[4];
#pragma unroll
        for (int i = 0; i < 4; i++)
            af[i] = *(const s8v*)&A_lds[(wm + i * 16 + lrow) * LR + lgrp * 8];
#pragma unroll
        for (int j = 0; j < 4; j++)
            bfr[j] = *(const s8v*)&B_lds[(wn + j * 16 + lrow) * LR + lgrp * 8];
#pragma unroll
        for (int i = 0; i < 4; i++)
#pragma unroll
            for (int j = 0; j < 4; j++)
                acc[i][j] = __builtin_amdgcn_mfma_f32_16x16x32_bf16(af[i], bfr[j], acc[i][j], 0, 0, 0);
        if (EPI == 2) {
            s8v gfr[4];
#pragma unroll
            for (int j = 0; j < 4; j++)
                gfr[j] = *(const s8v*)&G_lds[(wn + j * 16 + lrow) * LR + lgrp * 8];
#pragma unroll
            for (int i = 0; i < 4; i++)
#pragma unroll
                for (int j = 0; j < 4; j++)
                    accg[i][j] = __builtin_amdgcn_mfma_f32_16x16x32_bf16(af[i], gfr[j], accg[i][j], 0, 0, 0);
        }
        __syncthreads();
    }
#pragma unroll
    for (int i = 0; i < 4; i++) {
#pragma unroll
        for (int r = 0; r < 4; r++) {
            int m = m0 + wm + i * 16 + lgrp * 4 + r;
#pragma unroll
            for (int j = 0; j < 4; j++) {
                int n = n0 + wn + j * 16 + lrow;
                float v = acc[i][j][r];
                if (EPI == 0) {
                    ((bf16*)C)[(size_t)m * ldc + n] = f2b(v);
                } else if (EPI == 1) {
                    v += bias[n] + res[(size_t)m * ldres + n];
                    ((float*)C)[(size_t)m * ldc + n] = v;
                } else {
                    float p = v + bias[n];
                    float g = accg[i][j][r] + bias[INNER + n];
                    float gl = 0.5f * g * (1.f + erff(g * 0.70710678118654752f));
                    ((bf16*)C)[(size_t)m * ldc + n] = f2b(p * gl);
                }
            }
        }
    }
}

__global__ __launch_bounds__(256) void gemm_valu(
    const float* __restrict__ A, int lda,
    const float* __restrict__ B, int ldb,
    bf16* __restrict__ C, int ldc,
    int M, int N, int K) {
    __shared__ float As[16][65];
    __shared__ float Bs[16][65];
    const int t  = threadIdx.x;
    const int m0 = blockIdx.y * 64, n0 = blockIdx.x * 64;
    const int ar = t >> 2, ak = (t & 3) * 4;
    const int bk = t >> 4, bn = (t & 15) * 4;
    const int ty = t >> 4, tx = t & 15;
    float acc[4][4];
#pragma unroll
    for (int i = 0; i < 4; i++)
#pragma unroll
        for (int j = 0; j < 4; j++) acc[i][j] = 0.f;

    for (int k0 = 0; k0 < K; k0 += 16) {
        {
            int m = m0 + ar;
            float tmp[4];
            if (m < M) load4(A + (size_t)m * lda + k0 + ak, tmp);
            else { tmp[0] = tmp[1] = tmp[2] = tmp[3] = 0.f; }
            As[ak + 0][ar] = tmp[0]; As[ak + 1][ar] = tmp[1];
            As[ak + 2][ar] = tmp[2]; As[ak + 3][ar] = tmp[3];
        }
        {
            float tmp[4];
            load4(B + (size_t)(k0 + bk) * ldb + n0 + bn, tmp);
            Bs[bk][bn + 0] = tmp[0]; Bs[bk][bn + 1] = tmp[1];
            Bs[bk][bn + 2] = tmp[2]; Bs[bk][bn + 3] = tmp[3];
        }
        __syncthreads();
#pragma unroll
        for (int k = 0; k < 16; k++) {
            float a[4], b[4];
#pragma unroll
            for (int i = 0; i < 4; i++) a[i] = As[k][ty * 4 + i];
#pragma unroll
            for (int j = 0; j < 4; j++) b[j] = Bs[k][tx * 4 + j];
#pragma unroll
            for (int i = 0; i < 4; i++)
#pragma unroll
                for (int j = 0; j < 4; j++) acc[i][j] += a[i] * b[j];
        }
        __syncthreads();
    }
#pragma unroll
    for (int i = 0; i < 4; i++) {
        int m = m0 + ty * 4 + i;
        if (m >= M) continue;
#pragma unroll
        for (int j = 0; j < 4; j++) {
            int n = n0 + tx * 4 + j;
            C[(size_t)m * ldc + n] = f2b(acc[i][j]);
        }
    }
}

#define SOFTMAX_SCALE 0.07905694150420949f  // 1/sqrt(160)

// =====================================================================
// attn1 (sparse-causal, 512 keys) — MFMA flash-attention.
// q/k/v may live in a fused QKV buffer: row stride = ldq. Output stride DIM.
// =====================================================================
#define A1_KP 168   // K LDS pitch (shorts): 160 + 8 pad
#define A1_VP 72    // V^T pitch (shorts):   64 + 8 pad
#define A1_PP 72    // P  pitch (shorts)

__global__ __launch_bounds__(256) void attn1_mfma(const bf16* __restrict__ q,
                                                  const bf16* __restrict__ k,
                                                  const bf16* __restrict__ v,
                                                  int ldq,
                                                  bf16* __restrict__ o) {
    __shared__ short K_lds[64 * A1_KP];
    __shared__ short Vt_lds[160 * A1_VP];
    __shared__ short P_lds[4 * 16 * A1_PP];

    const int t = threadIdx.x;
    const int wid = t >> 6, lane = t & 63;
    const int lrow = lane & 15, lgrp = lane >> 4;
    const int bx = blockIdx.x, hd = blockIdx.y, bfi = blockIdx.z;
    const int bi = bfi >> 4, fi = bfi & 15;
    const int former = fi > 0 ? fi - 1 : 0;
    const int qrow0 = bfi * TOK + bx * 64 + wid * 16;

    s8v qf[5];
    {
        const bf16* qp = q + (size_t)(qrow0 + lrow) * ldq + hd * DH + lgrp * 8;
#pragma unroll
        for (int ks = 0; ks < 5; ks++)
            qf[ks] = *(const s8v*)(qp + ks * 32);
    }

    f4v oacc[10];
#pragma unroll
    for (int dg = 0; dg < 10; dg++) oacc[dg] = (f4v){0.f, 0.f, 0.f, 0.f};
    float m_run[4], l_run[4];
#pragma unroll
    for (int r = 0; r < 4; r++) { m_run[r] = -1e30f; l_run[r] = 0.f; }

    short* P_w = P_lds + wid * 16 * A1_PP;

    for (int c = 0; c < 8; c++) {
        const int kf = (c < 4) ? 0 : former;
        const size_t krow0 = (size_t)(bi * FRAMES + kf) * TOK + (c & 3) * 64;

        __syncthreads();
#pragma unroll
        for (int it = 0; it < 5; it++) {
            int idx = t + it * 256;
            int jr = idx / 20, g = idx % 20;
            const bf16* kp = k + (krow0 + jr) * ldq + hd * DH + g * 8;
            *(uint4*)&K_lds[jr * A1_KP + g * 8] = *(const uint4*)kp;
            s8v vv = *(const s8v*)(v + (krow0 + jr) * ldq + hd * DH + g * 8);
#pragma unroll
            for (int i = 0; i < 8; i++) {
                int d = g * 8 + i;
                Vt_lds[d * A1_VP + (jr ^ (d & 56))] = vv[i];
            }
        }
        __syncthreads();

        f4v sacc[4];
#pragma unroll
        for (int kg = 0; kg < 4; kg++) {
            sacc[kg] = (f4v){0.f, 0.f, 0.f, 0.f};
#pragma unroll
            for (int ks = 0; ks < 5; ks++) {
                s8v kfr = *(const s8v*)&K_lds[(kg * 16 + lrow) * A1_KP + ks * 32 + lgrp * 8];
                sacc[kg] = __builtin_amdgcn_mfma_f32_16x16x32_bf16(qf[ks], kfr, sacc[kg], 0, 0, 0);
            }
        }

        float mc[4];
#pragma unroll
        for (int r = 0; r < 4; r++) {
            float mm = fmaxf(fmaxf(sacc[0][r], sacc[1][r]), fmaxf(sacc[2][r], sacc[3][r]));
            mc[r] = mm * SOFTMAX_SCALE;
        }
#pragma unroll
        for (int x = 1; x < 16; x <<= 1)
#pragma unroll
            for (int r = 0; r < 4; r++)
                mc[r] = fmaxf(mc[r], __shfl_xor(mc[r], x));

        float p[4][4], rs[4];
#pragma unroll
        for (int r = 0; r < 4; r++) {
            float mn = fmaxf(m_run[r], mc[r]);
            float sc = __expf(m_run[r] - mn);
            m_run[r] = mn;
            l_run[r] *= sc;
#pragma unroll
            for (int dg = 0; dg < 10; dg++) oacc[dg][r] *= sc;
            float acc = 0.f;
#pragma unroll
            for (int kg = 0; kg < 4; kg++) {
                float e = __expf(sacc[kg][r] * SOFTMAX_SCALE - mn);
                p[kg][r] = e; acc += e;
            }
            rs[r] = acc;
        }
#pragma unroll
        for (int x = 1; x < 16; x <<= 1)
#pragma unroll
            for (int r = 0; r < 4; r++)
                rs[r] += __shfl_xor(rs[r], x);
#pragma unroll
        for (int r = 0; r < 4; r++) l_run[r] += rs[r];

#pragma unroll
        for (int kg = 0; kg < 4; kg++)
#pragma unroll
            for (int r = 0; r < 4; r++)
                P_w[(lgrp * 4 + r) * A1_PP + kg * 16 + lrow] = f2s(p[kg][r]);
        __syncthreads();

        s8v pa[2];
#pragma unroll
        for (int ks2 = 0; ks2 < 2; ks2++)
            pa[ks2] = *(const s8v*)&P_w[lrow * A1_PP + ks2 * 32 + lgrp * 8];
#pragma unroll
        for (int dg = 0; dg < 10; dg++) {
            int dd = dg * 16 + lrow;
#pragma unroll
            for (int ks2 = 0; ks2 < 2; ks2++) {
                s8v vfr = *(const s8v*)&Vt_lds[dd * A1_VP + ((ks2 * 32 + lgrp * 8) ^ (dd & 56))];
                oacc[dg] = __builtin_amdgcn_mfma_f32_16x16x32_bf16(pa[ks2], vfr, oacc[dg], 0, 0, 0);
            }
        }
    }

    float invl[4];
#pragma unroll
    for (int r = 0; r < 4; r++) invl[r] = 1.f / l_run[r];
#pragma unroll
    for (int dg = 0; dg < 10; dg++) {
#pragma unroll
        for (int r = 0; r < 4; r++) {
            int qq = qrow0 + lgrp * 4 + r;
            o[(size_t)qq * DIM + hd * DH + dg * 16 + lrow] = f2b(oacc[dg][r] * invl[r]);
        }
    }
}

// =====================================================================
// attn2 (cross, 77 keys) — MFMA flash-attention, 2 key-chunks, masked.
// k/v have row stride ldk (fused KV buffer); pad rows are exact zeros.
// =====================================================================
__global__ __launch_bounds__(256) void attn2_mfma(const bf16* __restrict__ q,
                                                  const bf16* __restrict__ k,
                                                  const bf16* __restrict__ v,
                                                  int ldk,
                                                  bf16* __restrict__ o) {
    __shared__ short K_lds[64 * A1_KP];
    __shared__ short Vt_lds[160 * A1_VP];
    __shared__ short P_lds[4 * 16 * A1_PP];

    const int t = threadIdx.x;
    const int wid = t >> 6, lane = t & 63;
    const int lrow = lane & 15, lgrp = lane >> 4;
    const int bx = blockIdx.x, hd = blockIdx.y, bfi = blockIdx.z;
    const int qrow0 = bfi * TOK + bx * 64 + wid * 16;

    s8v qf[5];
    {
        const bf16* qp = q + (size_t)(qrow0 + lrow) * DIM + hd * DH + lgrp * 8;
#pragma unroll
        for (int ks = 0; ks < 5; ks++)
            qf[ks] = *(const s8v*)(qp + ks * 32);
    }

    f4v oacc[10];
#pragma unroll
    for (int dg = 0; dg < 10; dg++) oacc[dg] = (f4v){0.f, 0.f, 0.f, 0.f};
    float m_run[4], l_run[4];
#pragma unroll
    for (int r = 0; r < 4; r++) { m_run[r] = -1e30f; l_run[r] = 0.f; }

    short* P_w = P_lds + wid * 16 * A1_PP;

    for (int c = 0; c < 2; c++) {
        const size_t krow0 = (size_t)bfi * ESEQ + c * 64;

        __syncthreads();
#pragma unroll
        for (int it = 0; it < 5; it++) {
            int idx = t + it * 256;
            int jr = idx / 20, g = idx % 20;
            const bf16* kp = k + (krow0 + jr) * ldk + hd * DH + g * 8;
            *(uint4*)&K_lds[jr * A1_KP + g * 8] = *(const uint4*)kp;
            s8v vv = *(const s8v*)(v + (krow0 + jr) * ldk + hd * DH + g * 8);
#pragma unroll
            for (int i = 0; i < 8; i++) {
                int d = g * 8 + i;
                Vt_lds[d * A1_VP + (jr ^ (d & 56))] = vv[i];
            }
        }
        __syncthreads();

        f4v sacc[4];
#pragma unroll
        for (int kg = 0; kg < 4; kg++) {
            sacc[kg] = (f4v){0.f, 0.f, 0.f, 0.f};
#pragma unroll
            for (int ks = 0; ks < 5; ks++) {
                s8v kfr = *(const s8v*)&K_lds[(kg * 16 + lrow) * A1_KP + ks * 32 + lgrp * 8];
                sacc[kg] = __builtin_amdgcn_mfma_f32_16x16x32_bf16(qf[ks], kfr, sacc[kg], 0, 0, 0);
            }
            if (c == 1 && (kg > 0 || lrow >= 13))
                sacc[kg] = (f4v){-1e30f, -1e30f, -1e30f, -1e30f};
        }

        float mc[4];
#pragma unroll
        for (int r = 0; r < 4; r++) {
            float mm = fmaxf(fmaxf(sacc[0][r], sacc[1][r]), fmaxf(sacc[2][r], sacc[3][r]));
            mc[r] = mm * SOFTMAX_SCALE;
        }
#pragma unroll
        for (int x = 1; x < 16; x <<= 1)
#pragma unroll
            for (int r = 0; r < 4; r++)
                mc[r] = fmaxf(mc[r], __shfl_xor(mc[r], x));

        float p[4][4], rs[4];
#pragma unroll
        for (int r = 0; r < 4; r++) {
            float mn = fmaxf(m_run[r], mc[r]);
            float sc = __expf(m_run[r] - mn);
            m_run[r] = mn;
            l_run[r] *= sc;
#pragma unroll
            for (int dg = 0; dg < 10; dg++) oacc[dg][r] *= sc;
            float acc = 0.f;
#pragma unroll
            for (int kg = 0; kg < 4; kg++) {
                float e = __expf(sacc[kg][r] * SOFTMAX_SCALE - mn);
                p[kg][r] = e; acc += e;
            }
            rs[r] = acc;
        }
#pragma unroll
        for (int x = 1; x < 16; x <<= 1)
#pragma unroll
            for (int r = 0; r < 4; r++)
                rs[r] += __shfl_xor(rs[r], x);
#pragma unroll
        for (int r = 0; r < 4; r++) l_run[r] += rs[r];

#pragma unroll
        for (int kg = 0; kg < 4; kg++)
#pragma unroll
            for (int r = 0; r < 4; r++)
                P_w[(lgrp * 4 + r) * A1_PP + kg * 16 + lrow] = f2s(p[kg][r]);
        __syncthreads();

        s8v pa[2];
#pragma unroll
        for (int ks2 = 0; ks2 < 2; ks2++)
            pa[ks2] = *(const s8v*)&P_w[lrow * A1_PP + ks2 * 32 + lgrp * 8];
#pragma unroll
        for (int dg = 0; dg < 10; dg++) {
            int dd = dg * 16 + lrow;
#pragma unroll
            for (int ks2 = 0; ks2 < 2; ks2++) {
                s8v vfr = *(const s8v*)&Vt_lds[dd * A1_VP + ((ks2 * 32 + lgrp * 8) ^ (dd & 56))];
                oacc[dg] = __builtin_amdgcn_mfma_f32_16x16x32_bf16(pa[ks2], vfr, oacc[dg], 0, 0, 0);
            }
        }
    }

    float invl[4];
#pragma unroll
    for (int r = 0; r < 4; r++) invl[r] = 1.f / l_run[r];
#pragma unroll
    for (int dg = 0; dg < 10; dg++) {
#pragma unroll
        for (int r = 0; r < 4; r++) {
            int qq = qrow0 + lgrp * 4 + r;
            o[(size_t)qq * DIM + hd * DH + dg * 16 + lrow] = f2b(oacc[dg][r] * invl[r]);
        }
    }
}

// ---- attn2 legacy scalar (tier0 fallback) ----
__global__ __launch_bounds__(256) void attn2_kernel(const bf16* __restrict__ q,
                                                    const bf16* __restrict__ k,
                                                    const bf16* __restrict__ v,
                                                    bf16* __restrict__ o) {
    __shared__ float sQ[DH];
    __shared__ float sS[128];
    __shared__ float red[256];
    int t = threadIdx.x;
    int qi = blockIdx.x, hd = blockIdx.y, bfi = blockIdx.z;
    size_t qbase = ((size_t)(bfi * TOK + qi)) * DIM + hd * DH;
    if (t < DH) sQ[t] = b2f(q[qbase + t]);
    __syncthreads();
    if (t < ESEQ) {
        size_t kbase = ((size_t)(bfi * ESEQ + t)) * DIM + hd * DH;
        float acc = 0.f;
        for (int d = 0; d < DH; d++) acc += sQ[d] * b2f(k[kbase + d]);
        sS[t] = acc * SOFTMAX_SCALE;
    }
    __syncthreads();
    float lm = (t < ESEQ) ? sS[t] : -1e30f;
    red[t] = lm; __syncthreads();
    for (int s = 128; s > 0; s >>= 1) { if (t < s) red[t] = fmaxf(red[t], red[t + s]); __syncthreads(); }
    float mx = red[0]; __syncthreads();
    float ls = 0.f;
    if (t < ESEQ) { float e = __expf(sS[t] - mx); sS[t] = e; ls = e; }
    red[t] = ls; __syncthreads();
    for (int s = 128; s > 0; s >>= 1) { if (t < s) red[t] += red[t + s]; __syncthreads(); }
    float inv = 1.f / red[0];
    __syncthreads();
    if (t < DH) {
        float acc = 0.f;
        for (int j = 0; j < ESEQ; j++) {
            size_t vbase = ((size_t)(bfi * ESEQ + j)) * DIM + hd * DH;
            acc += sS[j] * b2f(v[vbase + t]);
        }
        o[qbase + t] = f2b(acc * inv);
    }
}

// =====================================================================
// attnt (temporal, 16 keys) — vectorized full-block kernel.
// =====================================================================
#define AT_P 168
__global__ __launch_bounds__(256) void attnt_vec(const bf16* __restrict__ q,
                                                 const bf16* __restrict__ k,
                                                 const bf16* __restrict__ v,
                                                 int ldq,
                                                 bf16* __restrict__ o) {
    __shared__ short Q_l[16 * AT_P], K_l[16 * AT_P], V_l[16 * AT_P];
    __shared__ float P_l[16][17];
    const int t = threadIdx.x;
    const int hd = blockIdx.y;
    const int z = blockIdx.x;
    const int bi = z >> 8, ti = z & 255;

#pragma unroll
    for (int it = 0; it < 2; it++) {
        int c = t + it * 256;
        if (c < 320) {
            int f = c / 20, g = c % 20;
            size_t row = (size_t)(bi * FRAMES + f) * TOK + ti;
            const bf16* qp = q + row * ldq + hd * DH + g * 8;
            const bf16* kp = k + row * ldq + hd * DH + g * 8;
            const bf16* vp = v + row * ldq + hd * DH + g * 8;
            *(uint4*)&Q_l[f * AT_P + g * 8] = *(const uint4*)qp;
            *(uint4*)&K_l[f * AT_P + g * 8] = *(const uint4*)kp;
            *(uint4*)&V_l[f * AT_P + g * 8] = *(const uint4*)vp;
        }
    }
    __syncthreads();

    const int fq = t >> 4, fk = t & 15;
    float acc = 0.f;
#pragma unroll
    for (int dg = 0; dg < 20; dg++) {
        s8v qv = *(const s8v*)&Q_l[fq * AT_P + dg * 8];
        s8v kv = *(const s8v*)&K_l[fk * AT_P + dg * 8];
#pragma unroll
        for (int e = 0; e < 8; e++)
            acc += us2f((unsigned short)qv[e]) * us2f((unsigned short)kv[e]);
    }
    acc *= SOFTMAX_SCALE;
    float mx = acc;
#pragma unroll
    for (int x = 1; x < 16; x <<= 1) mx = fmaxf(mx, __shfl_xor(mx, x));
    float ex = __expf(acc - mx);
    float sm = ex;
#pragma unroll
    for (int x = 1; x < 16; x <<= 1) sm += __shfl_xor(sm, x);
    P_l[fq][fk] = ex / sm;
    __syncthreads();

#pragma unroll
    for (int it = 0; it < 2; it++) {
        int a = t + it * 256;
        if (a < 320) {
            int pq = a & 15, dg = a >> 4;
            float pr[16];
#pragma unroll
            for (int j = 0; j < 16; j++) pr[j] = P_l[pq][j];
            float ov[8] = {0.f, 0.f, 0.f, 0.f, 0.f, 0.f, 0.f, 0.f};
#pragma unroll
            for (int j = 0; j < 16; j++) {
                s8v vv = *(const s8v*)&V_l[j * AT_P + dg * 8];
#pragma unroll
                for (int i = 0; i < 8; i++)
                    ov[i] += pr[j] * us2f((unsigned short)vv[i]);
            }
            s8v o8;
#pragma unroll
            for (int i = 0; i < 8; i++) o8[i] = f2s(ov[i]);
            size_t orow = (size_t)(bi * FRAMES + pq) * TOK + ti;
            *(s8v*)(o + orow * DIM + hd * DH + dg * 8) = o8;
        }
    }
}

// ---- temporal self-attn legacy scalar (tier0 fallback) ----
__global__ __launch_bounds__(256) void attnt_kernel(const bf16* __restrict__ q,
                                                    const bf16* __restrict__ k,
                                                    const bf16* __restrict__ v,
                                                    int ldq,
                                                    bf16* __restrict__ o) {
    __shared__ float sQ[DH];
    __shared__ float sS[16];
    __shared__ float red[256];
    int t = threadIdx.x;
    int qfi = blockIdx.x, hd = blockIdx.y, z = blockIdx.z;
    int bi = z >> 8, ti = z & 255;
    size_t qrow = (size_t)(bi * FRAMES + qfi) * TOK + ti;
    if (t < DH) sQ[t] = b2f(q[qrow * ldq + hd * DH + t]);
    __syncthreads();
    if (t < FRAMES) {
        size_t krow = (size_t)(bi * FRAMES + t) * TOK + ti;
        float acc = 0.f;
        for (int d = 0; d < DH; d++) acc += sQ[d] * b2f(k[krow * ldq + hd * DH + d]);
        sS[t] = acc * SOFTMAX_SCALE;
    }
    __syncthreads();
    float lm = (t < FRAMES) ? sS[t] : -1e30f;
    red[t] = lm; __syncthreads();
    for (int s = 128; s > 0; s >>= 1) { if (t < s) red[t] = fmaxf(red[t], red[t + s]); __syncthreads(); }
    float mx = red[0]; __syncthreads();
    float ls = 0.f;
    if (t < FRAMES) { float e = __expf(sS[t] - mx); sS[t] = e; ls = e; }
    red[t] = ls; __syncthreads();
    for (int s = 128; s > 0; s >>= 1) { if (t < s) red[t] += red[t + s]; __syncthreads(); }
    float inv = 1.f / red[0];
    __syncthreads();
    if (t < DH) {
        float acc = 0.f;
        for (int j = 0; j < FRAMES; j++) {
            size_t vrow = (size_t)(bi * FRAMES + j) * TOK + ti;
            acc += sS[j] * b2f(v[vrow * ldq + hd * DH + t]);
        }
        o[qrow * DIM + hd * DH + t] = f2b(acc * inv);
    }
}

extern "C" void kernel_launch(void* const* d_in, const int* in_sizes, int n_in,
                              void* d_out, int out_size, void* d_ws, size_t ws_size,
                              hipStream_t stream) {
    (void)in_sizes; (void)n_in; (void)out_size;
    const float* hs   = (const float*)d_in[0];
    const float* enc  = (const float*)d_in[1];
    const float* n1w  = (const float*)d_in[2];
    const float* n1b  = (const float*)d_in[3];
    const float* a1wq = (const float*)d_in[4];
    const float* a1wk = (const float*)d_in[5];
    const float* a1wv = (const float*)d_in[6];
    const float* a1wo = (const float*)d_in[7];
    const float* a1bo = (const float*)d_in[8];
    const float* n2w  = (const float*)d_in[9];
    const float* n2b  = (const float*)d_in[10];
    const float* a2wq = (const float*)d_in[11];
    const float* a2wk = (const float*)d_in[12];
    const float* a2wv = (const float*)d_in[13];
    const float* a2wo = (const float*)d_in[14];
    const float* a2bo = (const float*)d_in[15];
    const float* n3w  = (const float*)d_in[16];
    const float* n3b  = (const float*)d_in[17];
    const float* ffw1 = (const float*)d_in[18];
    const float* ffb1 = (const float*)d_in[19];
    const float* ffw2 = (const float*)d_in[20];
    const float* ffb2 = (const float*)d_in[21];
    const float* ntw  = (const float*)d_in[22];
    const float* ntb  = (const float*)d_in[23];
    const float* atwq = (const float*)d_in[24];
    const float* atwk = (const float*)d_in[25];
    const float* atwv = (const float*)d_in[26];
    const float* atwo = (const float*)d_in[27];
    const float* atbo = (const float*)d_in[28];

    char* wp = (char*)d_ws;
    auto carve = [&](size_t bytes) -> char* {
        char* p = wp; wp += (bytes + 255) & ~((size_t)255); return p;
    };
    const size_t BUF = (size_t)ROWS * DIM * 2;   // 20,971,520
    const size_t W_FULL = 26214400;              // ffw1t: 10240x1280 bf16
    float* out = (float*)d_out;                  // f32 residual stream in d_out
    dim3 blk(256);
    dim3 blk8(512);

    bf16* nh = (bf16*)carve(BUF);

    bool full = (ws_size >= 5 * BUF + W_FULL + 4096);
    if (!full) {
        // ------- legacy path (R1 kernel, known-good at 105 MB ws) -------
        bf16* qb = (bf16*)carve(BUF);
        bf16* kb = (bf16*)carve(BUF);
        bf16* vb = (bf16*)carve(BUF);
        bf16* ob = (bf16*)carve(BUF);
        bf16* Pb = qb;
        auto proj = [&](const bf16* A, int lda, const float* B, int ldb,
                        bf16* C, int ldc, int M, int N, int K) {
            gemm_mfma<0><<<dim3(N / 128, M / 128), blk, 0, stream>>>(
                A, lda, B, ldb, C, ldc, nullptr, nullptr, 0, M, N, K);
        };
        auto outproj = [&](const bf16* A, int lda, const float* B,
                           const float* bias, const float* res, int K) {
            gemm_mfma<1><<<dim3(DIM / 128, ROWS / 128), blk, 0, stream>>>(
                A, lda, B, DIM, out, DIM, bias, res, DIM, ROWS, DIM, K);
        };
        ln_kernel<<<dim3(ROWS), blk, 0, stream>>>(hs, n1w, n1b, nh);
        proj(nh, DIM, a1wq, DIM, qb, DIM, ROWS, DIM, DIM);
        proj(nh, DIM, a1wk, DIM, kb, DIM, ROWS, DIM, DIM);
        proj(nh, DIM, a1wv, DIM, vb, DIM, ROWS, DIM, DIM);
        attn1_mfma<<<dim3(TOK / 64, HEADS, BF), blk, 0, stream>>>(qb, kb, vb, DIM, ob);
        outproj(ob, DIM, a1wo, a1bo, hs, DIM);

        ln_kernel<<<dim3(ROWS), blk, 0, stream>>>(out, n2w, n2b, nh);
        proj(nh, DIM, a2wq, DIM, qb, DIM, ROWS, DIM, DIM);
        gemm_valu<<<dim3(DIM / 64, (EROWS + 63) / 64), blk, 0, stream>>>(enc, CROSS, a2wk, DIM, kb, DIM, EROWS, DIM, CROSS);
        gemm_valu<<<dim3(DIM / 64, (EROWS + 63) / 64), blk, 0, stream>>>(enc, CROSS, a2wv, DIM, vb, DIM, EROWS, DIM, CROSS);
        attn2_kernel<<<dim3(TOK, HEADS, BF), blk, 0, stream>>>(qb, kb, vb, ob);
        outproj(ob, DIM, a2wo, a2bo, out, DIM);

        ln_kernel<<<dim3(ROWS), blk, 0, stream>>>(out, n3w, n3b, nh);
        gemm_mfma<2><<<dim3(INNER / 128, ROWS / 128), blk, 0, stream>>>(
            nh, DIM, ffw1, 2 * INNER, Pb, INNER, ffb1, nullptr, 0, ROWS, INNER, DIM);
        outproj(Pb, INNER, ffw2, ffb2, out, INNER);

        ln_kernel<<<dim3(ROWS), blk, 0, stream>>>(out, ntw, ntb, nh);
        proj(nh, DIM, atwq, DIM, qb, DIM, ROWS, DIM, DIM);
        proj(nh, DIM, atwk, DIM, kb, DIM, ROWS, DIM, DIM);
        proj(nh, DIM, atwv, DIM, vb, DIM, ROWS, DIM, DIM);
        attnt_kernel<<<dim3(FRAMES, HEADS, BATCH * TOK), blk, 0, stream>>>(qb, kb, vb, DIM, ob);
        outproj(ob, DIM, atwo, atbo, out, DIM);
        return;
    }

    // ------- full path: bf16 B^T weights + 256^2 gemm_bt8 + fused QKV -------
    bf16* C3 = (bf16*)carve(3 * BUF);            // fused QKV [ROWS][3840]
    bf16* ob = (bf16*)carve(BUF);
    bf16* Ws = (bf16*)carve(W_FULL);
    bf16* Pb = C3;                               // FFN intermediate spans C3+ob (84 MB)
    const size_t WQ = (size_t)DIM * DIM;
    const size_t WC = (size_t)DIM * CROSS;
    const int LDQ3 = 3 * DIM;                    // 3840

    auto projN = [&](const bf16* A, int lda, const bf16* Bt, int ldb,
                     bf16* C, int ldc, int M, int N, int K) {
        gemm_bt8<0><<<dim3(N / 256, M / 256), blk8, 0, stream>>>(
            A, lda, Bt, ldb, C, ldc, nullptr, nullptr, 0, M, N, K);
    };
    auto outprojN = [&](const bf16* A, int lda, const bf16* Bt, int ldb,
                        const float* bias, const float* res, int K) {
        gemm_bt8<1><<<dim3(DIM / 256, ROWS / 256), blk8, 0, stream>>>(
            A, lda, Bt, ldb, out, DIM, bias, res, DIM, ROWS, DIM, K);
    };

    // ---- attn1: sparse-causal self-attention (fused QKV proj, N=3840) ----
    wconv_t4<<<dim3(DIM / 64, DIM / 64, 4), blk, 0, stream>>>(
        a1wq, a1wk, a1wv, a1wo, Ws, WQ, DIM, DIM);
    ln_kernel<<<dim3(ROWS), blk, 0, stream>>>(hs, n1w, n1b, nh);
    projN(nh, DIM, Ws, DIM, C3, LDQ3, ROWS, 3 * DIM, DIM);
    attn1_mfma<<<dim3(TOK / 64, HEADS, BF), blk, 0, stream>>>(
        C3, C3 + DIM, C3 + 2 * DIM, LDQ3, ob);
    outprojN(ob, DIM, Ws + 3 * WQ, DIM, a1bo, hs, DIM);

    // ---- attn2: cross-attention (MFMA attn, padded encoder, fused KV) ----
    {
        bf16* w2q  = Ws;                         // [DIM][DIM]
        bf16* w2o  = Ws + WQ;                    // [DIM][DIM]
        bf16* w2k  = Ws + 2 * WQ;                // [DIM][CROSS]
        bf16* w2v  = w2k + WC;                   // [DIM][CROSS] (contiguous after w2k)
        bf16* encb = w2v + WC;                   // [EPAD][CROSS]
        bf16* qb2  = C3;                         // [ROWS][DIM]
        bf16* kv2  = C3 + (size_t)ROWS * DIM;    // [EPAD][2560] fused K|V
        wconv_t4<<<dim3(DIM / 64, DIM / 64, 2), blk, 0, stream>>>(
            a2wq, a2wo, nullptr, nullptr, w2q, WQ, DIM, DIM);
        wconv_t4<<<dim3(DIM / 64, CROSS / 64, 2), blk, 0, stream>>>(
            a2wk, a2wv, nullptr, nullptr, w2k, WC, DIM, CROSS);
        encconv<<<dim3(EPAD * CROSS / 1024), blk, 0, stream>>>(enc, encb);
        ln_kernel<<<dim3(ROWS), blk, 0, stream>>>(out, n2w, n2b, nh);
        projN(nh, DIM, w2q, DIM, qb2, DIM, ROWS, DIM, DIM);
        projN(encb, CROSS, w2k, CROSS, kv2, 2 * DIM, EPAD, 2 * DIM, CROSS);
        attn2_mfma<<<dim3(TOK / 64, HEADS, BF), blk, 0, stream>>>(
            qb2, kv2, kv2 + DIM, 2 * DIM, ob);
        outprojN(ob, DIM, w2o, DIM, a2bo, out, DIM);
    }

    // ---- geglu FFN (256x128 8-wave geglu GEMM) ----
    wconv_t<<<dim3(2 * INNER / 64, DIM / 64), blk, 0, stream>>>(ffw1, Ws, 2 * INNER, DIM);
    ln_kernel<<<dim3(ROWS), blk, 0, stream>>>(out, n3w, n3b, nh);
    gemm_bt8g<<<dim3(INNER / 128, ROWS / 256), blk8, 0, stream>>>(
        nh, DIM, Ws, DIM, Pb, INNER, ffb1, ROWS, INNER, DIM);
    wconv_t<<<dim3(DIM / 64, INNER / 64), blk, 0, stream>>>(ffw2, Ws, DIM, INNER);
    gemm_bt8<1><<<dim3(DIM / 256, ROWS / 256), blk8, 0, stream>>>(
        Pb, INNER, Ws, INNER, out, DIM, ffb2, out, DIM, ROWS, DIM, INNER);

    // ---- temporal self-attention (fused QKV proj + vectorized attn) ----
    wconv_t4<<<dim3(DIM / 64, DIM / 64, 4), blk, 0, stream>>>(
        atwq, atwk, atwv, atwo, Ws, WQ, DIM, DIM);
    ln_kernel<<<dim3(ROWS), blk, 0, stream>>>(out, ntw, ntb, nh);
    projN(nh, DIM, Ws, DIM, C3, LDQ3, ROWS, 3 * DIM, DIM);
    attnt_vec<<<dim3(BATCH * TOK, HEADS), blk, 0, stream>>>(
        C3, C3 + DIM, C3 + 2 * DIM, LDQ3, ob);
    outprojN(ob, DIM, Ws + 3 * WQ, DIM, atbo, out, DIM);
}